// Round 13
// baseline (447.355 us; speedup 1.0000x reference)
//
#include <hip/hip_runtime.h>
#include <math.h>

#define BB 64
#define LATENT 256
#define ACTD 6
#define HIDD 512
#define DST 16

typedef __attribute__((ext_vector_type(8))) short bf16x8;
typedef __attribute__((ext_vector_type(4))) float f32x4;

static __device__ __forceinline__ ushort f2bf(float f) {
  unsigned u = __builtin_bit_cast(unsigned, f);
  unsigned r = (u + 0x7FFFu + ((u >> 16) & 1u)) >> 16;
  return (ushort)r;
}
static __device__ __forceinline__ float bf2f(ushort u) {
  return __builtin_bit_cast(float, ((unsigned)u) << 16);
}

// ---------------- output offsets (floats) ----------------
#define O_PRED   0
#define O_ZT     4194304
#define O_STATE  4210688
#define O_MUP    4734976
#define O_LVP    4751360
#define O_MUPO   4767744
#define O_LVPO   4784128

// ---------------- ws offsets (floats), lifetime-reused ----------------
#define W_BELIEF 67584u
#define W_CNN    100352u
#define W_ZB16   133120u
#define PW_C2    137216u
#define PW_C3    153600u
#define PW_C4    219136u
#define PW_D1    481280u
#define PW_D2    546816u
#define PW_D3    563200u
#define PW_C1    567296u
#define W_TIMG   602112u      // timg4 bf16 [65536][64][4]
#define W_H1B    13185024u
#define W_H2B    29962240u
#define W_H3B    38350848u
#define W_H4B    42545152u
#define W_SIWT   44642304u
#define W_DWT    44776448u
#define W_PRWT   45038592u
#define W_POWT   45300736u
// reuse:
#define W_ENCP   602112u
#define W_DECO   8990720u
#define W_D1O    10039296u
#define W_D2O    13185024u
#define W_D3O    17379328u

#define ENC_KS 128

// ================= fused SSM chain =================
__global__ __launch_bounds__(512) void k_ssm_all(
    const float* __restrict__ z_prev, const float* __restrict__ act,
    const float* __restrict__ siwT, const float* __restrict__ sib,
    const float* __restrict__ DwT, const float* __restrict__ Db,
    const float* __restrict__ Bw, const float* __restrict__ Cw,
    const float* __restrict__ Alog, const float* __restrict__ Dv,
    const float* __restrict__ st_prev, float* __restrict__ state_out,
    float* __restrict__ belief_out, const float* __restrict__ prwT,
    const float* __restrict__ prb, float* __restrict__ out) {
  __shared__ float zs[256];
  __shared__ float as_[8];
  __shared__ float si[512];
  __shared__ float bel[512];
  __shared__ float part[2][16][4];
  __shared__ float btct[2][16];
  int b = blockIdx.x;
  int h = threadIdx.x;
  if (h < 256) zs[h] = z_prev[(size_t)b * LATENT + h];
  if (h >= 256 && h < 256 + ACTD) as_[h - 256] = act[(size_t)b * ACTD + (h - 256)];
  __syncthreads();
  {
    float acc = sib[h];
    #pragma unroll 8
    for (int k = 0; k < LATENT; ++k) acc += zs[k] * siwT[(size_t)k * 512 + h];
    #pragma unroll
    for (int k = 0; k < ACTD; ++k) acc += as_[k] * siwT[(size_t)(LATENT + k) * 512 + h];
    si[h] = acc / (1.f + expf(-acc));
  }
  __syncthreads();
  float d;
  {
    float acc = Db[h];
    #pragma unroll 8
    for (int k = 0; k < HIDD; ++k) acc += si[k] * DwT[(size_t)k * 512 + h];
    d = fmaxf(acc, 0.f) + log1pf(expf(-fabsf(acc)));
  }
  if (h < 128) {
    int half = h >> 6;
    int l = h & 63;
    int n = l & 15, p = l >> 4;
    const float* wr = (half ? Cw : Bw) + (size_t)n * HIDD + p * 128;
    const float* sr = si + p * 128;
    float acc = 0.f;
    #pragma unroll 4
    for (int k = 0; k < 128; k += 4) {
      float4 w4 = *(const float4*)(wr + k);
      acc += sr[k] * w4.x + sr[k+1] * w4.y + sr[k+2] * w4.z + sr[k+3] * w4.w;
    }
    part[half][n][p] = acc;
  }
  __syncthreads();
  if (h < 32) {
    int half = h >> 4, n = h & 15;
    btct[half][n] = part[half][n][0] + part[half][n][1] + part[half][n][2] + part[half][n][3];
  }
  __syncthreads();
  {
    float si_h = si[h];
    float belv = Dv[h] * si_h;
    const float* al = Alog + (size_t)h * DST;
    const float* sp = st_prev + ((size_t)b * 512 + h) * DST;
    float* so = state_out + ((size_t)b * 512 + h) * DST;
    #pragma unroll
    for (int n = 0; n < DST; ++n) {
      float A = -expf(al[n]);
      float st = expf(d * A) * sp[n] + d * btct[0][n] * si_h;
      so[n] = st;
      belv += st * btct[1][n];
    }
    bel[h] = belv;
    belief_out[(size_t)b * 512 + h] = belv;
  }
  __syncthreads();
  {
    float acc = prb[h];
    #pragma unroll 8
    for (int k = 0; k < HIDD; ++k) acc += bel[k] * prwT[(size_t)k * 512 + h];
    if (h < 256) out[O_MUP + b * 256 + h] = acc;
    else         out[O_LVP + b * 256 + (h - 256)] = acc;
  }
}

// ================= merged weight prepack =================

static __device__ __forceinline__ void pack_conv_elem(const float* __restrict__ w,
                                                      ushort* __restrict__ o,
                                                      int Cout, int Cin, int id) {
  int NCH = Cin / 2;
  int per = NCH * 512;
  int mt = id / per, r = id % per;
  int kcg = r >> 9, s = r & 511;
  int kg = s >> 7, m = (s >> 3) & 15, k8 = s & 7;
  int co = mt * 16 + m;
  int k = kcg * 32 + kg * 8 + k8;
  int tap = k / Cin, ci = k % Cin;
  o[id] = f2bf(w[(size_t)(co * Cin + ci) * 16 + tap]);
}

static __device__ __forceinline__ void pack_deconv_elem(const float* __restrict__ w,
                                                        ushort* __restrict__ o,
                                                        int Cout, int Cin, int id) {
  int NCH = Cin / 8;
  int perM = NCH * 512;
  int perC = (Cout / 16) * perM;
  int cls = id / perC, r = id % perC;
  int mt = r / perM, r2 = r % perM;
  int kcg = r2 >> 9, s = r2 & 511;
  int kg = s >> 7, m = (s >> 3) & 15, k8 = s & 7;
  int co = mt * 16 + m;
  int k = kcg * 32 + kg * 8 + k8;
  int t = k / Cin, ci = k % Cin;
  int p = (cls >> 1) + 2 * (t >> 1);
  int q = (cls & 1) + 2 * (t & 1);
  o[id] = f2bf(w[(size_t)(ci * Cout + co) * 16 + p * 4 + q]);
}

static __device__ __forceinline__ void pack_conv1_elem(const float* __restrict__ w,
                                                       ushort* __restrict__ o, int id) {
  int mt = id >> 10, r = id & 1023;
  int kcg = r >> 9, s = r & 511;
  int kg = s >> 7, m = (s >> 3) & 15, k8 = s & 7;
  int co = mt * 16 + m;
  int k = kcg * 32 + kg * 8 + k8;
  int tap = k >> 2, ci = k & 3;
  o[id] = (ci < 3) ? f2bf(w[(size_t)(co * 3 + ci) * 16 + tap]) : (ushort)0;
}

__global__ __launch_bounds__(256) void k_pack_all(
    const float* __restrict__ c2w, const float* __restrict__ c3w,
    const float* __restrict__ c4w, const float* __restrict__ d1w,
    const float* __restrict__ d2w, const float* __restrict__ d3w,
    const float* __restrict__ c1w,
    const float* __restrict__ siw, const float* __restrict__ Dw,
    const float* __restrict__ prw, const float* __restrict__ pw,
    ushort* __restrict__ pc2, ushort* __restrict__ pc3, ushort* __restrict__ pc4,
    ushort* __restrict__ pd1, ushort* __restrict__ pd2, ushort* __restrict__ pd3,
    ushort* __restrict__ pc1,
    float* __restrict__ siwT, float* __restrict__ DwT,
    float* __restrict__ prwT, float* __restrict__ powT) {
  int id = blockIdx.x * 256 + threadIdx.x;
  if (id < 32768)            pack_conv_elem(c2w, pc2, 64, 32, id);
  else if (id < 163840)      pack_conv_elem(c3w, pc3, 128, 64, id - 32768);
  else if (id < 688128)      pack_conv_elem(c4w, pc4, 256, 128, id - 163840);
  else if (id < 819200)      pack_deconv_elem(d1w, pd1, 64, 128, id - 688128);
  else if (id < 851968)      pack_deconv_elem(d2w, pd2, 32, 64, id - 819200);
  else if (id < 860160)      pack_deconv_elem(d3w, pd3, 16, 32, id - 851968);
  else if (id < 862208)      pack_conv1_elem(c1w, pc1, id - 860160);
  else if (id < 996352) {    // siwT [262][512]
    int r = id - 862208; int k = r >> 9, h = r & 511;
    siwT[r] = siw[(size_t)h * (LATENT + ACTD) + k];
  } else if (id < 1258496) { // DwT [512][512]
    int r = id - 996352; int k = r >> 9, h = r & 511;
    DwT[r] = Dw[(size_t)h * HIDD + k];
  } else if (id < 1520640) { // prwT [512][512]
    int r = id - 1258496; int k = r >> 9, h = r & 511;
    prwT[r] = prw[(size_t)h * HIDD + k];
  } else if (id < 2044928) { // powT [1024][512]
    int r = id - 1520640; int k = r >> 9, j = r & 511;
    powT[r] = pw[(size_t)j * 1024 + k];
  }
}

// ================= img -> [px][64b][4ci] bf16 (ci padded) =================
__global__ __launch_bounds__(256) void k_timg4(const float* __restrict__ img,
                                               ushort* __restrict__ timg4) {
  __shared__ float ts[3][64][65];
  int p0 = blockIdx.x << 6;
  int tid = threadIdx.x;
  #pragma unroll
  for (int c = 0; c < 3; ++c) {
    #pragma unroll
    for (int i = 0; i < 16; ++i) {
      int idx = tid + i * 256;
      int b = idx >> 6, pr = idx & 63;
      ts[c][pr][b] = img[((size_t)b * 3 + c) * 65536 + p0 + pr];
    }
  }
  __syncthreads();
  #pragma unroll
  for (int i = 0; i < 16; ++i) {
    int idx = tid + i * 256;
    int pr = idx >> 6, b = idx & 63;
    uint2 pk;
    pk.x = (unsigned)f2bf(ts[0][pr][b]) | ((unsigned)f2bf(ts[1][pr][b]) << 16);
    pk.y = (unsigned)f2bf(ts[2][pr][b]);
    *(uint2*)(timg4 + ((size_t)(p0 + pr) * 64 + b) * 4) = pk;
  }
}

// ================= conv1 MFMA: Cin=4(padded), one wave per output pixel =================
__global__ __launch_bounds__(256) void k_conv1_mfma(const ushort* __restrict__ in,
                                                    const ushort* __restrict__ wp,
                                                    const float* __restrict__ bias,
                                                    ushort* __restrict__ out) {
  int wid = __builtin_amdgcn_readfirstlane(blockIdx.x * 4 + (threadIdx.x >> 6));
  int lane = threadIdx.x & 63;
  int ox = wid & 127, oy = wid >> 7;
  int ml = lane & 15, khi = lane >> 4;
  f32x4 zero = {0.f, 0.f, 0.f, 0.f};
  f32x4 acc[2][4];
  #pragma unroll
  for (int mt = 0; mt < 2; ++mt)
    #pragma unroll
    for (int nt = 0; nt < 4; ++nt) acc[mt][nt] = zero;
  int by = 2 * oy - 1, bx = 2 * ox - 1;
  bool interior = (oy >= 1) & (oy <= 126) & (ox >= 1) & (ox <= 126);

  #pragma unroll
  for (int kc = 0; kc < 2; ++kc) {
    bf16x8 a0 = *(const bf16x8*)(wp + kc * 512 + lane * 8);
    bf16x8 a1 = *(const bf16x8*)(wp + 1024 + kc * 512 + lane * 8);
    int t0 = kc * 8 + khi * 2;
    int ky0 = t0 >> 2, kx0 = t0 & 3;
    int ky1 = (t0 + 1) >> 2, kx1 = (t0 + 1) & 3;
    int iy0 = by + ky0, ix0 = bx + kx0;
    int iy1 = by + ky1, ix1 = bx + kx1;
    const ushort* pA = in + ((size_t)(iy0 * 256 + ix0) * 64 + ml) * 4;
    const ushort* pB = in + ((size_t)(iy1 * 256 + ix1) * 64 + ml) * 4;
    if (interior) {
      #pragma unroll
      for (int nt = 0; nt < 4; ++nt) {
        uint2 lo = *(const uint2*)(pA + nt * 64);
        uint2 hi = *(const uint2*)(pB + nt * 64);
        uint4 u; u.x = lo.x; u.y = lo.y; u.z = hi.x; u.w = hi.y;
        bf16x8 bb = __builtin_bit_cast(bf16x8, u);
        acc[0][nt] = __builtin_amdgcn_mfma_f32_16x16x32_bf16(a0, bb, acc[0][nt], 0, 0, 0);
        acc[1][nt] = __builtin_amdgcn_mfma_f32_16x16x32_bf16(a1, bb, acc[1][nt], 0, 0, 0);
      }
    } else {
      bool ok0 = ((unsigned)iy0 < 256u) & ((unsigned)ix0 < 256u);
      bool ok1 = ((unsigned)iy1 < 256u) & ((unsigned)ix1 < 256u);
      #pragma unroll
      for (int nt = 0; nt < 4; ++nt) {
        uint2 z2; z2.x = 0u; z2.y = 0u;
        uint2 lo = ok0 ? *(const uint2*)(pA + nt * 64) : z2;
        uint2 hi = ok1 ? *(const uint2*)(pB + nt * 64) : z2;
        uint4 u; u.x = lo.x; u.y = lo.y; u.z = hi.x; u.w = hi.y;
        bf16x8 bb = __builtin_bit_cast(bf16x8, u);
        acc[0][nt] = __builtin_amdgcn_mfma_f32_16x16x32_bf16(a0, bb, acc[0][nt], 0, 0, 0);
        acc[1][nt] = __builtin_amdgcn_mfma_f32_16x16x32_bf16(a1, bb, acc[1][nt], 0, 0, 0);
      }
    }
  }
  int px = oy * 128 + ox;
  int rb = khi * 4;
  #pragma unroll
  for (int mt = 0; mt < 2; ++mt) {
    int co = mt * 16 + rb;
    f32x4 bv = *(const f32x4*)(bias + co);
    #pragma unroll
    for (int nt = 0; nt < 4; ++nt) {
      float v0 = fmaxf(acc[mt][nt][0] + bv[0], 0.f);
      float v1 = fmaxf(acc[mt][nt][1] + bv[1], 0.f);
      float v2 = fmaxf(acc[mt][nt][2] + bv[2], 0.f);
      float v3 = fmaxf(acc[mt][nt][3] + bv[3], 0.f);
      uint2 pk;
      pk.x = (unsigned)f2bf(v0) | ((unsigned)f2bf(v1) << 16);
      pk.y = (unsigned)f2bf(v2) | ((unsigned)f2bf(v3) << 16);
      size_t off = (size_t)px * 2048 + nt * 512 + ((co >> 3) & 3) * 128 + ml * 8 + (co & 7);
      *(uint2*)(out + off) = pk;
    }
  }
}

// ================= MFMA conv, interior fast path =================
template<int CIN, int COUT, int MT>
__global__ __launch_bounds__(256) void mfma_conv(const ushort* __restrict__ in,
                                                 const ushort* __restrict__ wp,
                                                 const float* __restrict__ bias,
                                                 ushort* __restrict__ out,
                                                 int Hin, int Win, int Hout, int Wout) {
  constexpr int NMG = COUT / (16 * MT);
  constexpr int NKC = CIN / 32;
  constexpr int NCH = 16 * NKC;
  int wid = __builtin_amdgcn_readfirstlane(blockIdx.x * 4 + (threadIdx.x >> 6));
  int lane = threadIdx.x & 63;
  int mg = wid % NMG;
  int px = wid / NMG;
  int ox = px % Wout, oy = px / Wout;
  if (oy >= Hout) return;
  int mtile0 = mg * MT;
  f32x4 zero = {0.f, 0.f, 0.f, 0.f};
  f32x4 acc[MT][4];
  #pragma unroll
  for (int mt = 0; mt < MT; ++mt)
    #pragma unroll
    for (int nt = 0; nt < 4; ++nt) acc[mt][nt] = zero;
  const ushort* wbase = wp + (size_t)mtile0 * NCH * 512 + lane * 8;
  const size_t mstride = (size_t)NCH * 512;
  bool interior = (oy >= 1) & (oy < Hout - 1) & (ox >= 1) & (ox < Wout - 1);

  if (interior) {
    #pragma unroll
    for (int ky = 0; ky < 4; ++ky) {
      int iy = 2 * oy - 1 + ky;
      #pragma unroll
      for (int kx = 0; kx < 4; ++kx) {
        int ix = 2 * ox - 1 + kx;
        const ushort* ib = in + (size_t)(iy * Win + ix) * (CIN * 64) + lane * 8;
        int tap = ky * 4 + kx;
        #pragma unroll
        for (int kc = 0; kc < NKC; ++kc) {
          int kcg = tap * NKC + kc;
          bf16x8 a[MT], bb[4];
          #pragma unroll
          for (int mt = 0; mt < MT; ++mt)
            a[mt] = *(const bf16x8*)(wbase + mt * mstride + (size_t)kcg * 512);
          #pragma unroll
          for (int nt = 0; nt < 4; ++nt)
            bb[nt] = *(const bf16x8*)(ib + kc * 2048 + nt * 512);
          #pragma unroll
          for (int mt = 0; mt < MT; ++mt)
            #pragma unroll
            for (int nt = 0; nt < 4; ++nt)
              acc[mt][nt] = __builtin_amdgcn_mfma_f32_16x16x32_bf16(a[mt], bb[nt], acc[mt][nt], 0, 0, 0);
        }
      }
    }
  } else {
    for (int ky = 0; ky < 4; ++ky) {
      int iy = 2 * oy - 1 + ky;
      if ((unsigned)iy >= (unsigned)Hin) continue;
      for (int kx = 0; kx < 4; ++kx) {
        int ix = 2 * ox - 1 + kx;
        if ((unsigned)ix >= (unsigned)Win) continue;
        const ushort* ib = in + (size_t)(iy * Win + ix) * (CIN * 64) + lane * 8;
        int tap = ky * 4 + kx;
        #pragma unroll
        for (int kc = 0; kc < NKC; ++kc) {
          int kcg = tap * NKC + kc;
          bf16x8 a[MT], bb[4];
          #pragma unroll
          for (int mt = 0; mt < MT; ++mt)
            a[mt] = *(const bf16x8*)(wbase + mt * mstride + (size_t)kcg * 512);
          #pragma unroll
          for (int nt = 0; nt < 4; ++nt)
            bb[nt] = *(const bf16x8*)(ib + kc * 2048 + nt * 512);
          #pragma unroll
          for (int mt = 0; mt < MT; ++mt)
            #pragma unroll
            for (int nt = 0; nt < 4; ++nt)
              acc[mt][nt] = __builtin_amdgcn_mfma_f32_16x16x32_bf16(a[mt], bb[nt], acc[mt][nt], 0, 0, 0);
        }
      }
    }
  }
  int ml = lane & 15, rb = (lane >> 4) * 4;
  #pragma unroll
  for (int mt = 0; mt < MT; ++mt) {
    int co = mtile0 * 16 + mt * 16 + rb;
    f32x4 bv = *(const f32x4*)(bias + co);
    #pragma unroll
    for (int nt = 0; nt < 4; ++nt) {
      float v0 = fmaxf(acc[mt][nt][0] + bv[0], 0.f);
      float v1 = fmaxf(acc[mt][nt][1] + bv[1], 0.f);
      float v2 = fmaxf(acc[mt][nt][2] + bv[2], 0.f);
      float v3 = fmaxf(acc[mt][nt][3] + bv[3], 0.f);
      uint2 pk;
      pk.x = (unsigned)f2bf(v0) | ((unsigned)f2bf(v1) << 16);
      pk.y = (unsigned)f2bf(v2) | ((unsigned)f2bf(v3) << 16);
      size_t off = (size_t)px * (COUT * 64) + (size_t)(co >> 5) * 2048 + nt * 512
                 + ((co >> 3) & 3) * 128 + ml * 8 + (co & 7);
      *(uint2*)(out + off) = pk;
    }
  }
}

// ================= MFMA transposed conv, interior fast path =================
template<int CIN, int COUT, int MT, bool RELU>
__global__ __launch_bounds__(256) void mfma_deconv(const ushort* __restrict__ in,
                                                   const ushort* __restrict__ wp,
                                                   const float* __restrict__ bias,
                                                   ushort* __restrict__ out,
                                                   int Hin, int Win, int Hout, int Wout) {
  constexpr int NMG = COUT / (16 * MT);
  constexpr int NKC = CIN / 32;
  constexpr int NCH = 4 * NKC;
  constexpr int NTS = (COUT >= 32) ? 512 : (COUT * 16);
  int wid = __builtin_amdgcn_readfirstlane(blockIdx.x * 4 + (threadIdx.x >> 6));
  int lane = threadIdx.x & 63;
  int mg = wid % NMG; int r1 = wid / NMG;
  int wo2 = Wout >> 1;
  int pc = (Hout >> 1) * wo2;
  int pxc = r1 % pc; int cls = r1 / pc;
  if (cls >= 4) return;
  int p0 = cls >> 1, q0 = cls & 1;
  int tx = pxc % wo2, ty = pxc / wo2;
  int oy = 2 * ty + 1 - p0, ox = 2 * tx + 1 - q0;
  int iy0 = (oy + 1 - p0) >> 1, ix0 = (ox + 1 - q0) >> 1;
  int mtile0 = mg * MT;
  f32x4 zero = {0.f, 0.f, 0.f, 0.f};
  f32x4 acc[MT][4];
  #pragma unroll
  for (int mt = 0; mt < MT; ++mt)
    #pragma unroll
    for (int nt = 0; nt < 4; ++nt) acc[mt][nt] = zero;
  const ushort* wbase = wp + ((size_t)cls * (COUT / 16) + mtile0) * NCH * 512 + lane * 8;
  const size_t mstride = (size_t)NCH * 512;
  bool interior = (iy0 >= 1) & (iy0 <= Hin - 1) & (ix0 >= 1) & (ix0 <= Win - 1);

  if (interior) {
    #pragma unroll
    for (int i = 0; i < 2; ++i) {
      int iy = iy0 - i;
      #pragma unroll
      for (int j = 0; j < 2; ++j) {
        int ix = ix0 - j;
        const ushort* ib = in + (size_t)(iy * Win + ix) * (CIN * 64) + lane * 8;
        int tap = i * 2 + j;
        #pragma unroll
        for (int kc = 0; kc < NKC; ++kc) {
          int kcg = tap * NKC + kc;
          bf16x8 a[MT], bb[4];
          #pragma unroll
          for (int mt = 0; mt < MT; ++mt)
            a[mt] = *(const bf16x8*)(wbase + mt * mstride + (size_t)kcg * 512);
          #pragma unroll
          for (int nt = 0; nt < 4; ++nt)
            bb[nt] = *(const bf16x8*)(ib + kc * 2048 + nt * 512);
          #pragma unroll
          for (int mt = 0; mt < MT; ++mt)
            #pragma unroll
            for (int nt = 0; nt < 4; ++nt)
              acc[mt][nt] = __builtin_amdgcn_mfma_f32_16x16x32_bf16(a[mt], bb[nt], acc[mt][nt], 0, 0, 0);
        }
      }
    }
  } else {
    for (int i = 0; i < 2; ++i) {
      int iy = iy0 - i;
      if ((unsigned)iy >= (unsigned)Hin) continue;
      for (int j = 0; j < 2; ++j) {
        int ix = ix0 - j;
        if ((unsigned)ix >= (unsigned)Win) continue;
        const ushort* ib = in + (size_t)(iy * Win + ix) * (CIN * 64) + lane * 8;
        int tap = i * 2 + j;
        #pragma unroll
        for (int kc = 0; kc < NKC; ++kc) {
          int kcg = tap * NKC + kc;
          bf16x8 a[MT], bb[4];
          #pragma unroll
          for (int mt = 0; mt < MT; ++mt)
            a[mt] = *(const bf16x8*)(wbase + mt * mstride + (size_t)kcg * 512);
          #pragma unroll
          for (int nt = 0; nt < 4; ++nt)
            bb[nt] = *(const bf16x8*)(ib + kc * 2048 + nt * 512);
          #pragma unroll
          for (int mt = 0; mt < MT; ++mt)
            #pragma unroll
            for (int nt = 0; nt < 4; ++nt)
              acc[mt][nt] = __builtin_amdgcn_mfma_f32_16x16x32_bf16(a[mt], bb[nt], acc[mt][nt], 0, 0, 0);
        }
      }
    }
  }
  int ml = lane & 15, rb = (lane >> 4) * 4;
  int px = oy * Wout + ox;
  #pragma unroll
  for (int mt = 0; mt < MT; ++mt) {
    int co = mtile0 * 16 + mt * 16 + rb;
    f32x4 bv = *(const f32x4*)(bias + co);
    #pragma unroll
    for (int nt = 0; nt < 4; ++nt) {
      float v0 = acc[mt][nt][0] + bv[0];
      float v1 = acc[mt][nt][1] + bv[1];
      float v2 = acc[mt][nt][2] + bv[2];
      float v3 = acc[mt][nt][3] + bv[3];
      if (RELU) { v0=fmaxf(v0,0.f); v1=fmaxf(v1,0.f); v2=fmaxf(v2,0.f); v3=fmaxf(v3,0.f); }
      uint2 pk;
      pk.x = (unsigned)f2bf(v0) | ((unsigned)f2bf(v1) << 16);
      pk.y = (unsigned)f2bf(v2) | ((unsigned)f2bf(v3) << 16);
      size_t off = (size_t)px * (COUT * 64) + (size_t)(co >> 5) * 2048 + (size_t)nt * NTS
                 + ((co >> 3) & 3) * 128 + ml * 8 + (co & 7);
      *(uint2*)(out + off) = pk;
    }
  }
}

// ================= enc_fc fused: LDS-transpose staging + MFMA =================
#define APXS 1032
__global__ __launch_bounds__(256) void k_encfc_fused(const ushort* __restrict__ h4,
                                                     const float* __restrict__ wE,
                                                     float* __restrict__ partial) {
  __shared__ float smem[8320];
  ushort* au = (ushort*)smem;
  int s = blockIdx.x;
  int bid = (s & 7) * 256 + (s >> 3);
  int mg = bid & 15;
  int ccf = (bid >> 4) & 7;
  int pxg = bid >> 7;
  int tid = threadIdx.x;
  int co0 = mg * 32;
  #pragma unroll 4
  for (int i = 0; i < 64; ++i) {
    int idx = tid + i * 256;
    int px_l = idx & 15;
    int ci_l = (idx >> 4) & 31;
    int co_l = idx >> 9;
    float v = wE[((size_t)(co0 + co_l) << 16) + (size_t)(ccf * 32 + ci_l) * 256 + pxg * 16 + px_l];
    int mt = co_l >> 4, m = co_l & 15;
    int kg = ci_l >> 3, k8 = ci_l & 7;
    au[px_l * APXS + mt * 512 + kg * 128 + m * 8 + k8] = f2bf(v);
  }
  __syncthreads();
  int lane = tid & 63, wv = tid >> 6;
  int ml = lane & 15, rb = (lane >> 4) * 4;
  f32x4 zero = {0.f, 0.f, 0.f, 0.f};
  f32x4 acc[2][4];
  #pragma unroll
  for (int mt = 0; mt < 2; ++mt)
    #pragma unroll
    for (int nt = 0; nt < 4; ++nt) acc[mt][nt] = zero;
  #pragma unroll
  for (int jj = 0; jj < 4; ++jj) {
    int j = wv * 4 + jj;
    int px = pxg * 16 + j;
    bf16x8 a0 = *(const bf16x8*)(au + j * APXS + lane * 8);
    bf16x8 a1 = *(const bf16x8*)(au + j * APXS + 512 + lane * 8);
    const ushort* hb = h4 + (size_t)px * 16384 + ccf * 2048 + lane * 8;
    bf16x8 bb[4];
    #pragma unroll
    for (int nt = 0; nt < 4; ++nt)
      bb[nt] = *(const bf16x8*)(hb + nt * 512);
    #pragma unroll
    for (int nt = 0; nt < 4; ++nt) {
      acc[0][nt] = __builtin_amdgcn_mfma_f32_16x16x32_bf16(a0, bb[nt], acc[0][nt], 0, 0, 0);
      acc[1][nt] = __builtin_amdgcn_mfma_f32_16x16x32_bf16(a1, bb[nt], acc[1][nt], 0, 0, 0);
    }
  }
  __syncthreads();
  #pragma unroll
  for (int mt = 0; mt < 2; ++mt)
    #pragma unroll
    for (int nt = 0; nt < 4; ++nt)
      #pragma unroll
      for (int r = 0; r < 4; ++r)
        smem[wv * 2080 + (mt * 16 + rb + r) * 65 + nt * 16 + ml] = acc[mt][nt][r];
  __syncthreads();
  int ks = pxg * 8 + ccf;
  #pragma unroll
  for (int i = 0; i < 8; ++i) {
    int e = tid + i * 256;
    int b = e & 63, co_l = e >> 6;
    float sum = smem[co_l * 65 + b] + smem[2080 + co_l * 65 + b]
              + smem[4160 + co_l * 65 + b] + smem[6240 + co_l * 65 + b];
    partial[((size_t)(co0 + co_l) * ENC_KS + ks) * 64 + b] = sum;
  }
}

__global__ void k_encfc_red(const float* __restrict__ partial, const float* __restrict__ bias,
                            float* __restrict__ cnn) {
  int id = blockIdx.x * blockDim.x + threadIdx.x;
  int o = id >> 6, b = id & 63;
  float acc = bias[o];
  #pragma unroll 8
  for (int s = 0; s < ENC_KS; ++s) acc += partial[((size_t)o * ENC_KS + s) * 64 + b];
  cnn[(size_t)b * 512 + o] = fmaxf(acc, 0.f);
}

// ================= fused posterior + reparam (coalesced powT) =================
__global__ __launch_bounds__(512) void k_postz(const float* __restrict__ cnn,
                                               const float* __restrict__ belief,
                                               const float* __restrict__ powT,
                                               const float* __restrict__ bias,
                                               const float* __restrict__ eps,
                                               float* __restrict__ out,
                                               ushort* __restrict__ zb) {
  __shared__ float cs[512];
  __shared__ float bs[512];
  __shared__ float sm[512];
  int b = blockIdx.x;
  int j = threadIdx.x;
  cs[j] = cnn[(size_t)b * HIDD + j];
  bs[j] = belief[(size_t)b * HIDD + j];
  __syncthreads();
  float acc = bias[j];
  #pragma unroll 8
  for (int k = 0; k < HIDD; ++k) acc += cs[k] * powT[(size_t)k * 512 + j];
  #pragma unroll 8
  for (int k = 0; k < HIDD; ++k) acc += bs[k] * powT[(size_t)(512 + k) * 512 + j];
  sm[j] = acc;
  if (j < 256) out[O_MUPO + b * 256 + j] = acc;
  else         out[O_LVPO + b * 256 + (j - 256)] = acc;
  __syncthreads();
  if (j < 256) {
    float z = sm[j] + eps[b * 256 + j] * expf(0.5f * sm[j + 256]);
    out[O_ZT + b * 256 + j] = z;
    if (j < 128) zb[b * 128 + j] = f2bf(z);
  }
}

// ================= dec_fc MFMA: direct f32 weights, frag-order out =================
__global__ __launch_bounds__(256) void k_decfc_mfma(const ushort* __restrict__ zb,
                                                    const float* __restrict__ dfw,
                                                    const float* __restrict__ dfb,
                                                    ushort* __restrict__ dec) {
  int wid = __builtin_amdgcn_readfirstlane(blockIdx.x * 4 + (threadIdx.x >> 6));
  int lane = threadIdx.x & 63;
  int m0 = wid * 32;
  int ml = lane & 15, kl = (lane >> 4) * 8;
  f32x4 zero = {0.f, 0.f, 0.f, 0.f};
  f32x4 acc[2][4];
  #pragma unroll
  for (int mt = 0; mt < 2; ++mt)
    #pragma unroll
    for (int nt = 0; nt < 4; ++nt) acc[mt][nt] = zero;
  #pragma unroll
  for (int kc = 0; kc < 4; ++kc) {
    bf16x8 a[2], bb[4];
    #pragma unroll
    for (int mt = 0; mt < 2; ++mt) {
      int m_r = m0 + mt * 16 + ml;
      const float* wr = dfw + (size_t)((m_r & 127) * 256 + (m_r >> 7)) * 128 + kc * 32 + kl;
      float4 u0 = *(const float4*)wr;
      float4 u1 = *(const float4*)(wr + 4);
      bf16x8 av;
      av[0] = (short)f2bf(u0.x); av[1] = (short)f2bf(u0.y);
      av[2] = (short)f2bf(u0.z); av[3] = (short)f2bf(u0.w);
      av[4] = (short)f2bf(u1.x); av[5] = (short)f2bf(u1.y);
      av[6] = (short)f2bf(u1.z); av[7] = (short)f2bf(u1.w);
      a[mt] = av;
    }
    #pragma unroll
    for (int nt = 0; nt < 4; ++nt)
      bb[nt] = *(const bf16x8*)(zb + (size_t)(nt * 16 + ml) * 128 + kc * 32 + kl);
    #pragma unroll
    for (int mt = 0; mt < 2; ++mt)
      #pragma unroll
      for (int nt = 0; nt < 4; ++nt)
        acc[mt][nt] = __builtin_amdgcn_mfma_f32_16x16x32_bf16(a[mt], bb[nt], acc[mt][nt], 0, 0, 0);
  }
  int rb = (lane >> 4) * 4;
  #pragma unroll
  for (int mt = 0; mt < 2; ++mt) {
    int m = m0 + mt * 16 + rb;
    int pix = m >> 7, co = m & 127;
    float bv0 = dfb[(size_t)(co + 0) * 256 + pix];
    float bv1 = dfb[(size_t)(co + 1) * 256 + pix];
    float bv2 = dfb[(size_t)(co + 2) * 256 + pix];
    float bv3 = dfb[(size_t)(co + 3) * 256 + pix];
    #pragma unroll
    for (int nt = 0; nt < 4; ++nt) {
      uint2 pk;
      pk.x = (unsigned)f2bf(acc[mt][nt][0] + bv0) | ((unsigned)f2bf(acc[mt][nt][1] + bv1) << 16);
      pk.y = (unsigned)f2bf(acc[mt][nt][2] + bv2) | ((unsigned)f2bf(acc[mt][nt][3] + bv3) << 16);
      size_t off = (size_t)pix * 8192 + (size_t)(co >> 5) * 2048 + nt * 512
                 + ((co >> 3) & 3) * 128 + ml * 8 + (co & 7);
      *(uint2*)(dec + off) = pk;
    }
  }
}

// ================= d4 fused with output transpose =================
__global__ __launch_bounds__(256) void k_d4t(const ushort* __restrict__ in,
                                             const float* __restrict__ w,
                                             const float* __restrict__ bias,
                                             float* __restrict__ out) {
  __shared__ float lds[64][65];
  int blk = blockIdx.x;
  int oy = blk >> 2, ox0 = (blk & 3) << 6;
  int t = threadIdx.x;
  int b = t & 63, sub = t >> 6;
  float bv = bias[0];
  for (int j = 0; j < 16; ++j) {
    int oxl = j * 4 + sub;
    int ox = ox0 + oxl;
    int p0 = (oy + 1) & 1, q0 = (ox + 1) & 1;
    int iy0 = (oy + 1 - p0) >> 1, ix0 = (ox + 1 - q0) >> 1;
    float acc = bv;
    #pragma unroll
    for (int i = 0; i < 2; ++i) {
      int iy = iy0 - i;
      if ((unsigned)iy >= 128u) continue;
      int p = p0 + 2 * i;
      #pragma unroll
      for (int jj = 0; jj < 2; ++jj) {
        int ix = ix0 - jj;
        if ((unsigned)ix >= 128u) continue;
        int q = q0 + 2 * jj;
        const ushort* base = in + (size_t)(iy * 128 + ix) * 1024 + (b >> 4) * 256 + (b & 15) * 8;
        bf16x8 v0 = *(const bf16x8*)(base);
        bf16x8 v1 = *(const bf16x8*)(base + 128);
        const float* wq = w + p * 4 + q;
        #pragma unroll
        for (int ci = 0; ci < 8; ++ci) acc += bf2f((ushort)v0[ci]) * wq[ci * 16];
        #pragma unroll
        for (int ci = 0; ci < 8; ++ci) acc += bf2f((ushort)v1[ci]) * wq[(ci + 8) * 16];
      }
    }
    lds[oxl][b] = acc;
  }
  __syncthreads();
  #pragma unroll
  for (int j = 0; j < 16; ++j) {
    int idx = t + j * 256;
    int b2 = idx >> 6, oxl = idx & 63;
    out[(size_t)b2 * 65536 + oy * 256 + ox0 + oxl] = lds[oxl][b2];
  }
}

// ================= launch =================

extern "C" void kernel_launch(void* const* d_in, const int* in_sizes, int n_in,
                              void* d_out, int out_size, void* d_ws, size_t ws_size,
                              hipStream_t stream) {
  const float* img      = (const float*)d_in[0];
  const float* act      = (const float*)d_in[1];
  const float* z_prev   = (const float*)d_in[2];
  const float* st_prev  = (const float*)d_in[3];
  const float* eps      = (const float*)d_in[4];
  const float* c1w = (const float*)d_in[5];  const float* c1b = (const float*)d_in[6];
  const float* c2w = (const float*)d_in[7];  const float* c2b = (const float*)d_in[8];
  const float* c3w = (const float*)d_in[9];  const float* c3b = (const float*)d_in[10];
  const float* c4w = (const float*)d_in[11]; const float* c4b = (const float*)d_in[12];
  const float* efw = (const float*)d_in[13]; const float* efb = (const float*)d_in[14];
  const float* pow_ = (const float*)d_in[15]; const float* pob = (const float*)d_in[16];
  const float* prw = (const float*)d_in[17]; const float* prb = (const float*)d_in[18];
  const float* siw = (const float*)d_in[19]; const float* sib = (const float*)d_in[20];
  const float* Alog = (const float*)d_in[21];
  const float* Bw = (const float*)d_in[22];  const float* Cw = (const float*)d_in[23];
  const float* Dw = (const float*)d_in[24];  const float* Db = (const float*)d_in[25];
  const float* Dv = (const float*)d_in[26];
  const float* dfw = (const float*)d_in[27]; const float* dfb = (const float*)d_in[28];
  const float* d1w = (const float*)d_in[29]; const float* d1b = (const float*)d_in[30];
  const float* d2w = (const float*)d_in[31]; const float* d2b = (const float*)d_in[32];
  const float* d3w = (const float*)d_in[33]; const float* d3b = (const float*)d_in[34];
  const float* d4w = (const float*)d_in[35]; const float* d4b = (const float*)d_in[36];

  float* ws = (float*)d_ws;
  float* out = (float*)d_out;

  ushort* pc2 = (ushort*)(ws + PW_C2);
  ushort* pc3 = (ushort*)(ws + PW_C3);
  ushort* pc4 = (ushort*)(ws + PW_C4);
  ushort* pd1 = (ushort*)(ws + PW_D1);
  ushort* pd2 = (ushort*)(ws + PW_D2);
  ushort* pd3 = (ushort*)(ws + PW_D3);
  ushort* pc1 = (ushort*)(ws + PW_C1);
  ushort* timg4 = (ushort*)(ws + W_TIMG);
  ushort* h1b = (ushort*)(ws + W_H1B);
  ushort* h2b = (ushort*)(ws + W_H2B);
  ushort* h3b = (ushort*)(ws + W_H3B);
  ushort* h4b = (ushort*)(ws + W_H4B);
  ushort* deco = (ushort*)(ws + W_DECO);
  ushort* d1o = (ushort*)(ws + W_D1O);
  ushort* d2o = (ushort*)(ws + W_D2O);
  ushort* d3o = (ushort*)(ws + W_D3O);
  ushort* zb = (ushort*)(ws + W_ZB16);
  float* siwT = ws + W_SIWT;
  float* DwT  = ws + W_DWT;
  float* prwT = ws + W_PRWT;
  float* powT = ws + W_POWT;

  // ---- merged weight prepack (+ conv1 pack + dense transposes) ----
  k_pack_all<<<7988, 256, 0, stream>>>(c2w, c3w, c4w, d1w, d2w, d3w, c1w,
                                       siw, Dw, prw, pow_,
                                       pc2, pc3, pc4, pd1, pd2, pd3, pc1,
                                       siwT, DwT, prwT, powT);

  // ---- fused SSM chain (coalesced) ----
  k_ssm_all<<<64, 512, 0, stream>>>(z_prev, act, siwT, sib, DwT, Db, Bw, Cw,
                                    Alog, Dv, st_prev, out + O_STATE,
                                    ws + W_BELIEF, prwT, prb, out);

  // ---- encoder ----
  k_timg4<<<1024, 256, 0, stream>>>(img, timg4);
  k_conv1_mfma<<<4096, 256, 0, stream>>>(timg4, pc1, c1b, h1b);
  mfma_conv<32, 64, 4><<<1024, 256, 0, stream>>>(h1b, pc2, c2b, h2b, 128, 128, 64, 64);
  mfma_conv<64, 128, 4><<<512, 256, 0, stream>>>(h2b, pc3, c3b, h3b, 64, 64, 32, 32);
  mfma_conv<128, 256, 2><<<512, 256, 0, stream>>>(h3b, pc4, c4b, h4b, 32, 32, 16, 16);

  // ---- enc_fc (fused transpose+GEMM) ----
  k_encfc_fused<<<2048, 256, 0, stream>>>(h4b, efw, ws + W_ENCP);
  k_encfc_red<<<128, 256, 0, stream>>>(ws + W_ENCP, efb, ws + W_CNN);

  // ---- fused posterior + reparam ----
  k_postz<<<64, 512, 0, stream>>>(ws + W_CNN, ws + W_BELIEF, powT, pob, eps, out, zb);

  // ---- decoder ----
  k_decfc_mfma<<<256, 256, 0, stream>>>(zb, dfw, dfb, deco);
  mfma_deconv<128, 64, 2, true><<<512, 256, 0, stream>>>(deco, pd1, d1b, d1o, 16, 16, 32, 32);
  mfma_deconv<64, 32, 2, true><<<1024, 256, 0, stream>>>(d1o, pd2, d2b, d2o, 32, 32, 64, 64);
  mfma_deconv<32, 16, 1, true><<<4096, 256, 0, stream>>>(d2o, pd3, d3b, d3o, 64, 64, 128, 128);
  k_d4t<<<1024, 256, 0, stream>>>(d3o, d4w, d4b, out + O_PRED);
}

// Round 14
// 435.394 us; speedup vs baseline: 1.0275x; 1.0275x over previous
//
#include <hip/hip_runtime.h>
#include <math.h>

#define BB 64
#define LATENT 256
#define ACTD 6
#define HIDD 512
#define DST 16

typedef __attribute__((ext_vector_type(8))) short bf16x8;
typedef __attribute__((ext_vector_type(4))) float f32x4;

static __device__ __forceinline__ ushort f2bf(float f) {
  unsigned u = __builtin_bit_cast(unsigned, f);
  unsigned r = (u + 0x7FFFu + ((u >> 16) & 1u)) >> 16;
  return (ushort)r;
}
static __device__ __forceinline__ float bf2f(ushort u) {
  return __builtin_bit_cast(float, ((unsigned)u) << 16);
}

// ---------------- output offsets (floats) ----------------
#define O_PRED   0
#define O_ZT     4194304
#define O_STATE  4210688
#define O_MUP    4734976
#define O_LVP    4751360
#define O_MUPO   4767744
#define O_LVPO   4784128

// ---------------- ws offsets (floats), lifetime-reused ----------------
#define W_BELIEF 67584u
#define W_CNN    100352u
#define W_ZB16   133120u
#define PW_C2    137216u
#define PW_C3    153600u
#define PW_C4    219136u
#define PW_D1    481280u
#define PW_D2    546816u
#define PW_D3    563200u
#define PW_C1    567296u
#define W_TIMG   602112u      // timg4 bf16 [65536][64][4]
#define W_H1B    13185024u
#define W_H2B    29962240u
#define W_H3B    38350848u
#define W_H4B    42545152u
#define W_SIWT   44642304u
#define W_DWT    44776448u
#define W_PRWT   45038592u
#define W_POWT   45300736u
// reuse:
#define W_ENCP   602112u
#define W_DECO   8990720u
#define W_D1O    10039296u
#define W_D2O    13185024u
#define W_D3O    17379328u

#define ENC_KS 128

// ================= merged weight prepack =================

static __device__ __forceinline__ void pack_conv_elem(const float* __restrict__ w,
                                                      ushort* __restrict__ o,
                                                      int Cout, int Cin, int id) {
  int NCH = Cin / 2;
  int per = NCH * 512;
  int mt = id / per, r = id % per;
  int kcg = r >> 9, s = r & 511;
  int kg = s >> 7, m = (s >> 3) & 15, k8 = s & 7;
  int co = mt * 16 + m;
  int k = kcg * 32 + kg * 8 + k8;
  int tap = k / Cin, ci = k % Cin;
  o[id] = f2bf(w[(size_t)(co * Cin + ci) * 16 + tap]);
}

static __device__ __forceinline__ void pack_deconv_elem(const float* __restrict__ w,
                                                        ushort* __restrict__ o,
                                                        int Cout, int Cin, int id) {
  int NCH = Cin / 8;
  int perM = NCH * 512;
  int perC = (Cout / 16) * perM;
  int cls = id / perC, r = id % perC;
  int mt = r / perM, r2 = r % perM;
  int kcg = r2 >> 9, s = r2 & 511;
  int kg = s >> 7, m = (s >> 3) & 15, k8 = s & 7;
  int co = mt * 16 + m;
  int k = kcg * 32 + kg * 8 + k8;
  int t = k / Cin, ci = k % Cin;
  int p = (cls >> 1) + 2 * (t >> 1);
  int q = (cls & 1) + 2 * (t & 1);
  o[id] = f2bf(w[(size_t)(ci * Cout + co) * 16 + p * 4 + q]);
}

static __device__ __forceinline__ void pack_conv1_elem(const float* __restrict__ w,
                                                       ushort* __restrict__ o, int id) {
  int mt = id >> 10, r = id & 1023;
  int kcg = r >> 9, s = r & 511;
  int kg = s >> 7, m = (s >> 3) & 15, k8 = s & 7;
  int co = mt * 16 + m;
  int k = kcg * 32 + kg * 8 + k8;
  int tap = k >> 2, ci = k & 3;
  o[id] = (ci < 3) ? f2bf(w[(size_t)(co * 3 + ci) * 16 + tap]) : (ushort)0;
}

__global__ __launch_bounds__(256) void k_pack_all(
    const float* __restrict__ c2w, const float* __restrict__ c3w,
    const float* __restrict__ c4w, const float* __restrict__ d1w,
    const float* __restrict__ d2w, const float* __restrict__ d3w,
    const float* __restrict__ c1w,
    const float* __restrict__ siw, const float* __restrict__ Dw,
    const float* __restrict__ prw, const float* __restrict__ pw,
    ushort* __restrict__ pc2, ushort* __restrict__ pc3, ushort* __restrict__ pc4,
    ushort* __restrict__ pd1, ushort* __restrict__ pd2, ushort* __restrict__ pd3,
    ushort* __restrict__ pc1,
    float* __restrict__ siwT, float* __restrict__ DwT,
    float* __restrict__ prwT, float* __restrict__ powT) {
  int id = blockIdx.x * 256 + threadIdx.x;
  if (id < 32768)            pack_conv_elem(c2w, pc2, 64, 32, id);
  else if (id < 163840)      pack_conv_elem(c3w, pc3, 128, 64, id - 32768);
  else if (id < 688128)      pack_conv_elem(c4w, pc4, 256, 128, id - 163840);
  else if (id < 819200)      pack_deconv_elem(d1w, pd1, 64, 128, id - 688128);
  else if (id < 851968)      pack_deconv_elem(d2w, pd2, 32, 64, id - 819200);
  else if (id < 860160)      pack_deconv_elem(d3w, pd3, 16, 32, id - 851968);
  else if (id < 862208)      pack_conv1_elem(c1w, pc1, id - 860160);
  else if (id < 996352) {    // siwT [262][512]
    int r = id - 862208; int k = r >> 9, h = r & 511;
    siwT[r] = siw[(size_t)h * (LATENT + ACTD) + k];
  } else if (id < 1258496) { // DwT [512][512]
    int r = id - 996352; int k = r >> 9, h = r & 511;
    DwT[r] = Dw[(size_t)h * HIDD + k];
  } else if (id < 1520640) { // prwT [512][512]
    int r = id - 1258496; int k = r >> 9, h = r & 511;
    prwT[r] = prw[(size_t)h * HIDD + k];
  } else if (id < 2044928) { // powT [1024][512]
    int r = id - 1520640; int k = r >> 9, j = r & 511;
    powT[r] = pw[(size_t)j * 1024 + k];
  }
}

// ================= merged SSM (blocks 0..63) + img transpose (blocks 64..1087) =================
// BOTH branches depend only on k_pack_all / inputs; they are mutually independent.
__global__ __launch_bounds__(512) void k_ssm_timg(
    const float* __restrict__ z_prev, const float* __restrict__ act,
    const float* __restrict__ siwT, const float* __restrict__ sib,
    const float* __restrict__ DwT, const float* __restrict__ Db,
    const float* __restrict__ Bw, const float* __restrict__ Cw,
    const float* __restrict__ Alog, const float* __restrict__ Dv,
    const float* __restrict__ st_prev, float* __restrict__ state_out,
    float* __restrict__ belief_out, const float* __restrict__ prwT,
    const float* __restrict__ prb, float* __restrict__ out,
    const float* __restrict__ img, ushort* __restrict__ timg4) {
  __shared__ float sm[12480];              // 50 KB arena, unioned across branches
  int blk = blockIdx.x;
  int tid = threadIdx.x;

  if (blk < 64) {
    // ---------- SSM chain, one block per batch ----------
    float* zs   = sm;            // 256
    float* as_  = sm + 256;      // 8
    float* si   = sm + 264;      // 512
    float* bel  = sm + 776;      // 512
    float* part = sm + 1288;     // 128
    float* btct = sm + 1416;     // 32
    int b = blk;
    int h = tid;
    if (h < 256) zs[h] = z_prev[(size_t)b * LATENT + h];
    if (h >= 256 && h < 256 + ACTD) as_[h - 256] = act[(size_t)b * ACTD + (h - 256)];
    __syncthreads();
    {
      float acc = sib[h];
      #pragma unroll 8
      for (int k = 0; k < LATENT; ++k) acc += zs[k] * siwT[(size_t)k * 512 + h];
      #pragma unroll
      for (int k = 0; k < ACTD; ++k) acc += as_[k] * siwT[(size_t)(LATENT + k) * 512 + h];
      si[h] = acc / (1.f + expf(-acc));
    }
    __syncthreads();
    float d;
    {
      float acc = Db[h];
      #pragma unroll 8
      for (int k = 0; k < HIDD; ++k) acc += si[k] * DwT[(size_t)k * 512 + h];
      d = fmaxf(acc, 0.f) + log1pf(expf(-fabsf(acc)));
    }
    if (h < 128) {
      int half = h >> 6;
      int l = h & 63;
      int n = l & 15, p = l >> 4;
      const float* wr = (half ? Cw : Bw) + (size_t)n * HIDD + p * 128;
      const float* sr = si + p * 128;
      float acc = 0.f;
      #pragma unroll 4
      for (int k = 0; k < 128; k += 4) {
        float4 w4 = *(const float4*)(wr + k);
        acc += sr[k] * w4.x + sr[k+1] * w4.y + sr[k+2] * w4.z + sr[k+3] * w4.w;
      }
      part[(half * 16 + n) * 4 + p] = acc;
    }
    __syncthreads();
    if (h < 32) {
      int half = h >> 4, n = h & 15;
      const float* pp = part + (half * 16 + n) * 4;
      btct[half * 16 + n] = pp[0] + pp[1] + pp[2] + pp[3];
    }
    __syncthreads();
    {
      float si_h = si[h];
      float belv = Dv[h] * si_h;
      const float* al = Alog + (size_t)h * DST;
      const float* sp = st_prev + ((size_t)b * 512 + h) * DST;
      float* so = state_out + ((size_t)b * 512 + h) * DST;
      #pragma unroll
      for (int n = 0; n < DST; ++n) {
        float A = -expf(al[n]);
        float st = expf(d * A) * sp[n] + d * btct[n] * si_h;
        so[n] = st;
        belv += st * btct[16 + n];
      }
      bel[h] = belv;
      belief_out[(size_t)b * 512 + h] = belv;
    }
    __syncthreads();
    {
      float acc = prb[h];
      #pragma unroll 8
      for (int k = 0; k < HIDD; ++k) acc += bel[k] * prwT[(size_t)k * 512 + h];
      if (h < 256) out[O_MUP + b * 256 + h] = acc;
      else         out[O_LVP + b * 256 + (h - 256)] = acc;
    }
  } else {
    // ---------- img -> [px][64b][4ci] bf16 (ci padded) ----------
    float (*ts)[64][65] = (float (*)[64][65])sm;
    int p0 = (blk - 64) << 6;
    #pragma unroll
    for (int c = 0; c < 3; ++c) {
      #pragma unroll
      for (int i = 0; i < 8; ++i) {
        int idx = tid + i * 512;
        int b = idx >> 6, pr = idx & 63;
        ts[c][pr][b] = img[((size_t)b * 3 + c) * 65536 + p0 + pr];
      }
    }
    __syncthreads();
    #pragma unroll
    for (int i = 0; i < 8; ++i) {
      int idx = tid + i * 512;
      int pr = idx >> 6, b = idx & 63;
      uint2 pk;
      pk.x = (unsigned)f2bf(ts[0][pr][b]) | ((unsigned)f2bf(ts[1][pr][b]) << 16);
      pk.y = (unsigned)f2bf(ts[2][pr][b]);
      *(uint2*)(timg4 + ((size_t)(p0 + pr) * 64 + b) * 4) = pk;
    }
  }
}

// ================= conv1 MFMA: Cin=4(padded), one wave per output pixel =================
__global__ __launch_bounds__(256) void k_conv1_mfma(const ushort* __restrict__ in,
                                                    const ushort* __restrict__ wp,
                                                    const float* __restrict__ bias,
                                                    ushort* __restrict__ out) {
  int wid = __builtin_amdgcn_readfirstlane(blockIdx.x * 4 + (threadIdx.x >> 6));
  int lane = threadIdx.x & 63;
  int ox = wid & 127, oy = wid >> 7;
  int ml = lane & 15, khi = lane >> 4;
  f32x4 zero = {0.f, 0.f, 0.f, 0.f};
  f32x4 acc[2][4];
  #pragma unroll
  for (int mt = 0; mt < 2; ++mt)
    #pragma unroll
    for (int nt = 0; nt < 4; ++nt) acc[mt][nt] = zero;
  int by = 2 * oy - 1, bx = 2 * ox - 1;
  bool interior = (oy >= 1) & (oy <= 126) & (ox >= 1) & (ox <= 126);

  #pragma unroll
  for (int kc = 0; kc < 2; ++kc) {
    bf16x8 a0 = *(const bf16x8*)(wp + kc * 512 + lane * 8);
    bf16x8 a1 = *(const bf16x8*)(wp + 1024 + kc * 512 + lane * 8);
    int t0 = kc * 8 + khi * 2;
    int ky0 = t0 >> 2, kx0 = t0 & 3;
    int ky1 = (t0 + 1) >> 2, kx1 = (t0 + 1) & 3;
    int iy0 = by + ky0, ix0 = bx + kx0;
    int iy1 = by + ky1, ix1 = bx + kx1;
    const ushort* pA = in + ((size_t)(iy0 * 256 + ix0) * 64 + ml) * 4;
    const ushort* pB = in + ((size_t)(iy1 * 256 + ix1) * 64 + ml) * 4;
    if (interior) {
      #pragma unroll
      for (int nt = 0; nt < 4; ++nt) {
        uint2 lo = *(const uint2*)(pA + nt * 64);
        uint2 hi = *(const uint2*)(pB + nt * 64);
        uint4 u; u.x = lo.x; u.y = lo.y; u.z = hi.x; u.w = hi.y;
        bf16x8 bb = __builtin_bit_cast(bf16x8, u);
        acc[0][nt] = __builtin_amdgcn_mfma_f32_16x16x32_bf16(a0, bb, acc[0][nt], 0, 0, 0);
        acc[1][nt] = __builtin_amdgcn_mfma_f32_16x16x32_bf16(a1, bb, acc[1][nt], 0, 0, 0);
      }
    } else {
      bool ok0 = ((unsigned)iy0 < 256u) & ((unsigned)ix0 < 256u);
      bool ok1 = ((unsigned)iy1 < 256u) & ((unsigned)ix1 < 256u);
      #pragma unroll
      for (int nt = 0; nt < 4; ++nt) {
        uint2 z2; z2.x = 0u; z2.y = 0u;
        uint2 lo = ok0 ? *(const uint2*)(pA + nt * 64) : z2;
        uint2 hi = ok1 ? *(const uint2*)(pB + nt * 64) : z2;
        uint4 u; u.x = lo.x; u.y = lo.y; u.z = hi.x; u.w = hi.y;
        bf16x8 bb = __builtin_bit_cast(bf16x8, u);
        acc[0][nt] = __builtin_amdgcn_mfma_f32_16x16x32_bf16(a0, bb, acc[0][nt], 0, 0, 0);
        acc[1][nt] = __builtin_amdgcn_mfma_f32_16x16x32_bf16(a1, bb, acc[1][nt], 0, 0, 0);
      }
    }
  }
  int px = oy * 128 + ox;
  int rb = khi * 4;
  #pragma unroll
  for (int mt = 0; mt < 2; ++mt) {
    int co = mt * 16 + rb;
    f32x4 bv = *(const f32x4*)(bias + co);
    #pragma unroll
    for (int nt = 0; nt < 4; ++nt) {
      float v0 = fmaxf(acc[mt][nt][0] + bv[0], 0.f);
      float v1 = fmaxf(acc[mt][nt][1] + bv[1], 0.f);
      float v2 = fmaxf(acc[mt][nt][2] + bv[2], 0.f);
      float v3 = fmaxf(acc[mt][nt][3] + bv[3], 0.f);
      uint2 pk;
      pk.x = (unsigned)f2bf(v0) | ((unsigned)f2bf(v1) << 16);
      pk.y = (unsigned)f2bf(v2) | ((unsigned)f2bf(v3) << 16);
      size_t off = (size_t)px * 2048 + nt * 512 + ((co >> 3) & 3) * 128 + ml * 8 + (co & 7);
      *(uint2*)(out + off) = pk;
    }
  }
}

// ================= MFMA conv, interior fast path =================
template<int CIN, int COUT, int MT>
__global__ __launch_bounds__(256) void mfma_conv(const ushort* __restrict__ in,
                                                 const ushort* __restrict__ wp,
                                                 const float* __restrict__ bias,
                                                 ushort* __restrict__ out,
                                                 int Hin, int Win, int Hout, int Wout) {
  constexpr int NMG = COUT / (16 * MT);
  constexpr int NKC = CIN / 32;
  constexpr int NCH = 16 * NKC;
  int wid = __builtin_amdgcn_readfirstlane(blockIdx.x * 4 + (threadIdx.x >> 6));
  int lane = threadIdx.x & 63;
  int mg = wid % NMG;
  int px = wid / NMG;
  int ox = px % Wout, oy = px / Wout;
  if (oy >= Hout) return;
  int mtile0 = mg * MT;
  f32x4 zero = {0.f, 0.f, 0.f, 0.f};
  f32x4 acc[MT][4];
  #pragma unroll
  for (int mt = 0; mt < MT; ++mt)
    #pragma unroll
    for (int nt = 0; nt < 4; ++nt) acc[mt][nt] = zero;
  const ushort* wbase = wp + (size_t)mtile0 * NCH * 512 + lane * 8;
  const size_t mstride = (size_t)NCH * 512;
  bool interior = (oy >= 1) & (oy < Hout - 1) & (ox >= 1) & (ox < Wout - 1);

  if (interior) {
    #pragma unroll
    for (int ky = 0; ky < 4; ++ky) {
      int iy = 2 * oy - 1 + ky;
      #pragma unroll
      for (int kx = 0; kx < 4; ++kx) {
        int ix = 2 * ox - 1 + kx;
        const ushort* ib = in + (size_t)(iy * Win + ix) * (CIN * 64) + lane * 8;
        int tap = ky * 4 + kx;
        #pragma unroll
        for (int kc = 0; kc < NKC; ++kc) {
          int kcg = tap * NKC + kc;
          bf16x8 a[MT], bb[4];
          #pragma unroll
          for (int mt = 0; mt < MT; ++mt)
            a[mt] = *(const bf16x8*)(wbase + mt * mstride + (size_t)kcg * 512);
          #pragma unroll
          for (int nt = 0; nt < 4; ++nt)
            bb[nt] = *(const bf16x8*)(ib + kc * 2048 + nt * 512);
          #pragma unroll
          for (int mt = 0; mt < MT; ++mt)
            #pragma unroll
            for (int nt = 0; nt < 4; ++nt)
              acc[mt][nt] = __builtin_amdgcn_mfma_f32_16x16x32_bf16(a[mt], bb[nt], acc[mt][nt], 0, 0, 0);
        }
      }
    }
  } else {
    for (int ky = 0; ky < 4; ++ky) {
      int iy = 2 * oy - 1 + ky;
      if ((unsigned)iy >= (unsigned)Hin) continue;
      for (int kx = 0; kx < 4; ++kx) {
        int ix = 2 * ox - 1 + kx;
        if ((unsigned)ix >= (unsigned)Win) continue;
        const ushort* ib = in + (size_t)(iy * Win + ix) * (CIN * 64) + lane * 8;
        int tap = ky * 4 + kx;
        #pragma unroll
        for (int kc = 0; kc < NKC; ++kc) {
          int kcg = tap * NKC + kc;
          bf16x8 a[MT], bb[4];
          #pragma unroll
          for (int mt = 0; mt < MT; ++mt)
            a[mt] = *(const bf16x8*)(wbase + mt * mstride + (size_t)kcg * 512);
          #pragma unroll
          for (int nt = 0; nt < 4; ++nt)
            bb[nt] = *(const bf16x8*)(ib + kc * 2048 + nt * 512);
          #pragma unroll
          for (int mt = 0; mt < MT; ++mt)
            #pragma unroll
            for (int nt = 0; nt < 4; ++nt)
              acc[mt][nt] = __builtin_amdgcn_mfma_f32_16x16x32_bf16(a[mt], bb[nt], acc[mt][nt], 0, 0, 0);
        }
      }
    }
  }
  int ml = lane & 15, rb = (lane >> 4) * 4;
  #pragma unroll
  for (int mt = 0; mt < MT; ++mt) {
    int co = mtile0 * 16 + mt * 16 + rb;
    f32x4 bv = *(const f32x4*)(bias + co);
    #pragma unroll
    for (int nt = 0; nt < 4; ++nt) {
      float v0 = fmaxf(acc[mt][nt][0] + bv[0], 0.f);
      float v1 = fmaxf(acc[mt][nt][1] + bv[1], 0.f);
      float v2 = fmaxf(acc[mt][nt][2] + bv[2], 0.f);
      float v3 = fmaxf(acc[mt][nt][3] + bv[3], 0.f);
      uint2 pk;
      pk.x = (unsigned)f2bf(v0) | ((unsigned)f2bf(v1) << 16);
      pk.y = (unsigned)f2bf(v2) | ((unsigned)f2bf(v3) << 16);
      size_t off = (size_t)px * (COUT * 64) + (size_t)(co >> 5) * 2048 + nt * 512
                 + ((co >> 3) & 3) * 128 + ml * 8 + (co & 7);
      *(uint2*)(out + off) = pk;
    }
  }
}

// ================= MFMA transposed conv, interior fast path =================
template<int CIN, int COUT, int MT, bool RELU>
__global__ __launch_bounds__(256) void mfma_deconv(const ushort* __restrict__ in,
                                                   const ushort* __restrict__ wp,
                                                   const float* __restrict__ bias,
                                                   ushort* __restrict__ out,
                                                   int Hin, int Win, int Hout, int Wout) {
  constexpr int NMG = COUT / (16 * MT);
  constexpr int NKC = CIN / 32;
  constexpr int NCH = 4 * NKC;
  constexpr int NTS = (COUT >= 32) ? 512 : (COUT * 16);
  int wid = __builtin_amdgcn_readfirstlane(blockIdx.x * 4 + (threadIdx.x >> 6));
  int lane = threadIdx.x & 63;
  int mg = wid % NMG; int r1 = wid / NMG;
  int wo2 = Wout >> 1;
  int pc = (Hout >> 1) * wo2;
  int pxc = r1 % pc; int cls = r1 / pc;
  if (cls >= 4) return;
  int p0 = cls >> 1, q0 = cls & 1;
  int tx = pxc % wo2, ty = pxc / wo2;
  int oy = 2 * ty + 1 - p0, ox = 2 * tx + 1 - q0;
  int iy0 = (oy + 1 - p0) >> 1, ix0 = (ox + 1 - q0) >> 1;
  int mtile0 = mg * MT;
  f32x4 zero = {0.f, 0.f, 0.f, 0.f};
  f32x4 acc[MT][4];
  #pragma unroll
  for (int mt = 0; mt < MT; ++mt)
    #pragma unroll
    for (int nt = 0; nt < 4; ++nt) acc[mt][nt] = zero;
  const ushort* wbase = wp + ((size_t)cls * (COUT / 16) + mtile0) * NCH * 512 + lane * 8;
  const size_t mstride = (size_t)NCH * 512;
  bool interior = (iy0 >= 1) & (iy0 <= Hin - 1) & (ix0 >= 1) & (ix0 <= Win - 1);

  if (interior) {
    #pragma unroll
    for (int i = 0; i < 2; ++i) {
      int iy = iy0 - i;
      #pragma unroll
      for (int j = 0; j < 2; ++j) {
        int ix = ix0 - j;
        const ushort* ib = in + (size_t)(iy * Win + ix) * (CIN * 64) + lane * 8;
        int tap = i * 2 + j;
        #pragma unroll
        for (int kc = 0; kc < NKC; ++kc) {
          int kcg = tap * NKC + kc;
          bf16x8 a[MT], bb[4];
          #pragma unroll
          for (int mt = 0; mt < MT; ++mt)
            a[mt] = *(const bf16x8*)(wbase + mt * mstride + (size_t)kcg * 512);
          #pragma unroll
          for (int nt = 0; nt < 4; ++nt)
            bb[nt] = *(const bf16x8*)(ib + kc * 2048 + nt * 512);
          #pragma unroll
          for (int mt = 0; mt < MT; ++mt)
            #pragma unroll
            for (int nt = 0; nt < 4; ++nt)
              acc[mt][nt] = __builtin_amdgcn_mfma_f32_16x16x32_bf16(a[mt], bb[nt], acc[mt][nt], 0, 0, 0);
        }
      }
    }
  } else {
    for (int i = 0; i < 2; ++i) {
      int iy = iy0 - i;
      if ((unsigned)iy >= (unsigned)Hin) continue;
      for (int j = 0; j < 2; ++j) {
        int ix = ix0 - j;
        if ((unsigned)ix >= (unsigned)Win) continue;
        const ushort* ib = in + (size_t)(iy * Win + ix) * (CIN * 64) + lane * 8;
        int tap = i * 2 + j;
        #pragma unroll
        for (int kc = 0; kc < NKC; ++kc) {
          int kcg = tap * NKC + kc;
          bf16x8 a[MT], bb[4];
          #pragma unroll
          for (int mt = 0; mt < MT; ++mt)
            a[mt] = *(const bf16x8*)(wbase + mt * mstride + (size_t)kcg * 512);
          #pragma unroll
          for (int nt = 0; nt < 4; ++nt)
            bb[nt] = *(const bf16x8*)(ib + kc * 2048 + nt * 512);
          #pragma unroll
          for (int mt = 0; mt < MT; ++mt)
            #pragma unroll
            for (int nt = 0; nt < 4; ++nt)
              acc[mt][nt] = __builtin_amdgcn_mfma_f32_16x16x32_bf16(a[mt], bb[nt], acc[mt][nt], 0, 0, 0);
        }
      }
    }
  }
  int ml = lane & 15, rb = (lane >> 4) * 4;
  int px = oy * Wout + ox;
  #pragma unroll
  for (int mt = 0; mt < MT; ++mt) {
    int co = mtile0 * 16 + mt * 16 + rb;
    f32x4 bv = *(const f32x4*)(bias + co);
    #pragma unroll
    for (int nt = 0; nt < 4; ++nt) {
      float v0 = acc[mt][nt][0] + bv[0];
      float v1 = acc[mt][nt][1] + bv[1];
      float v2 = acc[mt][nt][2] + bv[2];
      float v3 = acc[mt][nt][3] + bv[3];
      if (RELU) { v0=fmaxf(v0,0.f); v1=fmaxf(v1,0.f); v2=fmaxf(v2,0.f); v3=fmaxf(v3,0.f); }
      uint2 pk;
      pk.x = (unsigned)f2bf(v0) | ((unsigned)f2bf(v1) << 16);
      pk.y = (unsigned)f2bf(v2) | ((unsigned)f2bf(v3) << 16);
      size_t off = (size_t)px * (COUT * 64) + (size_t)(co >> 5) * 2048 + (size_t)nt * NTS
                 + ((co >> 3) & 3) * 128 + ml * 8 + (co & 7);
      *(uint2*)(out + off) = pk;
    }
  }
}

// ================= enc_fc fused: LDS-transpose staging + MFMA =================
#define APXS 1032
__global__ __launch_bounds__(256) void k_encfc_fused(const ushort* __restrict__ h4,
                                                     const float* __restrict__ wE,
                                                     float* __restrict__ partial) {
  __shared__ float smem[8320];
  ushort* au = (ushort*)smem;
  int s = blockIdx.x;
  int bid = (s & 7) * 256 + (s >> 3);
  int mg = bid & 15;
  int ccf = (bid >> 4) & 7;
  int pxg = bid >> 7;
  int tid = threadIdx.x;
  int co0 = mg * 32;
  #pragma unroll
  for (int i = 0; i < 16; ++i) {
    int idx = tid + i * 256;
    int px4 = idx & 3;
    int ci_l = (idx >> 2) & 31;
    int co_l = idx >> 7;
    float4 v = *(const float4*)&wE[((size_t)(co0 + co_l) << 16)
                                   + (size_t)(ccf * 32 + ci_l) * 256 + pxg * 16 + px4 * 4];
    int mt = co_l >> 4, m = co_l & 15;
    int kg = ci_l >> 3, k8 = ci_l & 7;
    int base = mt * 512 + kg * 128 + m * 8 + k8;
    au[(px4 * 4 + 0) * APXS + base] = f2bf(v.x);
    au[(px4 * 4 + 1) * APXS + base] = f2bf(v.y);
    au[(px4 * 4 + 2) * APXS + base] = f2bf(v.z);
    au[(px4 * 4 + 3) * APXS + base] = f2bf(v.w);
  }
  __syncthreads();
  int lane = tid & 63, wv = tid >> 6;
  int ml = lane & 15, rb = (lane >> 4) * 4;
  f32x4 zero = {0.f, 0.f, 0.f, 0.f};
  f32x4 acc[2][4];
  #pragma unroll
  for (int mt = 0; mt < 2; ++mt)
    #pragma unroll
    for (int nt = 0; nt < 4; ++nt) acc[mt][nt] = zero;
  #pragma unroll
  for (int jj = 0; jj < 4; ++jj) {
    int j = wv * 4 + jj;
    int px = pxg * 16 + j;
    bf16x8 a0 = *(const bf16x8*)(au + j * APXS + lane * 8);
    bf16x8 a1 = *(const bf16x8*)(au + j * APXS + 512 + lane * 8);
    const ushort* hb = h4 + (size_t)px * 16384 + ccf * 2048 + lane * 8;
    bf16x8 bb[4];
    #pragma unroll
    for (int nt = 0; nt < 4; ++nt)
      bb[nt] = *(const bf16x8*)(hb + nt * 512);
    #pragma unroll
    for (int nt = 0; nt < 4; ++nt) {
      acc[0][nt] = __builtin_amdgcn_mfma_f32_16x16x32_bf16(a0, bb[nt], acc[0][nt], 0, 0, 0);
      acc[1][nt] = __builtin_amdgcn_mfma_f32_16x16x32_bf16(a1, bb[nt], acc[1][nt], 0, 0, 0);
    }
  }
  __syncthreads();
  #pragma unroll
  for (int mt = 0; mt < 2; ++mt)
    #pragma unroll
    for (int nt = 0; nt < 4; ++nt)
      #pragma unroll
      for (int r = 0; r < 4; ++r)
        smem[wv * 2080 + (mt * 16 + rb + r) * 65 + nt * 16 + ml] = acc[mt][nt][r];
  __syncthreads();
  int ks = pxg * 8 + ccf;
  #pragma unroll
  for (int i = 0; i < 8; ++i) {
    int e = tid + i * 256;
    int b = e & 63, co_l = e >> 6;
    float sum = smem[co_l * 65 + b] + smem[2080 + co_l * 65 + b]
              + smem[4160 + co_l * 65 + b] + smem[6240 + co_l * 65 + b];
    partial[((size_t)(co0 + co_l) * ENC_KS + ks) * 64 + b] = sum;
  }
}

__global__ void k_encfc_red(const float* __restrict__ partial, const float* __restrict__ bias,
                            float* __restrict__ cnn) {
  int id = blockIdx.x * blockDim.x + threadIdx.x;
  int o = id >> 6, b = id & 63;
  float acc = bias[o];
  #pragma unroll 8
  for (int s = 0; s < ENC_KS; ++s) acc += partial[((size_t)o * ENC_KS + s) * 64 + b];
  cnn[(size_t)b * 512 + o] = fmaxf(acc, 0.f);
}

// ================= fused posterior + reparam (coalesced powT) =================
__global__ __launch_bounds__(512) void k_postz(const float* __restrict__ cnn,
                                               const float* __restrict__ belief,
                                               const float* __restrict__ powT,
                                               const float* __restrict__ bias,
                                               const float* __restrict__ eps,
                                               float* __restrict__ out,
                                               ushort* __restrict__ zb) {
  __shared__ float cs[512];
  __shared__ float bs[512];
  __shared__ float sm[512];
  int b = blockIdx.x;
  int j = threadIdx.x;
  cs[j] = cnn[(size_t)b * HIDD + j];
  bs[j] = belief[(size_t)b * HIDD + j];
  __syncthreads();
  float acc = bias[j];
  #pragma unroll 8
  for (int k = 0; k < HIDD; ++k) acc += cs[k] * powT[(size_t)k * 512 + j];
  #pragma unroll 8
  for (int k = 0; k < HIDD; ++k) acc += bs[k] * powT[(size_t)(512 + k) * 512 + j];
  sm[j] = acc;
  if (j < 256) out[O_MUPO + b * 256 + j] = acc;
  else         out[O_LVPO + b * 256 + (j - 256)] = acc;
  __syncthreads();
  if (j < 256) {
    float z = sm[j] + eps[b * 256 + j] * expf(0.5f * sm[j + 256]);
    out[O_ZT + b * 256 + j] = z;
    if (j < 128) zb[b * 128 + j] = f2bf(z);
  }
}

// ================= dec_fc MFMA: direct f32 weights, frag-order out =================
__global__ __launch_bounds__(256) void k_decfc_mfma(const ushort* __restrict__ zb,
                                                    const float* __restrict__ dfw,
                                                    const float* __restrict__ dfb,
                                                    ushort* __restrict__ dec) {
  int wid = __builtin_amdgcn_readfirstlane(blockIdx.x * 4 + (threadIdx.x >> 6));
  int lane = threadIdx.x & 63;
  int m0 = wid * 32;
  int ml = lane & 15, kl = (lane >> 4) * 8;
  f32x4 zero = {0.f, 0.f, 0.f, 0.f};
  f32x4 acc[2][4];
  #pragma unroll
  for (int mt = 0; mt < 2; ++mt)
    #pragma unroll
    for (int nt = 0; nt < 4; ++nt) acc[mt][nt] = zero;
  #pragma unroll
  for (int kc = 0; kc < 4; ++kc) {
    bf16x8 a[2], bb[4];
    #pragma unroll
    for (int mt = 0; mt < 2; ++mt) {
      int m_r = m0 + mt * 16 + ml;
      const float* wr = dfw + (size_t)((m_r & 127) * 256 + (m_r >> 7)) * 128 + kc * 32 + kl;
      float4 u0 = *(const float4*)wr;
      float4 u1 = *(const float4*)(wr + 4);
      bf16x8 av;
      av[0] = (short)f2bf(u0.x); av[1] = (short)f2bf(u0.y);
      av[2] = (short)f2bf(u0.z); av[3] = (short)f2bf(u0.w);
      av[4] = (short)f2bf(u1.x); av[5] = (short)f2bf(u1.y);
      av[6] = (short)f2bf(u1.z); av[7] = (short)f2bf(u1.w);
      a[mt] = av;
    }
    #pragma unroll
    for (int nt = 0; nt < 4; ++nt)
      bb[nt] = *(const bf16x8*)(zb + (size_t)(nt * 16 + ml) * 128 + kc * 32 + kl);
    #pragma unroll
    for (int mt = 0; mt < 2; ++mt)
      #pragma unroll
      for (int nt = 0; nt < 4; ++nt)
        acc[mt][nt] = __builtin_amdgcn_mfma_f32_16x16x32_bf16(a[mt], bb[nt], acc[mt][nt], 0, 0, 0);
  }
  int rb = (lane >> 4) * 4;
  #pragma unroll
  for (int mt = 0; mt < 2; ++mt) {
    int m = m0 + mt * 16 + rb;
    int pix = m >> 7, co = m & 127;
    float bv0 = dfb[(size_t)(co + 0) * 256 + pix];
    float bv1 = dfb[(size_t)(co + 1) * 256 + pix];
    float bv2 = dfb[(size_t)(co + 2) * 256 + pix];
    float bv3 = dfb[(size_t)(co + 3) * 256 + pix];
    #pragma unroll
    for (int nt = 0; nt < 4; ++nt) {
      uint2 pk;
      pk.x = (unsigned)f2bf(acc[mt][nt][0] + bv0) | ((unsigned)f2bf(acc[mt][nt][1] + bv1) << 16);
      pk.y = (unsigned)f2bf(acc[mt][nt][2] + bv2) | ((unsigned)f2bf(acc[mt][nt][3] + bv3) << 16);
      size_t off = (size_t)pix * 8192 + (size_t)(co >> 5) * 2048 + nt * 512
                 + ((co >> 3) & 3) * 128 + ml * 8 + (co & 7);
      *(uint2*)(dec + off) = pk;
    }
  }
}

// ================= d4 fused with output transpose =================
__global__ __launch_bounds__(256) void k_d4t(const ushort* __restrict__ in,
                                             const float* __restrict__ w,
                                             const float* __restrict__ bias,
                                             float* __restrict__ out) {
  __shared__ float lds[64][65];
  int blk = blockIdx.x;
  int oy = blk >> 2, ox0 = (blk & 3) << 6;
  int t = threadIdx.x;
  int b = t & 63, sub = t >> 6;
  float bv = bias[0];
  for (int j = 0; j < 16; ++j) {
    int oxl = j * 4 + sub;
    int ox = ox0 + oxl;
    int p0 = (oy + 1) & 1, q0 = (ox + 1) & 1;
    int iy0 = (oy + 1 - p0) >> 1, ix0 = (ox + 1 - q0) >> 1;
    float acc = bv;
    #pragma unroll
    for (int i = 0; i < 2; ++i) {
      int iy = iy0 - i;
      if ((unsigned)iy >= 128u) continue;
      int p = p0 + 2 * i;
      #pragma unroll
      for (int jj = 0; jj < 2; ++jj) {
        int ix = ix0 - jj;
        if ((unsigned)ix >= 128u) continue;
        int q = q0 + 2 * jj;
        const ushort* base = in + (size_t)(iy * 128 + ix) * 1024 + (b >> 4) * 256 + (b & 15) * 8;
        bf16x8 v0 = *(const bf16x8*)(base);
        bf16x8 v1 = *(const bf16x8*)(base + 128);
        const float* wq = w + p * 4 + q;
        #pragma unroll
        for (int ci = 0; ci < 8; ++ci) acc += bf2f((ushort)v0[ci]) * wq[ci * 16];
        #pragma unroll
        for (int ci = 0; ci < 8; ++ci) acc += bf2f((ushort)v1[ci]) * wq[(ci + 8) * 16];
      }
    }
    lds[oxl][b] = acc;
  }
  __syncthreads();
  #pragma unroll
  for (int j = 0; j < 16; ++j) {
    int idx = t + j * 256;
    int b2 = idx >> 6, oxl = idx & 63;
    out[(size_t)b2 * 65536 + oy * 256 + ox0 + oxl] = lds[oxl][b2];
  }
}

// ================= launch =================

extern "C" void kernel_launch(void* const* d_in, const int* in_sizes, int n_in,
                              void* d_out, int out_size, void* d_ws, size_t ws_size,
                              hipStream_t stream) {
  const float* img      = (const float*)d_in[0];
  const float* act      = (const float*)d_in[1];
  const float* z_prev   = (const float*)d_in[2];
  const float* st_prev  = (const float*)d_in[3];
  const float* eps      = (const float*)d_in[4];
  const float* c1w = (const float*)d_in[5];  const float* c1b = (const float*)d_in[6];
  const float* c2w = (const float*)d_in[7];  const float* c2b = (const float*)d_in[8];
  const float* c3w = (const float*)d_in[9];  const float* c3b = (const float*)d_in[10];
  const float* c4w = (const float*)d_in[11]; const float* c4b = (const float*)d_in[12];
  const float* efw = (const float*)d_in[13]; const float* efb = (const float*)d_in[14];
  const float* pow_ = (const float*)d_in[15]; const float* pob = (const float*)d_in[16];
  const float* prw = (const float*)d_in[17]; const float* prb = (const float*)d_in[18];
  const float* siw = (const float*)d_in[19]; const float* sib = (const float*)d_in[20];
  const float* Alog = (const float*)d_in[21];
  const float* Bw = (const float*)d_in[22];  const float* Cw = (const float*)d_in[23];
  const float* Dw = (const float*)d_in[24];  const float* Db = (const float*)d_in[25];
  const float* Dv = (const float*)d_in[26];
  const float* dfw = (const float*)d_in[27]; const float* dfb = (const float*)d_in[28];
  const float* d1w = (const float*)d_in[29]; const float* d1b = (const float*)d_in[30];
  const float* d2w = (const float*)d_in[31]; const float* d2b = (const float*)d_in[32];
  const float* d3w = (const float*)d_in[33]; const float* d3b = (const float*)d_in[34];
  const float* d4w = (const float*)d_in[35]; const float* d4b = (const float*)d_in[36];

  float* ws = (float*)d_ws;
  float* out = (float*)d_out;

  ushort* pc2 = (ushort*)(ws + PW_C2);
  ushort* pc3 = (ushort*)(ws + PW_C3);
  ushort* pc4 = (ushort*)(ws + PW_C4);
  ushort* pd1 = (ushort*)(ws + PW_D1);
  ushort* pd2 = (ushort*)(ws + PW_D2);
  ushort* pd3 = (ushort*)(ws + PW_D3);
  ushort* pc1 = (ushort*)(ws + PW_C1);
  ushort* timg4 = (ushort*)(ws + W_TIMG);
  ushort* h1b = (ushort*)(ws + W_H1B);
  ushort* h2b = (ushort*)(ws + W_H2B);
  ushort* h3b = (ushort*)(ws + W_H3B);
  ushort* h4b = (ushort*)(ws + W_H4B);
  ushort* deco = (ushort*)(ws + W_DECO);
  ushort* d1o = (ushort*)(ws + W_D1O);
  ushort* d2o = (ushort*)(ws + W_D2O);
  ushort* d3o = (ushort*)(ws + W_D3O);
  ushort* zb = (ushort*)(ws + W_ZB16);
  float* siwT = ws + W_SIWT;
  float* DwT  = ws + W_DWT;
  float* prwT = ws + W_PRWT;
  float* powT = ws + W_POWT;

  // ---- merged weight prepack (+ conv1 pack + dense transposes) ----
  k_pack_all<<<7988, 256, 0, stream>>>(c2w, c3w, c4w, d1w, d2w, d3w, c1w,
                                       siw, Dw, prw, pow_,
                                       pc2, pc3, pc4, pd1, pd2, pd3, pc1,
                                       siwT, DwT, prwT, powT);

  // ---- SSM (blocks 0..63) || img transpose (blocks 64..1087), both post-pack ----
  k_ssm_timg<<<1088, 512, 0, stream>>>(z_prev, act, siwT, sib, DwT, Db, Bw, Cw,
                                       Alog, Dv, st_prev, out + O_STATE,
                                       ws + W_BELIEF, prwT, prb, out,
                                       img, timg4);

  // ---- encoder ----
  k_conv1_mfma<<<4096, 256, 0, stream>>>(timg4, pc1, c1b, h1b);
  mfma_conv<32, 64, 4><<<1024, 256, 0, stream>>>(h1b, pc2, c2b, h2b, 128, 128, 64, 64);
  mfma_conv<64, 128, 4><<<512, 256, 0, stream>>>(h2b, pc3, c3b, h3b, 64, 64, 32, 32);
  mfma_conv<128, 256, 2><<<512, 256, 0, stream>>>(h3b, pc4, c4b, h4b, 32, 32, 16, 16);

  // ---- enc_fc (fused transpose+GEMM) ----
  k_encfc_fused<<<2048, 256, 0, stream>>>(h4b, efw, ws + W_ENCP);
  k_encfc_red<<<128, 256, 0, stream>>>(ws + W_ENCP, efb, ws + W_CNN);

  // ---- fused posterior + reparam ----
  k_postz<<<64, 512, 0, stream>>>(ws + W_CNN, ws + W_BELIEF, powT, pob, eps, out, zb);

  // ---- decoder ----
  k_decfc_mfma<<<256, 256, 0, stream>>>(zb, dfw, dfb, deco);
  mfma_deconv<128, 64, 2, true><<<512, 256, 0, stream>>>(deco, pd1, d1b, d1o, 16, 16, 32, 32);
  mfma_deconv<64, 32, 2, true><<<1024, 256, 0, stream>>>(d1o, pd2, d2b, d2o, 32, 32, 64, 64);
  mfma_deconv<32, 16, 1, true><<<4096, 256, 0, stream>>>(d2o, pd3, d3b, d3o, 64, 64, 128, 128);
  k_d4t<<<1024, 256, 0, stream>>>(d3o, d4w, d4b, out + O_PRED);
}

// Round 15
// 401.136 us; speedup vs baseline: 1.1152x; 1.0854x over previous
//
#include <hip/hip_runtime.h>
#include <math.h>

#define BB 64
#define LATENT 256
#define ACTD 6
#define HIDD 512
#define DST 16

typedef __attribute__((ext_vector_type(8))) short bf16x8;
typedef __attribute__((ext_vector_type(4))) float f32x4;

static __device__ __forceinline__ ushort f2bf(float f) {
  unsigned u = __builtin_bit_cast(unsigned, f);
  unsigned r = (u + 0x7FFFu + ((u >> 16) & 1u)) >> 16;
  return (ushort)r;
}
static __device__ __forceinline__ float bf2f(ushort u) {
  return __builtin_bit_cast(float, ((unsigned)u) << 16);
}

// ---------------- output offsets (floats) ----------------
#define O_PRED   0
#define O_ZT     4194304
#define O_STATE  4210688
#define O_MUP    4734976
#define O_LVP    4751360
#define O_MUPO   4767744
#define O_LVPO   4784128

// ---------------- ws offsets (floats), lifetime-reused ----------------
#define W_BELIEF 67584u
#define W_CNN    100352u
#define W_ZB16   133120u
#define PW_C2    137216u
#define PW_C3    153600u
#define PW_C4    219136u
#define PW_D1    481280u
#define PW_D2    546816u
#define PW_D3    563200u
#define PW_C1    567296u
#define W_TIMG   602112u      // timg4 bf16 [65536][64][4]
#define W_H1B    13185024u
#define W_H2B    29962240u
#define W_H3B    38350848u
#define W_H4B    42545152u
#define W_SIWT   44642304u
#define W_DWT    44776448u
#define W_PRWT   45038592u
#define W_POWT   45300736u
// reuse:
#define W_ENCP   602112u
#define W_DECO   8990720u
#define W_D1O    10039296u
#define W_D2O    13185024u
#define W_D3O    17379328u

#define ENC_KS 128

// ================= merged weight prepack =================

static __device__ __forceinline__ void pack_conv_elem(const float* __restrict__ w,
                                                      ushort* __restrict__ o,
                                                      int Cout, int Cin, int id) {
  int NCH = Cin / 2;
  int per = NCH * 512;
  int mt = id / per, r = id % per;
  int kcg = r >> 9, s = r & 511;
  int kg = s >> 7, m = (s >> 3) & 15, k8 = s & 7;
  int co = mt * 16 + m;
  int k = kcg * 32 + kg * 8 + k8;
  int tap = k / Cin, ci = k % Cin;
  o[id] = f2bf(w[(size_t)(co * Cin + ci) * 16 + tap]);
}

static __device__ __forceinline__ void pack_deconv_elem(const float* __restrict__ w,
                                                        ushort* __restrict__ o,
                                                        int Cout, int Cin, int id) {
  int NCH = Cin / 8;
  int perM = NCH * 512;
  int perC = (Cout / 16) * perM;
  int cls = id / perC, r = id % perC;
  int mt = r / perM, r2 = r % perM;
  int kcg = r2 >> 9, s = r2 & 511;
  int kg = s >> 7, m = (s >> 3) & 15, k8 = s & 7;
  int co = mt * 16 + m;
  int k = kcg * 32 + kg * 8 + k8;
  int t = k / Cin, ci = k % Cin;
  int p = (cls >> 1) + 2 * (t >> 1);
  int q = (cls & 1) + 2 * (t & 1);
  o[id] = f2bf(w[(size_t)(ci * Cout + co) * 16 + p * 4 + q]);
}

static __device__ __forceinline__ void pack_conv1_elem(const float* __restrict__ w,
                                                       ushort* __restrict__ o, int id) {
  int mt = id >> 10, r = id & 1023;
  int kcg = r >> 9, s = r & 511;
  int kg = s >> 7, m = (s >> 3) & 15, k8 = s & 7;
  int co = mt * 16 + m;
  int k = kcg * 32 + kg * 8 + k8;
  int tap = k >> 2, ci = k & 3;
  o[id] = (ci < 3) ? f2bf(w[(size_t)(co * 3 + ci) * 16 + tap]) : (ushort)0;
}

__global__ __launch_bounds__(256) void k_pack_all(
    const float* __restrict__ c2w, const float* __restrict__ c3w,
    const float* __restrict__ c4w, const float* __restrict__ d1w,
    const float* __restrict__ d2w, const float* __restrict__ d3w,
    const float* __restrict__ c1w,
    const float* __restrict__ siw, const float* __restrict__ Dw,
    const float* __restrict__ prw, const float* __restrict__ pw,
    ushort* __restrict__ pc2, ushort* __restrict__ pc3, ushort* __restrict__ pc4,
    ushort* __restrict__ pd1, ushort* __restrict__ pd2, ushort* __restrict__ pd3,
    ushort* __restrict__ pc1,
    float* __restrict__ siwT, float* __restrict__ DwT,
    float* __restrict__ prwT, float* __restrict__ powT) {
  int id = blockIdx.x * 256 + threadIdx.x;
  if (id < 32768)            pack_conv_elem(c2w, pc2, 64, 32, id);
  else if (id < 163840)      pack_conv_elem(c3w, pc3, 128, 64, id - 32768);
  else if (id < 688128)      pack_conv_elem(c4w, pc4, 256, 128, id - 163840);
  else if (id < 819200)      pack_deconv_elem(d1w, pd1, 64, 128, id - 688128);
  else if (id < 851968)      pack_deconv_elem(d2w, pd2, 32, 64, id - 819200);
  else if (id < 860160)      pack_deconv_elem(d3w, pd3, 16, 32, id - 851968);
  else if (id < 862208)      pack_conv1_elem(c1w, pc1, id - 860160);
  else if (id < 996352) {    // siwT [262][512] (scalar layout)
    int r = id - 862208; int k = r >> 9, h = r & 511;
    siwT[r] = siw[(size_t)h * (LATENT + ACTD) + k];
  } else if (id < 1258496) { // DwT2 [256p][512h][2]: r = p*1024 + h*2 + e, k = 2p+e
    int r = id - 996352;
    int p = r >> 10, h2 = (r & 1023) >> 1, e = r & 1;
    DwT[r] = Dw[(size_t)h2 * HIDD + (2 * p + e)];
  } else if (id < 1520640) { // prwT2 [256p][512h][2]
    int r = id - 1258496;
    int p = r >> 10, h2 = (r & 1023) >> 1, e = r & 1;
    prwT[r] = prw[(size_t)h2 * HIDD + (2 * p + e)];
  } else if (id < 2044928) { // powT2 [512p][512j][2]: k = 2p+e (k in [0,1024))
    int r = id - 1520640;
    int p = r >> 10, j2 = (r & 1023) >> 1, e = r & 1;
    powT[r] = pw[(size_t)j2 * 1024 + (2 * p + e)];
  }
}

// ================= merged SSM (blocks 0..63, k-split) + img transpose (64..1087) =================
__global__ __launch_bounds__(1024) void k_ssm_timg(
    const float* __restrict__ z_prev, const float* __restrict__ act,
    const float* __restrict__ siwT, const float* __restrict__ sib,
    const float* __restrict__ DwT, const float* __restrict__ Db,
    const float* __restrict__ Bw, const float* __restrict__ Cw,
    const float* __restrict__ Alog, const float* __restrict__ Dv,
    const float* __restrict__ st_prev, float* __restrict__ state_out,
    float* __restrict__ belief_out, const float* __restrict__ prwT,
    const float* __restrict__ prb, float* __restrict__ out,
    const float* __restrict__ img, ushort* __restrict__ timg4) {
  __shared__ float sm[12480];
  int blk = blockIdx.x;
  int tid = threadIdx.x;

  if (blk < 64) {
    // arena: xs 264 | si 512 | bel 512 | red 512 | part 128 | btct 32
    float* xs   = sm;
    float* si   = sm + 264;
    float* bel  = sm + 776;
    float* red  = sm + 1288;
    float* part = sm + 1800;
    float* btct = sm + 1928;
    int b = blk;
    int h = tid & 511;
    int half = tid >> 9;
    if (tid < 256) xs[tid] = z_prev[(size_t)b * LATENT + tid];
    else if (tid < 256 + ACTD) xs[tid] = act[(size_t)b * ACTD + (tid - 256)];
    else if (tid < 264) xs[tid] = 0.f;
    __syncthreads();
    // ---- ssm_in: K=262 split 131/131 ----
    {
      float acc = half ? 0.f : sib[h];
      int k0 = half * 131;
      #pragma unroll 4
      for (int k = k0; k < k0 + 131; ++k) acc += xs[k] * siwT[(size_t)k * 512 + h];
      if (half) red[h] = acc;
      __syncthreads();
      if (!half) {
        float t = acc + red[h];
        si[h] = t / (1.f + expf(-t));
      }
    }
    __syncthreads();
    // ---- delta: pair-interleaved DwT2, split 256/256 ----
    float d = 0.f;
    {
      float acc = half ? 0.f : Db[h];
      const float* wb = DwT + (size_t)(half * 128) * 1024 + h * 2;
      const float* sb = si + half * 256;
      #pragma unroll 4
      for (int p = 0; p < 128; ++p) {
        float2 w2 = *(const float2*)(wb + (size_t)p * 1024);
        acc += sb[2 * p] * w2.x + sb[2 * p + 1] * w2.y;
      }
      if (half) red[h] = acc;
      __syncthreads();
      if (!half) {
        float t = acc + red[h];
        d = fmaxf(t, 0.f) + log1pf(expf(-fabsf(t)));
      }
    }
    // ---- B_t/C_t partials (tid<128, all half0) ----
    if (tid < 128) {
      int hf2 = tid >> 6;
      int l = tid & 63;
      int n = l & 15, p = l >> 4;
      const float* wr = (hf2 ? Cw : Bw) + (size_t)n * HIDD + p * 128;
      const float* sr = si + p * 128;
      float a2 = 0.f;
      #pragma unroll 4
      for (int k = 0; k < 128; k += 4) {
        float4 w4 = *(const float4*)(wr + k);
        a2 += sr[k] * w4.x + sr[k+1] * w4.y + sr[k+2] * w4.z + sr[k+3] * w4.w;
      }
      part[(hf2 * 16 + n) * 4 + p] = a2;
    }
    __syncthreads();
    if (tid < 32) {
      int hf2 = tid >> 4, n = tid & 15;
      const float* pp = part + (hf2 * 16 + n) * 4;
      btct[hf2 * 16 + n] = pp[0] + pp[1] + pp[2] + pp[3];
    }
    __syncthreads();
    // ---- state + belief (half0) ----
    if (!half) {
      float si_h = si[h];
      float belv = Dv[h] * si_h;
      const float* al = Alog + (size_t)h * DST;
      const float* sp = st_prev + ((size_t)b * 512 + h) * DST;
      float* so = state_out + ((size_t)b * 512 + h) * DST;
      #pragma unroll
      for (int n = 0; n < DST; ++n) {
        float A = -expf(al[n]);
        float st = expf(d * A) * sp[n] + d * btct[n] * si_h;
        so[n] = st;
        belv += st * btct[16 + n];
      }
      bel[h] = belv;
      belief_out[(size_t)b * 512 + h] = belv;
    }
    __syncthreads();
    // ---- prior: pair-interleaved prwT2, split 256/256 ----
    {
      float acc = half ? 0.f : prb[h];
      const float* wb = prwT + (size_t)(half * 128) * 1024 + h * 2;
      const float* bb2 = bel + half * 256;
      #pragma unroll 4
      for (int p = 0; p < 128; ++p) {
        float2 w2 = *(const float2*)(wb + (size_t)p * 1024);
        acc += bb2[2 * p] * w2.x + bb2[2 * p + 1] * w2.y;
      }
      if (half) red[h] = acc;
      __syncthreads();
      if (!half) {
        float t = acc + red[h];
        if (h < 256) out[O_MUP + b * 256 + h] = t;
        else         out[O_LVP + b * 256 + (h - 256)] = t;
      }
    }
  } else {
    // ---------- img -> [px][64b][4ci] bf16 ----------
    float (*ts)[64][65] = (float (*)[64][65])sm;
    int p0 = (blk - 64) << 6;
    #pragma unroll
    for (int c = 0; c < 3; ++c) {
      #pragma unroll
      for (int i = 0; i < 4; ++i) {
        int idx = tid + i * 1024;
        int b = idx >> 6, pr = idx & 63;
        ts[c][pr][b] = img[((size_t)b * 3 + c) * 65536 + p0 + pr];
      }
    }
    __syncthreads();
    #pragma unroll
    for (int i = 0; i < 4; ++i) {
      int idx = tid + i * 1024;
      int pr = idx >> 6, b = idx & 63;
      uint2 pk;
      pk.x = (unsigned)f2bf(ts[0][pr][b]) | ((unsigned)f2bf(ts[1][pr][b]) << 16);
      pk.y = (unsigned)f2bf(ts[2][pr][b]);
      *(uint2*)(timg4 + ((size_t)(p0 + pr) * 64 + b) * 4) = pk;
    }
  }
}

// ================= conv1 MFMA =================
__global__ __launch_bounds__(256) void k_conv1_mfma(const ushort* __restrict__ in,
                                                    const ushort* __restrict__ wp,
                                                    const float* __restrict__ bias,
                                                    ushort* __restrict__ out) {
  int wid = __builtin_amdgcn_readfirstlane(blockIdx.x * 4 + (threadIdx.x >> 6));
  int lane = threadIdx.x & 63;
  int ox = wid & 127, oy = wid >> 7;
  int ml = lane & 15, khi = lane >> 4;
  f32x4 zero = {0.f, 0.f, 0.f, 0.f};
  f32x4 acc[2][4];
  #pragma unroll
  for (int mt = 0; mt < 2; ++mt)
    #pragma unroll
    for (int nt = 0; nt < 4; ++nt) acc[mt][nt] = zero;
  int by = 2 * oy - 1, bx = 2 * ox - 1;
  bool interior = (oy >= 1) & (oy <= 126) & (ox >= 1) & (ox <= 126);

  #pragma unroll
  for (int kc = 0; kc < 2; ++kc) {
    bf16x8 a0 = *(const bf16x8*)(wp + kc * 512 + lane * 8);
    bf16x8 a1 = *(const bf16x8*)(wp + 1024 + kc * 512 + lane * 8);
    int t0 = kc * 8 + khi * 2;
    int ky0 = t0 >> 2, kx0 = t0 & 3;
    int ky1 = (t0 + 1) >> 2, kx1 = (t0 + 1) & 3;
    int iy0 = by + ky0, ix0 = bx + kx0;
    int iy1 = by + ky1, ix1 = bx + kx1;
    const ushort* pA = in + ((size_t)(iy0 * 256 + ix0) * 64 + ml) * 4;
    const ushort* pB = in + ((size_t)(iy1 * 256 + ix1) * 64 + ml) * 4;
    if (interior) {
      #pragma unroll
      for (int nt = 0; nt < 4; ++nt) {
        uint2 lo = *(const uint2*)(pA + nt * 64);
        uint2 hi = *(const uint2*)(pB + nt * 64);
        uint4 u; u.x = lo.x; u.y = lo.y; u.z = hi.x; u.w = hi.y;
        bf16x8 bb = __builtin_bit_cast(bf16x8, u);
        acc[0][nt] = __builtin_amdgcn_mfma_f32_16x16x32_bf16(a0, bb, acc[0][nt], 0, 0, 0);
        acc[1][nt] = __builtin_amdgcn_mfma_f32_16x16x32_bf16(a1, bb, acc[1][nt], 0, 0, 0);
      }
    } else {
      bool ok0 = ((unsigned)iy0 < 256u) & ((unsigned)ix0 < 256u);
      bool ok1 = ((unsigned)iy1 < 256u) & ((unsigned)ix1 < 256u);
      #pragma unroll
      for (int nt = 0; nt < 4; ++nt) {
        uint2 z2; z2.x = 0u; z2.y = 0u;
        uint2 lo = ok0 ? *(const uint2*)(pA + nt * 64) : z2;
        uint2 hi = ok1 ? *(const uint2*)(pB + nt * 64) : z2;
        uint4 u; u.x = lo.x; u.y = lo.y; u.z = hi.x; u.w = hi.y;
        bf16x8 bb = __builtin_bit_cast(bf16x8, u);
        acc[0][nt] = __builtin_amdgcn_mfma_f32_16x16x32_bf16(a0, bb, acc[0][nt], 0, 0, 0);
        acc[1][nt] = __builtin_amdgcn_mfma_f32_16x16x32_bf16(a1, bb, acc[1][nt], 0, 0, 0);
      }
    }
  }
  int px = oy * 128 + ox;
  int rb = khi * 4;
  #pragma unroll
  for (int mt = 0; mt < 2; ++mt) {
    int co = mt * 16 + rb;
    f32x4 bv = *(const f32x4*)(bias + co);
    #pragma unroll
    for (int nt = 0; nt < 4; ++nt) {
      float v0 = fmaxf(acc[mt][nt][0] + bv[0], 0.f);
      float v1 = fmaxf(acc[mt][nt][1] + bv[1], 0.f);
      float v2 = fmaxf(acc[mt][nt][2] + bv[2], 0.f);
      float v3 = fmaxf(acc[mt][nt][3] + bv[3], 0.f);
      uint2 pk;
      pk.x = (unsigned)f2bf(v0) | ((unsigned)f2bf(v1) << 16);
      pk.y = (unsigned)f2bf(v2) | ((unsigned)f2bf(v3) << 16);
      size_t off = (size_t)px * 2048 + nt * 512 + ((co >> 3) & 3) * 128 + ml * 8 + (co & 7);
      *(uint2*)(out + off) = pk;
    }
  }
}

// ================= MFMA conv, interior fast path =================
template<int CIN, int COUT, int MT>
__global__ __launch_bounds__(256) void mfma_conv(const ushort* __restrict__ in,
                                                 const ushort* __restrict__ wp,
                                                 const float* __restrict__ bias,
                                                 ushort* __restrict__ out,
                                                 int Hin, int Win, int Hout, int Wout) {
  constexpr int NMG = COUT / (16 * MT);
  constexpr int NKC = CIN / 32;
  constexpr int NCH = 16 * NKC;
  int wid = __builtin_amdgcn_readfirstlane(blockIdx.x * 4 + (threadIdx.x >> 6));
  int lane = threadIdx.x & 63;
  int mg = wid % NMG;
  int px = wid / NMG;
  int ox = px % Wout, oy = px / Wout;
  if (oy >= Hout) return;
  int mtile0 = mg * MT;
  f32x4 zero = {0.f, 0.f, 0.f, 0.f};
  f32x4 acc[MT][4];
  #pragma unroll
  for (int mt = 0; mt < MT; ++mt)
    #pragma unroll
    for (int nt = 0; nt < 4; ++nt) acc[mt][nt] = zero;
  const ushort* wbase = wp + (size_t)mtile0 * NCH * 512 + lane * 8;
  const size_t mstride = (size_t)NCH * 512;
  bool interior = (oy >= 1) & (oy < Hout - 1) & (ox >= 1) & (ox < Wout - 1);

  if (interior) {
    #pragma unroll
    for (int ky = 0; ky < 4; ++ky) {
      int iy = 2 * oy - 1 + ky;
      #pragma unroll
      for (int kx = 0; kx < 4; ++kx) {
        int ix = 2 * ox - 1 + kx;
        const ushort* ib = in + (size_t)(iy * Win + ix) * (CIN * 64) + lane * 8;
        int tap = ky * 4 + kx;
        #pragma unroll
        for (int kc = 0; kc < NKC; ++kc) {
          int kcg = tap * NKC + kc;
          bf16x8 a[MT], bb[4];
          #pragma unroll
          for (int mt = 0; mt < MT; ++mt)
            a[mt] = *(const bf16x8*)(wbase + mt * mstride + (size_t)kcg * 512);
          #pragma unroll
          for (int nt = 0; nt < 4; ++nt)
            bb[nt] = *(const bf16x8*)(ib + kc * 2048 + nt * 512);
          #pragma unroll
          for (int mt = 0; mt < MT; ++mt)
            #pragma unroll
            for (int nt = 0; nt < 4; ++nt)
              acc[mt][nt] = __builtin_amdgcn_mfma_f32_16x16x32_bf16(a[mt], bb[nt], acc[mt][nt], 0, 0, 0);
        }
      }
    }
  } else {
    for (int ky = 0; ky < 4; ++ky) {
      int iy = 2 * oy - 1 + ky;
      if ((unsigned)iy >= (unsigned)Hin) continue;
      for (int kx = 0; kx < 4; ++kx) {
        int ix = 2 * ox - 1 + kx;
        if ((unsigned)ix >= (unsigned)Win) continue;
        const ushort* ib = in + (size_t)(iy * Win + ix) * (CIN * 64) + lane * 8;
        int tap = ky * 4 + kx;
        #pragma unroll
        for (int kc = 0; kc < NKC; ++kc) {
          int kcg = tap * NKC + kc;
          bf16x8 a[MT], bb[4];
          #pragma unroll
          for (int mt = 0; mt < MT; ++mt)
            a[mt] = *(const bf16x8*)(wbase + mt * mstride + (size_t)kcg * 512);
          #pragma unroll
          for (int nt = 0; nt < 4; ++nt)
            bb[nt] = *(const bf16x8*)(ib + kc * 2048 + nt * 512);
          #pragma unroll
          for (int mt = 0; mt < MT; ++mt)
            #pragma unroll
            for (int nt = 0; nt < 4; ++nt)
              acc[mt][nt] = __builtin_amdgcn_mfma_f32_16x16x32_bf16(a[mt], bb[nt], acc[mt][nt], 0, 0, 0);
        }
      }
    }
  }
  int ml = lane & 15, rb = (lane >> 4) * 4;
  #pragma unroll
  for (int mt = 0; mt < MT; ++mt) {
    int co = mtile0 * 16 + mt * 16 + rb;
    f32x4 bv = *(const f32x4*)(bias + co);
    #pragma unroll
    for (int nt = 0; nt < 4; ++nt) {
      float v0 = fmaxf(acc[mt][nt][0] + bv[0], 0.f);
      float v1 = fmaxf(acc[mt][nt][1] + bv[1], 0.f);
      float v2 = fmaxf(acc[mt][nt][2] + bv[2], 0.f);
      float v3 = fmaxf(acc[mt][nt][3] + bv[3], 0.f);
      uint2 pk;
      pk.x = (unsigned)f2bf(v0) | ((unsigned)f2bf(v1) << 16);
      pk.y = (unsigned)f2bf(v2) | ((unsigned)f2bf(v3) << 16);
      size_t off = (size_t)px * (COUT * 64) + (size_t)(co >> 5) * 2048 + nt * 512
                 + ((co >> 3) & 3) * 128 + ml * 8 + (co & 7);
      *(uint2*)(out + off) = pk;
    }
  }
}

// ================= MFMA transposed conv, interior fast path =================
template<int CIN, int COUT, int MT, bool RELU>
__global__ __launch_bounds__(256) void mfma_deconv(const ushort* __restrict__ in,
                                                   const ushort* __restrict__ wp,
                                                   const float* __restrict__ bias,
                                                   ushort* __restrict__ out,
                                                   int Hin, int Win, int Hout, int Wout) {
  constexpr int NMG = COUT / (16 * MT);
  constexpr int NKC = CIN / 32;
  constexpr int NCH = 4 * NKC;
  constexpr int NTS = (COUT >= 32) ? 512 : (COUT * 16);
  int wid = __builtin_amdgcn_readfirstlane(blockIdx.x * 4 + (threadIdx.x >> 6));
  int lane = threadIdx.x & 63;
  int mg = wid % NMG; int r1 = wid / NMG;
  int wo2 = Wout >> 1;
  int pc = (Hout >> 1) * wo2;
  int pxc = r1 % pc; int cls = r1 / pc;
  if (cls >= 4) return;
  int p0 = cls >> 1, q0 = cls & 1;
  int tx = pxc % wo2, ty = pxc / wo2;
  int oy = 2 * ty + 1 - p0, ox = 2 * tx + 1 - q0;
  int iy0 = (oy + 1 - p0) >> 1, ix0 = (ox + 1 - q0) >> 1;
  int mtile0 = mg * MT;
  f32x4 zero = {0.f, 0.f, 0.f, 0.f};
  f32x4 acc[MT][4];
  #pragma unroll
  for (int mt = 0; mt < MT; ++mt)
    #pragma unroll
    for (int nt = 0; nt < 4; ++nt) acc[mt][nt] = zero;
  const ushort* wbase = wp + ((size_t)cls * (COUT / 16) + mtile0) * NCH * 512 + lane * 8;
  const size_t mstride = (size_t)NCH * 512;
  bool interior = (iy0 >= 1) & (iy0 <= Hin - 1) & (ix0 >= 1) & (ix0 <= Win - 1);

  if (interior) {
    #pragma unroll
    for (int i = 0; i < 2; ++i) {
      int iy = iy0 - i;
      #pragma unroll
      for (int j = 0; j < 2; ++j) {
        int ix = ix0 - j;
        const ushort* ib = in + (size_t)(iy * Win + ix) * (CIN * 64) + lane * 8;
        int tap = i * 2 + j;
        #pragma unroll
        for (int kc = 0; kc < NKC; ++kc) {
          int kcg = tap * NKC + kc;
          bf16x8 a[MT], bb[4];
          #pragma unroll
          for (int mt = 0; mt < MT; ++mt)
            a[mt] = *(const bf16x8*)(wbase + mt * mstride + (size_t)kcg * 512);
          #pragma unroll
          for (int nt = 0; nt < 4; ++nt)
            bb[nt] = *(const bf16x8*)(ib + kc * 2048 + nt * 512);
          #pragma unroll
          for (int mt = 0; mt < MT; ++mt)
            #pragma unroll
            for (int nt = 0; nt < 4; ++nt)
              acc[mt][nt] = __builtin_amdgcn_mfma_f32_16x16x32_bf16(a[mt], bb[nt], acc[mt][nt], 0, 0, 0);
        }
      }
    }
  } else {
    for (int i = 0; i < 2; ++i) {
      int iy = iy0 - i;
      if ((unsigned)iy >= (unsigned)Hin) continue;
      for (int j = 0; j < 2; ++j) {
        int ix = ix0 - j;
        if ((unsigned)ix >= (unsigned)Win) continue;
        const ushort* ib = in + (size_t)(iy * Win + ix) * (CIN * 64) + lane * 8;
        int tap = i * 2 + j;
        #pragma unroll
        for (int kc = 0; kc < NKC; ++kc) {
          int kcg = tap * NKC + kc;
          bf16x8 a[MT], bb[4];
          #pragma unroll
          for (int mt = 0; mt < MT; ++mt)
            a[mt] = *(const bf16x8*)(wbase + mt * mstride + (size_t)kcg * 512);
          #pragma unroll
          for (int nt = 0; nt < 4; ++nt)
            bb[nt] = *(const bf16x8*)(ib + kc * 2048 + nt * 512);
          #pragma unroll
          for (int mt = 0; mt < MT; ++mt)
            #pragma unroll
            for (int nt = 0; nt < 4; ++nt)
              acc[mt][nt] = __builtin_amdgcn_mfma_f32_16x16x32_bf16(a[mt], bb[nt], acc[mt][nt], 0, 0, 0);
        }
      }
    }
  }
  int ml = lane & 15, rb = (lane >> 4) * 4;
  int px = oy * Wout + ox;
  #pragma unroll
  for (int mt = 0; mt < MT; ++mt) {
    int co = mtile0 * 16 + mt * 16 + rb;
    f32x4 bv = *(const f32x4*)(bias + co);
    #pragma unroll
    for (int nt = 0; nt < 4; ++nt) {
      float v0 = acc[mt][nt][0] + bv[0];
      float v1 = acc[mt][nt][1] + bv[1];
      float v2 = acc[mt][nt][2] + bv[2];
      float v3 = acc[mt][nt][3] + bv[3];
      if (RELU) { v0=fmaxf(v0,0.f); v1=fmaxf(v1,0.f); v2=fmaxf(v2,0.f); v3=fmaxf(v3,0.f); }
      uint2 pk;
      pk.x = (unsigned)f2bf(v0) | ((unsigned)f2bf(v1) << 16);
      pk.y = (unsigned)f2bf(v2) | ((unsigned)f2bf(v3) << 16);
      size_t off = (size_t)px * (COUT * 64) + (size_t)(co >> 5) * 2048 + (size_t)nt * NTS
                 + ((co >> 3) & 3) * 128 + ml * 8 + (co & 7);
      *(uint2*)(out + off) = pk;
    }
  }
}

// ================= enc_fc fused: LDS-transpose staging + MFMA =================
#define APXS 1032
__global__ __launch_bounds__(256) void k_encfc_fused(const ushort* __restrict__ h4,
                                                     const float* __restrict__ wE,
                                                     float* __restrict__ partial) {
  __shared__ float smem[8320];
  ushort* au = (ushort*)smem;
  int s = blockIdx.x;
  int bid = (s & 7) * 256 + (s >> 3);
  int mg = bid & 15;
  int ccf = (bid >> 4) & 7;
  int pxg = bid >> 7;
  int tid = threadIdx.x;
  int co0 = mg * 32;
  #pragma unroll
  for (int i = 0; i < 16; ++i) {
    int idx = tid + i * 256;
    int px4 = idx & 3;
    int ci_l = (idx >> 2) & 31;
    int co_l = idx >> 7;
    float4 v = *(const float4*)&wE[((size_t)(co0 + co_l) << 16)
                                   + (size_t)(ccf * 32 + ci_l) * 256 + pxg * 16 + px4 * 4];
    int mt = co_l >> 4, m = co_l & 15;
    int kg = ci_l >> 3, k8 = ci_l & 7;
    int base = mt * 512 + kg * 128 + m * 8 + k8;
    au[(px4 * 4 + 0) * APXS + base] = f2bf(v.x);
    au[(px4 * 4 + 1) * APXS + base] = f2bf(v.y);
    au[(px4 * 4 + 2) * APXS + base] = f2bf(v.z);
    au[(px4 * 4 + 3) * APXS + base] = f2bf(v.w);
  }
  __syncthreads();
  int lane = tid & 63, wv = tid >> 6;
  int ml = lane & 15, rb = (lane >> 4) * 4;
  f32x4 zero = {0.f, 0.f, 0.f, 0.f};
  f32x4 acc[2][4];
  #pragma unroll
  for (int mt = 0; mt < 2; ++mt)
    #pragma unroll
    for (int nt = 0; nt < 4; ++nt) acc[mt][nt] = zero;
  #pragma unroll
  for (int jj = 0; jj < 4; ++jj) {
    int j = wv * 4 + jj;
    int px = pxg * 16 + j;
    bf16x8 a0 = *(const bf16x8*)(au + j * APXS + lane * 8);
    bf16x8 a1 = *(const bf16x8*)(au + j * APXS + 512 + lane * 8);
    const ushort* hb = h4 + (size_t)px * 16384 + ccf * 2048 + lane * 8;
    bf16x8 bb[4];
    #pragma unroll
    for (int nt = 0; nt < 4; ++nt)
      bb[nt] = *(const bf16x8*)(hb + nt * 512);
    #pragma unroll
    for (int nt = 0; nt < 4; ++nt) {
      acc[0][nt] = __builtin_amdgcn_mfma_f32_16x16x32_bf16(a0, bb[nt], acc[0][nt], 0, 0, 0);
      acc[1][nt] = __builtin_amdgcn_mfma_f32_16x16x32_bf16(a1, bb[nt], acc[1][nt], 0, 0, 0);
    }
  }
  __syncthreads();
  #pragma unroll
  for (int mt = 0; mt < 2; ++mt)
    #pragma unroll
    for (int nt = 0; nt < 4; ++nt)
      #pragma unroll
      for (int r = 0; r < 4; ++r)
        smem[wv * 2080 + (mt * 16 + rb + r) * 65 + nt * 16 + ml] = acc[mt][nt][r];
  __syncthreads();
  int ks = pxg * 8 + ccf;
  #pragma unroll
  for (int i = 0; i < 8; ++i) {
    int e = tid + i * 256;
    int b = e & 63, co_l = e >> 6;
    float sum = smem[co_l * 65 + b] + smem[2080 + co_l * 65 + b]
              + smem[4160 + co_l * 65 + b] + smem[6240 + co_l * 65 + b];
    partial[((size_t)(co0 + co_l) * ENC_KS + ks) * 64 + b] = sum;
  }
}

__global__ void k_encfc_red(const float* __restrict__ partial, const float* __restrict__ bias,
                            float* __restrict__ cnn) {
  int id = blockIdx.x * blockDim.x + threadIdx.x;
  int o = id >> 6, b = id & 63;
  float acc = bias[o];
  #pragma unroll 8
  for (int s = 0; s < ENC_KS; ++s) acc += partial[((size_t)o * ENC_KS + s) * 64 + b];
  cnn[(size_t)b * 512 + o] = fmaxf(acc, 0.f);
}

// ================= fused posterior + reparam: 1024-thread k-split, powT2 =================
__global__ __launch_bounds__(1024) void k_postz(const float* __restrict__ cnn,
                                                const float* __restrict__ belief,
                                                const float* __restrict__ powT,
                                                const float* __restrict__ bias,
                                                const float* __restrict__ eps,
                                                float* __restrict__ out,
                                                ushort* __restrict__ zb) {
  __shared__ float cs[512];
  __shared__ float bs[512];
  __shared__ float smv[512];
  __shared__ float red[512];
  int b = blockIdx.x;
  int tid = threadIdx.x;
  int j = tid & 511;
  int half = tid >> 9;
  if (tid < 512) cs[tid] = cnn[(size_t)b * HIDD + tid];
  else           bs[tid - 512] = belief[(size_t)b * HIDD + (tid - 512)];
  __syncthreads();
  float acc = half ? 0.f : bias[j];
  const float* wb = powT + (size_t)(half * 256) * 1024 + j * 2;
  const float* src = half ? bs : cs;
  #pragma unroll 4
  for (int p = 0; p < 256; ++p) {
    float2 w2 = *(const float2*)(wb + (size_t)p * 1024);
    acc += src[2 * p] * w2.x + src[2 * p + 1] * w2.y;
  }
  if (half) red[j] = acc;
  __syncthreads();
  if (!half) {
    float t = acc + red[j];
    smv[j] = t;
    if (j < 256) out[O_MUPO + b * 256 + j] = t;
    else         out[O_LVPO + b * 256 + (j - 256)] = t;
  }
  __syncthreads();
  if (tid < 256) {
    float z = smv[tid] + eps[b * 256 + tid] * expf(0.5f * smv[tid + 256]);
    out[O_ZT + b * 256 + tid] = z;
    if (tid < 128) zb[b * 128 + tid] = f2bf(z);
  }
}

// ================= dec_fc MFMA: direct f32 weights, frag-order out =================
__global__ __launch_bounds__(256) void k_decfc_mfma(const ushort* __restrict__ zb,
                                                    const float* __restrict__ dfw,
                                                    const float* __restrict__ dfb,
                                                    ushort* __restrict__ dec) {
  int wid = __builtin_amdgcn_readfirstlane(blockIdx.x * 4 + (threadIdx.x >> 6));
  int lane = threadIdx.x & 63;
  int m0 = wid * 32;
  int ml = lane & 15, kl = (lane >> 4) * 8;
  f32x4 zero = {0.f, 0.f, 0.f, 0.f};
  f32x4 acc[2][4];
  #pragma unroll
  for (int mt = 0; mt < 2; ++mt)
    #pragma unroll
    for (int nt = 0; nt < 4; ++nt) acc[mt][nt] = zero;
  #pragma unroll
  for (int kc = 0; kc < 4; ++kc) {
    bf16x8 a[2], bb[4];
    #pragma unroll
    for (int mt = 0; mt < 2; ++mt) {
      int m_r = m0 + mt * 16 + ml;
      const float* wr = dfw + (size_t)((m_r & 127) * 256 + (m_r >> 7)) * 128 + kc * 32 + kl;
      float4 u0 = *(const float4*)wr;
      float4 u1 = *(const float4*)(wr + 4);
      bf16x8 av;
      av[0] = (short)f2bf(u0.x); av[1] = (short)f2bf(u0.y);
      av[2] = (short)f2bf(u0.z); av[3] = (short)f2bf(u0.w);
      av[4] = (short)f2bf(u1.x); av[5] = (short)f2bf(u1.y);
      av[6] = (short)f2bf(u1.z); av[7] = (short)f2bf(u1.w);
      a[mt] = av;
    }
    #pragma unroll
    for (int nt = 0; nt < 4; ++nt)
      bb[nt] = *(const bf16x8*)(zb + (size_t)(nt * 16 + ml) * 128 + kc * 32 + kl);
    #pragma unroll
    for (int mt = 0; mt < 2; ++mt)
      #pragma unroll
      for (int nt = 0; nt < 4; ++nt)
        acc[mt][nt] = __builtin_amdgcn_mfma_f32_16x16x32_bf16(a[mt], bb[nt], acc[mt][nt], 0, 0, 0);
  }
  int rb = (lane >> 4) * 4;
  #pragma unroll
  for (int mt = 0; mt < 2; ++mt) {
    int m = m0 + mt * 16 + rb;
    int pix = m >> 7, co = m & 127;
    float bv0 = dfb[(size_t)(co + 0) * 256 + pix];
    float bv1 = dfb[(size_t)(co + 1) * 256 + pix];
    float bv2 = dfb[(size_t)(co + 2) * 256 + pix];
    float bv3 = dfb[(size_t)(co + 3) * 256 + pix];
    #pragma unroll
    for (int nt = 0; nt < 4; ++nt) {
      uint2 pk;
      pk.x = (unsigned)f2bf(acc[mt][nt][0] + bv0) | ((unsigned)f2bf(acc[mt][nt][1] + bv1) << 16);
      pk.y = (unsigned)f2bf(acc[mt][nt][2] + bv2) | ((unsigned)f2bf(acc[mt][nt][3] + bv3) << 16);
      size_t off = (size_t)pix * 8192 + (size_t)(co >> 5) * 2048 + nt * 512
                 + ((co >> 3) & 3) * 128 + ml * 8 + (co & 7);
      *(uint2*)(dec + off) = pk;
    }
  }
}

// ================= d4 fused with output transpose =================
__global__ __launch_bounds__(256) void k_d4t(const ushort* __restrict__ in,
                                             const float* __restrict__ w,
                                             const float* __restrict__ bias,
                                             float* __restrict__ out) {
  __shared__ float lds[64][65];
  int blk = blockIdx.x;
  int oy = blk >> 2, ox0 = (blk & 3) << 6;
  int t = threadIdx.x;
  int b = t & 63, sub = t >> 6;
  float bv = bias[0];
  for (int j = 0; j < 16; ++j) {
    int oxl = j * 4 + sub;
    int ox = ox0 + oxl;
    int p0 = (oy + 1) & 1, q0 = (ox + 1) & 1;
    int iy0 = (oy + 1 - p0) >> 1, ix0 = (ox + 1 - q0) >> 1;
    float acc = bv;
    #pragma unroll
    for (int i = 0; i < 2; ++i) {
      int iy = iy0 - i;
      if ((unsigned)iy >= 128u) continue;
      int p = p0 + 2 * i;
      #pragma unroll
      for (int jj = 0; jj < 2; ++jj) {
        int ix = ix0 - jj;
        if ((unsigned)ix >= 128u) continue;
        int q = q0 + 2 * jj;
        const ushort* base = in + (size_t)(iy * 128 + ix) * 1024 + (b >> 4) * 256 + (b & 15) * 8;
        bf16x8 v0 = *(const bf16x8*)(base);
        bf16x8 v1 = *(const bf16x8*)(base + 128);
        const float* wq = w + p * 4 + q;
        #pragma unroll
        for (int ci = 0; ci < 8; ++ci) acc += bf2f((ushort)v0[ci]) * wq[ci * 16];
        #pragma unroll
        for (int ci = 0; ci < 8; ++ci) acc += bf2f((ushort)v1[ci]) * wq[(ci + 8) * 16];
      }
    }
    lds[oxl][b] = acc;
  }
  __syncthreads();
  #pragma unroll
  for (int j = 0; j < 16; ++j) {
    int idx = t + j * 256;
    int b2 = idx >> 6, oxl = idx & 63;
    out[(size_t)b2 * 65536 + oy * 256 + ox0 + oxl] = lds[oxl][b2];
  }
}

// ================= launch =================

extern "C" void kernel_launch(void* const* d_in, const int* in_sizes, int n_in,
                              void* d_out, int out_size, void* d_ws, size_t ws_size,
                              hipStream_t stream) {
  const float* img      = (const float*)d_in[0];
  const float* act      = (const float*)d_in[1];
  const float* z_prev   = (const float*)d_in[2];
  const float* st_prev  = (const float*)d_in[3];
  const float* eps      = (const float*)d_in[4];
  const float* c1w = (const float*)d_in[5];  const float* c1b = (const float*)d_in[6];
  const float* c2w = (const float*)d_in[7];  const float* c2b = (const float*)d_in[8];
  const float* c3w = (const float*)d_in[9];  const float* c3b = (const float*)d_in[10];
  const float* c4w = (const float*)d_in[11]; const float* c4b = (const float*)d_in[12];
  const float* efw = (const float*)d_in[13]; const float* efb = (const float*)d_in[14];
  const float* pow_ = (const float*)d_in[15]; const float* pob = (const float*)d_in[16];
  const float* prw = (const float*)d_in[17]; const float* prb = (const float*)d_in[18];
  const float* siw = (const float*)d_in[19]; const float* sib = (const float*)d_in[20];
  const float* Alog = (const float*)d_in[21];
  const float* Bw = (const float*)d_in[22];  const float* Cw = (const float*)d_in[23];
  const float* Dw = (const float*)d_in[24];  const float* Db = (const float*)d_in[25];
  const float* Dv = (const float*)d_in[26];
  const float* dfw = (const float*)d_in[27]; const float* dfb = (const float*)d_in[28];
  const float* d1w = (const float*)d_in[29]; const float* d1b = (const float*)d_in[30];
  const float* d2w = (const float*)d_in[31]; const float* d2b = (const float*)d_in[32];
  const float* d3w = (const float*)d_in[33]; const float* d3b = (const float*)d_in[34];
  const float* d4w = (const float*)d_in[35]; const float* d4b = (const float*)d_in[36];

  float* ws = (float*)d_ws;
  float* out = (float*)d_out;

  ushort* pc2 = (ushort*)(ws + PW_C2);
  ushort* pc3 = (ushort*)(ws + PW_C3);
  ushort* pc4 = (ushort*)(ws + PW_C4);
  ushort* pd1 = (ushort*)(ws + PW_D1);
  ushort* pd2 = (ushort*)(ws + PW_D2);
  ushort* pd3 = (ushort*)(ws + PW_D3);
  ushort* pc1 = (ushort*)(ws + PW_C1);
  ushort* timg4 = (ushort*)(ws + W_TIMG);
  ushort* h1b = (ushort*)(ws + W_H1B);
  ushort* h2b = (ushort*)(ws + W_H2B);
  ushort* h3b = (ushort*)(ws + W_H3B);
  ushort* h4b = (ushort*)(ws + W_H4B);
  ushort* deco = (ushort*)(ws + W_DECO);
  ushort* d1o = (ushort*)(ws + W_D1O);
  ushort* d2o = (ushort*)(ws + W_D2O);
  ushort* d3o = (ushort*)(ws + W_D3O);
  ushort* zb = (ushort*)(ws + W_ZB16);
  float* siwT = ws + W_SIWT;
  float* DwT  = ws + W_DWT;
  float* prwT = ws + W_PRWT;
  float* powT = ws + W_POWT;

  // ---- merged weight prepack (pair-interleaved dense transposes) ----
  k_pack_all<<<7988, 256, 0, stream>>>(c2w, c3w, c4w, d1w, d2w, d3w, c1w,
                                       siw, Dw, prw, pow_,
                                       pc2, pc3, pc4, pd1, pd2, pd3, pc1,
                                       siwT, DwT, prwT, powT);

  // ---- SSM (k-split) || img transpose, both post-pack ----
  k_ssm_timg<<<1088, 1024, 0, stream>>>(z_prev, act, siwT, sib, DwT, Db, Bw, Cw,
                                        Alog, Dv, st_prev, out + O_STATE,
                                        ws + W_BELIEF, prwT, prb, out,
                                        img, timg4);

  // ---- encoder ----
  k_conv1_mfma<<<4096, 256, 0, stream>>>(timg4, pc1, c1b, h1b);
  mfma_conv<32, 64, 4><<<1024, 256, 0, stream>>>(h1b, pc2, c2b, h2b, 128, 128, 64, 64);
  mfma_conv<64, 128, 4><<<512, 256, 0, stream>>>(h2b, pc3, c3b, h3b, 64, 64, 32, 32);
  mfma_conv<128, 256, 2><<<512, 256, 0, stream>>>(h3b, pc4, c4b, h4b, 32, 32, 16, 16);

  // ---- enc_fc (fused transpose+GEMM) ----
  k_encfc_fused<<<2048, 256, 0, stream>>>(h4b, efw, ws + W_ENCP);
  k_encfc_red<<<128, 256, 0, stream>>>(ws + W_ENCP, efb, ws + W_CNN);

  // ---- fused posterior + reparam (k-split) ----
  k_postz<<<64, 1024, 0, stream>>>(ws + W_CNN, ws + W_BELIEF, powT, pob, eps, out, zb);

  // ---- decoder ----
  k_decfc_mfma<<<256, 256, 0, stream>>>(zb, dfw, dfb, deco);
  mfma_deconv<128, 64, 2, true><<<512, 256, 0, stream>>>(deco, pd1, d1b, d1o, 16, 16, 32, 32);
  mfma_deconv<64, 32, 2, true><<<1024, 256, 0, stream>>>(d1o, pd2, d2b, d2o, 32, 32, 64, 64);
  mfma_deconv<32, 16, 1, true><<<4096, 256, 0, stream>>>(d2o, pd3, d3b, d3o, 64, 64, 128, 128);
  k_d4t<<<1024, 256, 0, stream>>>(d3o, d4w, d4b, out + O_PRED);
}

// Round 16
// 357.185 us; speedup vs baseline: 1.2524x; 1.1230x over previous
//
#include <hip/hip_runtime.h>
#include <math.h>

#define BB 64
#define LATENT 256
#define ACTD 6
#define HIDD 512
#define DST 16

typedef __attribute__((ext_vector_type(8))) short bf16x8;
typedef __attribute__((ext_vector_type(4))) float f32x4;

static __device__ __forceinline__ ushort f2bf(float f) {
  unsigned u = __builtin_bit_cast(unsigned, f);
  unsigned r = (u + 0x7FFFu + ((u >> 16) & 1u)) >> 16;
  return (ushort)r;
}
static __device__ __forceinline__ float bf2f(ushort u) {
  return __builtin_bit_cast(float, ((unsigned)u) << 16);
}

// ---------------- output offsets (floats) ----------------
#define O_PRED   0
#define O_ZT     4194304
#define O_STATE  4210688
#define O_MUP    4734976
#define O_LVP    4751360
#define O_MUPO   4767744
#define O_LVPO   4784128

// ---------------- ws offsets (floats), lifetime-reused ----------------
#define W_BELIEF 67584u
#define W_CNN    100352u
#define W_ZB16   133120u
#define PW_C2    137216u
#define PW_C3    153600u
#define PW_C4    219136u
#define PW_D1    481280u
#define PW_D2    546816u
#define PW_D3    563200u
#define PW_C1    567296u
#define W_TIMG   602112u      // timg4 bf16 [65536][64][4]
#define W_H1B    13185024u
#define W_H2B    29962240u
#define W_H3B    38350848u
#define W_H4B    42545152u
// bf16 4-grouped transposed dense weights (u16), after H4B:
#define W_SIWT   44642304u    // 135,168 u16 = 67,584 f
#define W_DWT    44709888u    // 262,144 u16 = 131,072 f
#define W_PRWT   44840960u    // 262,144 u16
#define W_POWT   44972032u    // 524,288 u16 (ends 45,234,176 f)
// reuse:
#define W_ENCP   602112u
#define W_DECO   8990720u
#define W_D1O    10039296u
#define W_D2O    13185024u
#define W_D3O    17379328u

#define ENC_KS 128

// ================= merged weight prepack =================

static __device__ __forceinline__ void pack_conv_elem(const float* __restrict__ w,
                                                      ushort* __restrict__ o,
                                                      int Cout, int Cin, int id) {
  int NCH = Cin / 2;
  int per = NCH * 512;
  int mt = id / per, r = id % per;
  int kcg = r >> 9, s = r & 511;
  int kg = s >> 7, m = (s >> 3) & 15, k8 = s & 7;
  int co = mt * 16 + m;
  int k = kcg * 32 + kg * 8 + k8;
  int tap = k / Cin, ci = k % Cin;
  o[id] = f2bf(w[(size_t)(co * Cin + ci) * 16 + tap]);
}

static __device__ __forceinline__ void pack_deconv_elem(const float* __restrict__ w,
                                                        ushort* __restrict__ o,
                                                        int Cout, int Cin, int id) {
  int NCH = Cin / 8;
  int perM = NCH * 512;
  int perC = (Cout / 16) * perM;
  int cls = id / perC, r = id % perC;
  int mt = r / perM, r2 = r % perM;
  int kcg = r2 >> 9, s = r2 & 511;
  int kg = s >> 7, m = (s >> 3) & 15, k8 = s & 7;
  int co = mt * 16 + m;
  int k = kcg * 32 + kg * 8 + k8;
  int t = k / Cin, ci = k % Cin;
  int p = (cls >> 1) + 2 * (t >> 1);
  int q = (cls & 1) + 2 * (t & 1);
  o[id] = f2bf(w[(size_t)(ci * Cout + co) * 16 + p * 4 + q]);
}

static __device__ __forceinline__ void pack_conv1_elem(const float* __restrict__ w,
                                                       ushort* __restrict__ o, int id) {
  int mt = id >> 10, r = id & 1023;
  int kcg = r >> 9, s = r & 511;
  int kg = s >> 7, m = (s >> 3) & 15, k8 = s & 7;
  int co = mt * 16 + m;
  int k = kcg * 32 + kg * 8 + k8;
  int tap = k >> 2, ci = k & 3;
  o[id] = (ci < 3) ? f2bf(w[(size_t)(co * 3 + ci) * 16 + tap]) : (ushort)0;
}

__global__ __launch_bounds__(256) void k_pack_all(
    const float* __restrict__ c2w, const float* __restrict__ c3w,
    const float* __restrict__ c4w, const float* __restrict__ d1w,
    const float* __restrict__ d2w, const float* __restrict__ d3w,
    const float* __restrict__ c1w,
    const float* __restrict__ siw, const float* __restrict__ Dw,
    const float* __restrict__ prw, const float* __restrict__ pw,
    ushort* __restrict__ pc2, ushort* __restrict__ pc3, ushort* __restrict__ pc4,
    ushort* __restrict__ pd1, ushort* __restrict__ pd2, ushort* __restrict__ pd3,
    ushort* __restrict__ pc1,
    ushort* __restrict__ siwT, ushort* __restrict__ DwT,
    ushort* __restrict__ prwT, ushort* __restrict__ powT) {
  int id = blockIdx.x * 256 + threadIdx.x;
  if (id < 32768)            pack_conv_elem(c2w, pc2, 64, 32, id);
  else if (id < 163840)      pack_conv_elem(c3w, pc3, 128, 64, id - 32768);
  else if (id < 688128)      pack_conv_elem(c4w, pc4, 256, 128, id - 163840);
  else if (id < 819200)      pack_deconv_elem(d1w, pd1, 64, 128, id - 688128);
  else if (id < 851968)      pack_deconv_elem(d2w, pd2, 32, 64, id - 819200);
  else if (id < 860160)      pack_deconv_elem(d3w, pd3, 16, 32, id - 851968);
  else if (id < 862208)      pack_conv1_elem(c1w, pc1, id - 860160);
  else if (id < 997376) {    // siwT4 [66][512][4] bf16, K padded 262->264
    int r = id - 862208;
    int q = r >> 11, h = (r & 2047) >> 2, e = r & 3;
    int k = q * 4 + e;
    siwT[r] = (k < LATENT + ACTD) ? f2bf(siw[(size_t)h * (LATENT + ACTD) + k]) : (ushort)0;
  } else if (id < 1259520) { // DwT4 [128][512][4] bf16
    int r = id - 997376;
    int q = r >> 11, h = (r & 2047) >> 2, e = r & 3;
    DwT[r] = f2bf(Dw[(size_t)h * HIDD + q * 4 + e]);
  } else if (id < 1521664) { // prwT4 [128][512][4] bf16
    int r = id - 1259520;
    int q = r >> 11, h = (r & 2047) >> 2, e = r & 3;
    prwT[r] = f2bf(prw[(size_t)h * HIDD + q * 4 + e]);
  } else if (id < 2045952) { // powT4 [256][512][4] bf16
    int r = id - 1521664;
    int q = r >> 11, j2 = (r & 2047) >> 2, e = r & 3;
    powT[r] = f2bf(pw[(size_t)j2 * 1024 + q * 4 + e]);
  }
}

// ================= merged SSM (blocks 0..63, k-split, bf16 weights) + img transpose =================
__global__ __launch_bounds__(1024) void k_ssm_timg(
    const float* __restrict__ z_prev, const float* __restrict__ act,
    const ushort* __restrict__ siwT, const float* __restrict__ sib,
    const ushort* __restrict__ DwT, const float* __restrict__ Db,
    const float* __restrict__ Bw, const float* __restrict__ Cw,
    const float* __restrict__ Alog, const float* __restrict__ Dv,
    const float* __restrict__ st_prev, float* __restrict__ state_out,
    float* __restrict__ belief_out, const ushort* __restrict__ prwT,
    const float* __restrict__ prb, float* __restrict__ out,
    const float* __restrict__ img, ushort* __restrict__ timg4) {
  __shared__ float sm[12480];
  int blk = blockIdx.x;
  int tid = threadIdx.x;

  if (blk < 64) {
    // arena: xs 264 | si 512 | bel 512 | red 512 | part 128 | btct 32
    float* xs   = sm;
    float* si   = sm + 264;
    float* bel  = sm + 776;
    float* red  = sm + 1288;
    float* part = sm + 1800;
    float* btct = sm + 1928;
    int b = blk;
    int h = tid & 511;
    int half = tid >> 9;
    if (tid < 256) xs[tid] = z_prev[(size_t)b * LATENT + tid];
    else if (tid < 256 + ACTD) xs[tid] = act[(size_t)b * ACTD + (tid - 256)];
    else if (tid < 264) xs[tid] = 0.f;
    __syncthreads();
    // ---- ssm_in: 66 k-groups of 4, split 33/33 ----
    {
      float acc = half ? 0.f : sib[h];
      const ushort* wb = siwT + (size_t)(half * 33) * 2048 + h * 4;
      const float* xb = xs + half * 132;
      #pragma unroll 4
      for (int p = 0; p < 33; ++p) {
        ushort4 w4 = *(const ushort4*)(wb + (size_t)p * 2048);
        acc += xb[4*p]   * bf2f(w4.x) + xb[4*p+1] * bf2f(w4.y)
             + xb[4*p+2] * bf2f(w4.z) + xb[4*p+3] * bf2f(w4.w);
      }
      if (half) red[h] = acc;
      __syncthreads();
      if (!half) {
        float t = acc + red[h];
        si[h] = t / (1.f + expf(-t));
      }
    }
    __syncthreads();
    // ---- delta: 128 k-groups of 4, split 64/64 ----
    float d = 0.f;
    {
      float acc = half ? 0.f : Db[h];
      const ushort* wb = DwT + (size_t)(half * 64) * 2048 + h * 4;
      const float* sb = si + half * 256;
      #pragma unroll 4
      for (int p = 0; p < 64; ++p) {
        ushort4 w4 = *(const ushort4*)(wb + (size_t)p * 2048);
        acc += sb[4*p]   * bf2f(w4.x) + sb[4*p+1] * bf2f(w4.y)
             + sb[4*p+2] * bf2f(w4.z) + sb[4*p+3] * bf2f(w4.w);
      }
      if (half) red[h] = acc;
      __syncthreads();
      if (!half) {
        float t = acc + red[h];
        d = fmaxf(t, 0.f) + log1pf(expf(-fabsf(t)));
      }
    }
    // ---- B_t/C_t partials (tid<128, all half0) ----
    if (tid < 128) {
      int hf2 = tid >> 6;
      int l = tid & 63;
      int n = l & 15, p = l >> 4;
      const float* wr = (hf2 ? Cw : Bw) + (size_t)n * HIDD + p * 128;
      const float* sr = si + p * 128;
      float a2 = 0.f;
      #pragma unroll 4
      for (int k = 0; k < 128; k += 4) {
        float4 w4 = *(const float4*)(wr + k);
        a2 += sr[k] * w4.x + sr[k+1] * w4.y + sr[k+2] * w4.z + sr[k+3] * w4.w;
      }
      part[(hf2 * 16 + n) * 4 + p] = a2;
    }
    __syncthreads();
    if (tid < 32) {
      int hf2 = tid >> 4, n = tid & 15;
      const float* pp = part + (hf2 * 16 + n) * 4;
      btct[hf2 * 16 + n] = pp[0] + pp[1] + pp[2] + pp[3];
    }
    __syncthreads();
    // ---- state + belief (half0) ----
    if (!half) {
      float si_h = si[h];
      float belv = Dv[h] * si_h;
      const float* al = Alog + (size_t)h * DST;
      const float* sp = st_prev + ((size_t)b * 512 + h) * DST;
      float* so = state_out + ((size_t)b * 512 + h) * DST;
      #pragma unroll
      for (int n = 0; n < DST; ++n) {
        float A = -expf(al[n]);
        float st = expf(d * A) * sp[n] + d * btct[n] * si_h;
        so[n] = st;
        belv += st * btct[16 + n];
      }
      bel[h] = belv;
      belief_out[(size_t)b * 512 + h] = belv;
    }
    __syncthreads();
    // ---- prior: 128 k-groups of 4, split 64/64 ----
    {
      float acc = half ? 0.f : prb[h];
      const ushort* wb = prwT + (size_t)(half * 64) * 2048 + h * 4;
      const float* bb2 = bel + half * 256;
      #pragma unroll 4
      for (int p = 0; p < 64; ++p) {
        ushort4 w4 = *(const ushort4*)(wb + (size_t)p * 2048);
        acc += bb2[4*p]   * bf2f(w4.x) + bb2[4*p+1] * bf2f(w4.y)
             + bb2[4*p+2] * bf2f(w4.z) + bb2[4*p+3] * bf2f(w4.w);
      }
      if (half) red[h] = acc;
      __syncthreads();
      if (!half) {
        float t = acc + red[h];
        if (h < 256) out[O_MUP + b * 256 + h] = t;
        else         out[O_LVP + b * 256 + (h - 256)] = t;
      }
    }
  } else {
    // ---------- img -> [px][64b][4ci] bf16 ----------
    float (*ts)[64][65] = (float (*)[64][65])sm;
    int p0 = (blk - 64) << 6;
    #pragma unroll
    for (int c = 0; c < 3; ++c) {
      #pragma unroll
      for (int i = 0; i < 4; ++i) {
        int idx = tid + i * 1024;
        int b = idx >> 6, pr = idx & 63;
        ts[c][pr][b] = img[((size_t)b * 3 + c) * 65536 + p0 + pr];
      }
    }
    __syncthreads();
    #pragma unroll
    for (int i = 0; i < 4; ++i) {
      int idx = tid + i * 1024;
      int pr = idx >> 6, b = idx & 63;
      uint2 pk;
      pk.x = (unsigned)f2bf(ts[0][pr][b]) | ((unsigned)f2bf(ts[1][pr][b]) << 16);
      pk.y = (unsigned)f2bf(ts[2][pr][b]);
      *(uint2*)(timg4 + ((size_t)(p0 + pr) * 64 + b) * 4) = pk;
    }
  }
}

// ================= conv1 MFMA =================
__global__ __launch_bounds__(256) void k_conv1_mfma(const ushort* __restrict__ in,
                                                    const ushort* __restrict__ wp,
                                                    const float* __restrict__ bias,
                                                    ushort* __restrict__ out) {
  int wid = __builtin_amdgcn_readfirstlane(blockIdx.x * 4 + (threadIdx.x >> 6));
  int lane = threadIdx.x & 63;
  int ox = wid & 127, oy = wid >> 7;
  int ml = lane & 15, khi = lane >> 4;
  f32x4 zero = {0.f, 0.f, 0.f, 0.f};
  f32x4 acc[2][4];
  #pragma unroll
  for (int mt = 0; mt < 2; ++mt)
    #pragma unroll
    for (int nt = 0; nt < 4; ++nt) acc[mt][nt] = zero;
  int by = 2 * oy - 1, bx = 2 * ox - 1;
  bool interior = (oy >= 1) & (oy <= 126) & (ox >= 1) & (ox <= 126);

  #pragma unroll
  for (int kc = 0; kc < 2; ++kc) {
    bf16x8 a0 = *(const bf16x8*)(wp + kc * 512 + lane * 8);
    bf16x8 a1 = *(const bf16x8*)(wp + 1024 + kc * 512 + lane * 8);
    int t0 = kc * 8 + khi * 2;
    int ky0 = t0 >> 2, kx0 = t0 & 3;
    int ky1 = (t0 + 1) >> 2, kx1 = (t0 + 1) & 3;
    int iy0 = by + ky0, ix0 = bx + kx0;
    int iy1 = by + ky1, ix1 = bx + kx1;
    const ushort* pA = in + ((size_t)(iy0 * 256 + ix0) * 64 + ml) * 4;
    const ushort* pB = in + ((size_t)(iy1 * 256 + ix1) * 64 + ml) * 4;
    if (interior) {
      #pragma unroll
      for (int nt = 0; nt < 4; ++nt) {
        uint2 lo = *(const uint2*)(pA + nt * 64);
        uint2 hi = *(const uint2*)(pB + nt * 64);
        uint4 u; u.x = lo.x; u.y = lo.y; u.z = hi.x; u.w = hi.y;
        bf16x8 bb = __builtin_bit_cast(bf16x8, u);
        acc[0][nt] = __builtin_amdgcn_mfma_f32_16x16x32_bf16(a0, bb, acc[0][nt], 0, 0, 0);
        acc[1][nt] = __builtin_amdgcn_mfma_f32_16x16x32_bf16(a1, bb, acc[1][nt], 0, 0, 0);
      }
    } else {
      bool ok0 = ((unsigned)iy0 < 256u) & ((unsigned)ix0 < 256u);
      bool ok1 = ((unsigned)iy1 < 256u) & ((unsigned)ix1 < 256u);
      #pragma unroll
      for (int nt = 0; nt < 4; ++nt) {
        uint2 z2; z2.x = 0u; z2.y = 0u;
        uint2 lo = ok0 ? *(const uint2*)(pA + nt * 64) : z2;
        uint2 hi = ok1 ? *(const uint2*)(pB + nt * 64) : z2;
        uint4 u; u.x = lo.x; u.y = lo.y; u.z = hi.x; u.w = hi.y;
        bf16x8 bb = __builtin_bit_cast(bf16x8, u);
        acc[0][nt] = __builtin_amdgcn_mfma_f32_16x16x32_bf16(a0, bb, acc[0][nt], 0, 0, 0);
        acc[1][nt] = __builtin_amdgcn_mfma_f32_16x16x32_bf16(a1, bb, acc[1][nt], 0, 0, 0);
      }
    }
  }
  int px = oy * 128 + ox;
  int rb = khi * 4;
  #pragma unroll
  for (int mt = 0; mt < 2; ++mt) {
    int co = mt * 16 + rb;
    f32x4 bv = *(const f32x4*)(bias + co);
    #pragma unroll
    for (int nt = 0; nt < 4; ++nt) {
      float v0 = fmaxf(acc[mt][nt][0] + bv[0], 0.f);
      float v1 = fmaxf(acc[mt][nt][1] + bv[1], 0.f);
      float v2 = fmaxf(acc[mt][nt][2] + bv[2], 0.f);
      float v3 = fmaxf(acc[mt][nt][3] + bv[3], 0.f);
      uint2 pk;
      pk.x = (unsigned)f2bf(v0) | ((unsigned)f2bf(v1) << 16);
      pk.y = (unsigned)f2bf(v2) | ((unsigned)f2bf(v3) << 16);
      size_t off = (size_t)px * 2048 + nt * 512 + ((co >> 3) & 3) * 128 + ml * 8 + (co & 7);
      *(uint2*)(out + off) = pk;
    }
  }
}

// ================= MFMA conv, interior fast path =================
template<int CIN, int COUT, int MT>
__global__ __launch_bounds__(256) void mfma_conv(const ushort* __restrict__ in,
                                                 const ushort* __restrict__ wp,
                                                 const float* __restrict__ bias,
                                                 ushort* __restrict__ out,
                                                 int Hin, int Win, int Hout, int Wout) {
  constexpr int NMG = COUT / (16 * MT);
  constexpr int NKC = CIN / 32;
  constexpr int NCH = 16 * NKC;
  int wid = __builtin_amdgcn_readfirstlane(blockIdx.x * 4 + (threadIdx.x >> 6));
  int lane = threadIdx.x & 63;
  int mg = wid % NMG;
  int px = wid / NMG;
  int ox = px % Wout, oy = px / Wout;
  if (oy >= Hout) return;
  int mtile0 = mg * MT;
  f32x4 zero = {0.f, 0.f, 0.f, 0.f};
  f32x4 acc[MT][4];
  #pragma unroll
  for (int mt = 0; mt < MT; ++mt)
    #pragma unroll
    for (int nt = 0; nt < 4; ++nt) acc[mt][nt] = zero;
  const ushort* wbase = wp + (size_t)mtile0 * NCH * 512 + lane * 8;
  const size_t mstride = (size_t)NCH * 512;
  bool interior = (oy >= 1) & (oy < Hout - 1) & (ox >= 1) & (ox < Wout - 1);

  if (interior) {
    #pragma unroll
    for (int ky = 0; ky < 4; ++ky) {
      int iy = 2 * oy - 1 + ky;
      #pragma unroll
      for (int kx = 0; kx < 4; ++kx) {
        int ix = 2 * ox - 1 + kx;
        const ushort* ib = in + (size_t)(iy * Win + ix) * (CIN * 64) + lane * 8;
        int tap = ky * 4 + kx;
        #pragma unroll
        for (int kc = 0; kc < NKC; ++kc) {
          int kcg = tap * NKC + kc;
          bf16x8 a[MT], bb[4];
          #pragma unroll
          for (int mt = 0; mt < MT; ++mt)
            a[mt] = *(const bf16x8*)(wbase + mt * mstride + (size_t)kcg * 512);
          #pragma unroll
          for (int nt = 0; nt < 4; ++nt)
            bb[nt] = *(const bf16x8*)(ib + kc * 2048 + nt * 512);
          #pragma unroll
          for (int mt = 0; mt < MT; ++mt)
            #pragma unroll
            for (int nt = 0; nt < 4; ++nt)
              acc[mt][nt] = __builtin_amdgcn_mfma_f32_16x16x32_bf16(a[mt], bb[nt], acc[mt][nt], 0, 0, 0);
        }
      }
    }
  } else {
    for (int ky = 0; ky < 4; ++ky) {
      int iy = 2 * oy - 1 + ky;
      if ((unsigned)iy >= (unsigned)Hin) continue;
      for (int kx = 0; kx < 4; ++kx) {
        int ix = 2 * ox - 1 + kx;
        if ((unsigned)ix >= (unsigned)Win) continue;
        const ushort* ib = in + (size_t)(iy * Win + ix) * (CIN * 64) + lane * 8;
        int tap = ky * 4 + kx;
        #pragma unroll
        for (int kc = 0; kc < NKC; ++kc) {
          int kcg = tap * NKC + kc;
          bf16x8 a[MT], bb[4];
          #pragma unroll
          for (int mt = 0; mt < MT; ++mt)
            a[mt] = *(const bf16x8*)(wbase + mt * mstride + (size_t)kcg * 512);
          #pragma unroll
          for (int nt = 0; nt < 4; ++nt)
            bb[nt] = *(const bf16x8*)(ib + kc * 2048 + nt * 512);
          #pragma unroll
          for (int mt = 0; mt < MT; ++mt)
            #pragma unroll
            for (int nt = 0; nt < 4; ++nt)
              acc[mt][nt] = __builtin_amdgcn_mfma_f32_16x16x32_bf16(a[mt], bb[nt], acc[mt][nt], 0, 0, 0);
        }
      }
    }
  }
  int ml = lane & 15, rb = (lane >> 4) * 4;
  #pragma unroll
  for (int mt = 0; mt < MT; ++mt) {
    int co = mtile0 * 16 + mt * 16 + rb;
    f32x4 bv = *(const f32x4*)(bias + co);
    #pragma unroll
    for (int nt = 0; nt < 4; ++nt) {
      float v0 = fmaxf(acc[mt][nt][0] + bv[0], 0.f);
      float v1 = fmaxf(acc[mt][nt][1] + bv[1], 0.f);
      float v2 = fmaxf(acc[mt][nt][2] + bv[2], 0.f);
      float v3 = fmaxf(acc[mt][nt][3] + bv[3], 0.f);
      uint2 pk;
      pk.x = (unsigned)f2bf(v0) | ((unsigned)f2bf(v1) << 16);
      pk.y = (unsigned)f2bf(v2) | ((unsigned)f2bf(v3) << 16);
      size_t off = (size_t)px * (COUT * 64) + (size_t)(co >> 5) * 2048 + nt * 512
                 + ((co >> 3) & 3) * 128 + ml * 8 + (co & 7);
      *(uint2*)(out + off) = pk;
    }
  }
}

// ================= MFMA transposed conv, interior fast path =================
template<int CIN, int COUT, int MT, bool RELU>
__global__ __launch_bounds__(256) void mfma_deconv(const ushort* __restrict__ in,
                                                   const ushort* __restrict__ wp,
                                                   const float* __restrict__ bias,
                                                   ushort* __restrict__ out,
                                                   int Hin, int Win, int Hout, int Wout) {
  constexpr int NMG = COUT / (16 * MT);
  constexpr int NKC = CIN / 32;
  constexpr int NCH = 4 * NKC;
  constexpr int NTS = (COUT >= 32) ? 512 : (COUT * 16);
  int wid = __builtin_amdgcn_readfirstlane(blockIdx.x * 4 + (threadIdx.x >> 6));
  int lane = threadIdx.x & 63;
  int mg = wid % NMG; int r1 = wid / NMG;
  int wo2 = Wout >> 1;
  int pc = (Hout >> 1) * wo2;
  int pxc = r1 % pc; int cls = r1 / pc;
  if (cls >= 4) return;
  int p0 = cls >> 1, q0 = cls & 1;
  int tx = pxc % wo2, ty = pxc / wo2;
  int oy = 2 * ty + 1 - p0, ox = 2 * tx + 1 - q0;
  int iy0 = (oy + 1 - p0) >> 1, ix0 = (ox + 1 - q0) >> 1;
  int mtile0 = mg * MT;
  f32x4 zero = {0.f, 0.f, 0.f, 0.f};
  f32x4 acc[MT][4];
  #pragma unroll
  for (int mt = 0; mt < MT; ++mt)
    #pragma unroll
    for (int nt = 0; nt < 4; ++nt) acc[mt][nt] = zero;
  const ushort* wbase = wp + ((size_t)cls * (COUT / 16) + mtile0) * NCH * 512 + lane * 8;
  const size_t mstride = (size_t)NCH * 512;
  bool interior = (iy0 >= 1) & (iy0 <= Hin - 1) & (ix0 >= 1) & (ix0 <= Win - 1);

  if (interior) {
    #pragma unroll
    for (int i = 0; i < 2; ++i) {
      int iy = iy0 - i;
      #pragma unroll
      for (int j = 0; j < 2; ++j) {
        int ix = ix0 - j;
        const ushort* ib = in + (size_t)(iy * Win + ix) * (CIN * 64) + lane * 8;
        int tap = i * 2 + j;
        #pragma unroll
        for (int kc = 0; kc < NKC; ++kc) {
          int kcg = tap * NKC + kc;
          bf16x8 a[MT], bb[4];
          #pragma unroll
          for (int mt = 0; mt < MT; ++mt)
            a[mt] = *(const bf16x8*)(wbase + mt * mstride + (size_t)kcg * 512);
          #pragma unroll
          for (int nt = 0; nt < 4; ++nt)
            bb[nt] = *(const bf16x8*)(ib + kc * 2048 + nt * 512);
          #pragma unroll
          for (int mt = 0; mt < MT; ++mt)
            #pragma unroll
            for (int nt = 0; nt < 4; ++nt)
              acc[mt][nt] = __builtin_amdgcn_mfma_f32_16x16x32_bf16(a[mt], bb[nt], acc[mt][nt], 0, 0, 0);
        }
      }
    }
  } else {
    for (int i = 0; i < 2; ++i) {
      int iy = iy0 - i;
      if ((unsigned)iy >= (unsigned)Hin) continue;
      for (int j = 0; j < 2; ++j) {
        int ix = ix0 - j;
        if ((unsigned)ix >= (unsigned)Win) continue;
        const ushort* ib = in + (size_t)(iy * Win + ix) * (CIN * 64) + lane * 8;
        int tap = i * 2 + j;
        #pragma unroll
        for (int kc = 0; kc < NKC; ++kc) {
          int kcg = tap * NKC + kc;
          bf16x8 a[MT], bb[4];
          #pragma unroll
          for (int mt = 0; mt < MT; ++mt)
            a[mt] = *(const bf16x8*)(wbase + mt * mstride + (size_t)kcg * 512);
          #pragma unroll
          for (int nt = 0; nt < 4; ++nt)
            bb[nt] = *(const bf16x8*)(ib + kc * 2048 + nt * 512);
          #pragma unroll
          for (int mt = 0; mt < MT; ++mt)
            #pragma unroll
            for (int nt = 0; nt < 4; ++nt)
              acc[mt][nt] = __builtin_amdgcn_mfma_f32_16x16x32_bf16(a[mt], bb[nt], acc[mt][nt], 0, 0, 0);
        }
      }
    }
  }
  int ml = lane & 15, rb = (lane >> 4) * 4;
  int px = oy * Wout + ox;
  #pragma unroll
  for (int mt = 0; mt < MT; ++mt) {
    int co = mtile0 * 16 + mt * 16 + rb;
    f32x4 bv = *(const f32x4*)(bias + co);
    #pragma unroll
    for (int nt = 0; nt < 4; ++nt) {
      float v0 = acc[mt][nt][0] + bv[0];
      float v1 = acc[mt][nt][1] + bv[1];
      float v2 = acc[mt][nt][2] + bv[2];
      float v3 = acc[mt][nt][3] + bv[3];
      if (RELU) { v0=fmaxf(v0,0.f); v1=fmaxf(v1,0.f); v2=fmaxf(v2,0.f); v3=fmaxf(v3,0.f); }
      uint2 pk;
      pk.x = (unsigned)f2bf(v0) | ((unsigned)f2bf(v1) << 16);
      pk.y = (unsigned)f2bf(v2) | ((unsigned)f2bf(v3) << 16);
      size_t off = (size_t)px * (COUT * 64) + (size_t)(co >> 5) * 2048 + (size_t)nt * NTS
                 + ((co >> 3) & 3) * 128 + ml * 8 + (co & 7);
      *(uint2*)(out + off) = pk;
    }
  }
}

// ================= enc_fc fused: LDS-transpose staging + MFMA =================
#define APXS 1032
__global__ __launch_bounds__(256) void k_encfc_fused(const ushort* __restrict__ h4,
                                                     const float* __restrict__ wE,
                                                     float* __restrict__ partial) {
  __shared__ float smem[8320];
  ushort* au = (ushort*)smem;
  int s = blockIdx.x;
  int bid = (s & 7) * 256 + (s >> 3);
  int mg = bid & 15;
  int ccf = (bid >> 4) & 7;
  int pxg = bid >> 7;
  int tid = threadIdx.x;
  int co0 = mg * 32;
  #pragma unroll
  for (int i = 0; i < 16; ++i) {
    int idx = tid + i * 256;
    int px4 = idx & 3;
    int ci_l = (idx >> 2) & 31;
    int co_l = idx >> 7;
    float4 v = *(const float4*)&wE[((size_t)(co0 + co_l) << 16)
                                   + (size_t)(ccf * 32 + ci_l) * 256 + pxg * 16 + px4 * 4];
    int mt = co_l >> 4, m = co_l & 15;
    int kg = ci_l >> 3, k8 = ci_l & 7;
    int base = mt * 512 + kg * 128 + m * 8 + k8;
    au[(px4 * 4 + 0) * APXS + base] = f2bf(v.x);
    au[(px4 * 4 + 1) * APXS + base] = f2bf(v.y);
    au[(px4 * 4 + 2) * APXS + base] = f2bf(v.z);
    au[(px4 * 4 + 3) * APXS + base] = f2bf(v.w);
  }
  __syncthreads();
  int lane = tid & 63, wv = tid >> 6;
  int ml = lane & 15, rb = (lane >> 4) * 4;
  f32x4 zero = {0.f, 0.f, 0.f, 0.f};
  f32x4 acc[2][4];
  #pragma unroll
  for (int mt = 0; mt < 2; ++mt)
    #pragma unroll
    for (int nt = 0; nt < 4; ++nt) acc[mt][nt] = zero;
  #pragma unroll
  for (int jj = 0; jj < 4; ++jj) {
    int j = wv * 4 + jj;
    int px = pxg * 16 + j;
    bf16x8 a0 = *(const bf16x8*)(au + j * APXS + lane * 8);
    bf16x8 a1 = *(const bf16x8*)(au + j * APXS + 512 + lane * 8);
    const ushort* hb = h4 + (size_t)px * 16384 + ccf * 2048 + lane * 8;
    bf16x8 bb[4];
    #pragma unroll
    for (int nt = 0; nt < 4; ++nt)
      bb[nt] = *(const bf16x8*)(hb + nt * 512);
    #pragma unroll
    for (int nt = 0; nt < 4; ++nt) {
      acc[0][nt] = __builtin_amdgcn_mfma_f32_16x16x32_bf16(a0, bb[nt], acc[0][nt], 0, 0, 0);
      acc[1][nt] = __builtin_amdgcn_mfma_f32_16x16x32_bf16(a1, bb[nt], acc[1][nt], 0, 0, 0);
    }
  }
  __syncthreads();
  #pragma unroll
  for (int mt = 0; mt < 2; ++mt)
    #pragma unroll
    for (int nt = 0; nt < 4; ++nt)
      #pragma unroll
      for (int r = 0; r < 4; ++r)
        smem[wv * 2080 + (mt * 16 + rb + r) * 65 + nt * 16 + ml] = acc[mt][nt][r];
  __syncthreads();
  int ks = pxg * 8 + ccf;
  #pragma unroll
  for (int i = 0; i < 8; ++i) {
    int e = tid + i * 256;
    int b = e & 63, co_l = e >> 6;
    float sum = smem[co_l * 65 + b] + smem[2080 + co_l * 65 + b]
              + smem[4160 + co_l * 65 + b] + smem[6240 + co_l * 65 + b];
    partial[((size_t)(co0 + co_l) * ENC_KS + ks) * 64 + b] = sum;
  }
}

__global__ void k_encfc_red(const float* __restrict__ partial, const float* __restrict__ bias,
                            float* __restrict__ cnn) {
  int id = blockIdx.x * blockDim.x + threadIdx.x;
  int o = id >> 6, b = id & 63;
  float acc = bias[o];
  #pragma unroll 8
  for (int s = 0; s < ENC_KS; ++s) acc += partial[((size_t)o * ENC_KS + s) * 64 + b];
  cnn[(size_t)b * 512 + o] = fmaxf(acc, 0.f);
}

// ================= fused posterior + reparam: 1024-thread k-split, bf16 powT4 =================
__global__ __launch_bounds__(1024) void k_postz(const float* __restrict__ cnn,
                                                const float* __restrict__ belief,
                                                const ushort* __restrict__ powT,
                                                const float* __restrict__ bias,
                                                const float* __restrict__ eps,
                                                float* __restrict__ out,
                                                ushort* __restrict__ zb) {
  __shared__ float cs[512];
  __shared__ float bs[512];
  __shared__ float smv[512];
  __shared__ float red[512];
  int b = blockIdx.x;
  int tid = threadIdx.x;
  int j = tid & 511;
  int half = tid >> 9;
  if (tid < 512) cs[tid] = cnn[(size_t)b * HIDD + tid];
  else           bs[tid - 512] = belief[(size_t)b * HIDD + (tid - 512)];
  __syncthreads();
  float acc = half ? 0.f : bias[j];
  const ushort* wb = powT + (size_t)(half * 128) * 2048 + j * 4;
  const float* src = half ? bs : cs;
  #pragma unroll 4
  for (int p = 0; p < 128; ++p) {
    ushort4 w4 = *(const ushort4*)(wb + (size_t)p * 2048);
    acc += src[4*p]   * bf2f(w4.x) + src[4*p+1] * bf2f(w4.y)
         + src[4*p+2] * bf2f(w4.z) + src[4*p+3] * bf2f(w4.w);
  }
  if (half) red[j] = acc;
  __syncthreads();
  if (!half) {
    float t = acc + red[j];
    smv[j] = t;
    if (j < 256) out[O_MUPO + b * 256 + j] = t;
    else         out[O_LVPO + b * 256 + (j - 256)] = t;
  }
  __syncthreads();
  if (tid < 256) {
    float z = smv[tid] + eps[b * 256 + tid] * expf(0.5f * smv[tid + 256]);
    out[O_ZT + b * 256 + tid] = z;
    if (tid < 128) zb[b * 128 + tid] = f2bf(z);
  }
}

// ================= dec_fc MFMA: direct f32 weights, frag-order out =================
__global__ __launch_bounds__(256) void k_decfc_mfma(const ushort* __restrict__ zb,
                                                    const float* __restrict__ dfw,
                                                    const float* __restrict__ dfb,
                                                    ushort* __restrict__ dec) {
  int wid = __builtin_amdgcn_readfirstlane(blockIdx.x * 4 + (threadIdx.x >> 6));
  int lane = threadIdx.x & 63;
  int m0 = wid * 32;
  int ml = lane & 15, kl = (lane >> 4) * 8;
  f32x4 zero = {0.f, 0.f, 0.f, 0.f};
  f32x4 acc[2][4];
  #pragma unroll
  for (int mt = 0; mt < 2; ++mt)
    #pragma unroll
    for (int nt = 0; nt < 4; ++nt) acc[mt][nt] = zero;
  #pragma unroll
  for (int kc = 0; kc < 4; ++kc) {
    bf16x8 a[2], bb[4];
    #pragma unroll
    for (int mt = 0; mt < 2; ++mt) {
      int m_r = m0 + mt * 16 + ml;
      const float* wr = dfw + (size_t)((m_r & 127) * 256 + (m_r >> 7)) * 128 + kc * 32 + kl;
      float4 u0 = *(const float4*)wr;
      float4 u1 = *(const float4*)(wr + 4);
      bf16x8 av;
      av[0] = (short)f2bf(u0.x); av[1] = (short)f2bf(u0.y);
      av[2] = (short)f2bf(u0.z); av[3] = (short)f2bf(u0.w);
      av[4] = (short)f2bf(u1.x); av[5] = (short)f2bf(u1.y);
      av[6] = (short)f2bf(u1.z); av[7] = (short)f2bf(u1.w);
      a[mt] = av;
    }
    #pragma unroll
    for (int nt = 0; nt < 4; ++nt)
      bb[nt] = *(const bf16x8*)(zb + (size_t)(nt * 16 + ml) * 128 + kc * 32 + kl);
    #pragma unroll
    for (int mt = 0; mt < 2; ++mt)
      #pragma unroll
      for (int nt = 0; nt < 4; ++nt)
        acc[mt][nt] = __builtin_amdgcn_mfma_f32_16x16x32_bf16(a[mt], bb[nt], acc[mt][nt], 0, 0, 0);
  }
  int rb = (lane >> 4) * 4;
  #pragma unroll
  for (int mt = 0; mt < 2; ++mt) {
    int m = m0 + mt * 16 + rb;
    int pix = m >> 7, co = m & 127;
    float bv0 = dfb[(size_t)(co + 0) * 256 + pix];
    float bv1 = dfb[(size_t)(co + 1) * 256 + pix];
    float bv2 = dfb[(size_t)(co + 2) * 256 + pix];
    float bv3 = dfb[(size_t)(co + 3) * 256 + pix];
    #pragma unroll
    for (int nt = 0; nt < 4; ++nt) {
      uint2 pk;
      pk.x = (unsigned)f2bf(acc[mt][nt][0] + bv0) | ((unsigned)f2bf(acc[mt][nt][1] + bv1) << 16);
      pk.y = (unsigned)f2bf(acc[mt][nt][2] + bv2) | ((unsigned)f2bf(acc[mt][nt][3] + bv3) << 16);
      size_t off = (size_t)pix * 8192 + (size_t)(co >> 5) * 2048 + nt * 512
                 + ((co >> 3) & 3) * 128 + ml * 8 + (co & 7);
      *(uint2*)(dec + off) = pk;
    }
  }
}

// ================= d4 fused with output transpose =================
__global__ __launch_bounds__(256) void k_d4t(const ushort* __restrict__ in,
                                             const float* __restrict__ w,
                                             const float* __restrict__ bias,
                                             float* __restrict__ out) {
  __shared__ float lds[64][65];
  int blk = blockIdx.x;
  int oy = blk >> 2, ox0 = (blk & 3) << 6;
  int t = threadIdx.x;
  int b = t & 63, sub = t >> 6;
  float bv = bias[0];
  for (int j = 0; j < 16; ++j) {
    int oxl = j * 4 + sub;
    int ox = ox0 + oxl;
    int p0 = (oy + 1) & 1, q0 = (ox + 1) & 1;
    int iy0 = (oy + 1 - p0) >> 1, ix0 = (ox + 1 - q0) >> 1;
    float acc = bv;
    #pragma unroll
    for (int i = 0; i < 2; ++i) {
      int iy = iy0 - i;
      if ((unsigned)iy >= 128u) continue;
      int p = p0 + 2 * i;
      #pragma unroll
      for (int jj = 0; jj < 2; ++jj) {
        int ix = ix0 - jj;
        if ((unsigned)ix >= 128u) continue;
        int q = q0 + 2 * jj;
        const ushort* base = in + (size_t)(iy * 128 + ix) * 1024 + (b >> 4) * 256 + (b & 15) * 8;
        bf16x8 v0 = *(const bf16x8*)(base);
        bf16x8 v1 = *(const bf16x8*)(base + 128);
        const float* wq = w + p * 4 + q;
        #pragma unroll
        for (int ci = 0; ci < 8; ++ci) acc += bf2f((ushort)v0[ci]) * wq[ci * 16];
        #pragma unroll
        for (int ci = 0; ci < 8; ++ci) acc += bf2f((ushort)v1[ci]) * wq[(ci + 8) * 16];
      }
    }
    lds[oxl][b] = acc;
  }
  __syncthreads();
  #pragma unroll
  for (int j = 0; j < 16; ++j) {
    int idx = t + j * 256;
    int b2 = idx >> 6, oxl = idx & 63;
    out[(size_t)b2 * 65536 + oy * 256 + ox0 + oxl] = lds[oxl][b2];
  }
}

// ================= launch =================

extern "C" void kernel_launch(void* const* d_in, const int* in_sizes, int n_in,
                              void* d_out, int out_size, void* d_ws, size_t ws_size,
                              hipStream_t stream) {
  const float* img      = (const float*)d_in[0];
  const float* act      = (const float*)d_in[1];
  const float* z_prev   = (const float*)d_in[2];
  const float* st_prev  = (const float*)d_in[3];
  const float* eps      = (const float*)d_in[4];
  const float* c1w = (const float*)d_in[5];  const float* c1b = (const float*)d_in[6];
  const float* c2w = (const float*)d_in[7];  const float* c2b = (const float*)d_in[8];
  const float* c3w = (const float*)d_in[9];  const float* c3b = (const float*)d_in[10];
  const float* c4w = (const float*)d_in[11]; const float* c4b = (const float*)d_in[12];
  const float* efw = (const float*)d_in[13]; const float* efb = (const float*)d_in[14];
  const float* pow_ = (const float*)d_in[15]; const float* pob = (const float*)d_in[16];
  const float* prw = (const float*)d_in[17]; const float* prb = (const float*)d_in[18];
  const float* siw = (const float*)d_in[19]; const float* sib = (const float*)d_in[20];
  const float* Alog = (const float*)d_in[21];
  const float* Bw = (const float*)d_in[22];  const float* Cw = (const float*)d_in[23];
  const float* Dw = (const float*)d_in[24];  const float* Db = (const float*)d_in[25];
  const float* Dv = (const float*)d_in[26];
  const float* dfw = (const float*)d_in[27]; const float* dfb = (const float*)d_in[28];
  const float* d1w = (const float*)d_in[29]; const float* d1b = (const float*)d_in[30];
  const float* d2w = (const float*)d_in[31]; const float* d2b = (const float*)d_in[32];
  const float* d3w = (const float*)d_in[33]; const float* d3b = (const float*)d_in[34];
  const float* d4w = (const float*)d_in[35]; const float* d4b = (const float*)d_in[36];

  float* ws = (float*)d_ws;
  float* out = (float*)d_out;

  ushort* pc2 = (ushort*)(ws + PW_C2);
  ushort* pc3 = (ushort*)(ws + PW_C3);
  ushort* pc4 = (ushort*)(ws + PW_C4);
  ushort* pd1 = (ushort*)(ws + PW_D1);
  ushort* pd2 = (ushort*)(ws + PW_D2);
  ushort* pd3 = (ushort*)(ws + PW_D3);
  ushort* pc1 = (ushort*)(ws + PW_C1);
  ushort* timg4 = (ushort*)(ws + W_TIMG);
  ushort* h1b = (ushort*)(ws + W_H1B);
  ushort* h2b = (ushort*)(ws + W_H2B);
  ushort* h3b = (ushort*)(ws + W_H3B);
  ushort* h4b = (ushort*)(ws + W_H4B);
  ushort* deco = (ushort*)(ws + W_DECO);
  ushort* d1o = (ushort*)(ws + W_D1O);
  ushort* d2o = (ushort*)(ws + W_D2O);
  ushort* d3o = (ushort*)(ws + W_D3O);
  ushort* zb = (ushort*)(ws + W_ZB16);
  ushort* siwT = (ushort*)(ws + W_SIWT);
  ushort* DwT  = (ushort*)(ws + W_DWT);
  ushort* prwT = (ushort*)(ws + W_PRWT);
  ushort* powT = (ushort*)(ws + W_POWT);

  // ---- merged weight prepack (bf16 4-grouped dense transposes) ----
  k_pack_all<<<7992, 256, 0, stream>>>(c2w, c3w, c4w, d1w, d2w, d3w, c1w,
                                       siw, Dw, prw, pow_,
                                       pc2, pc3, pc4, pd1, pd2, pd3, pc1,
                                       siwT, DwT, prwT, powT);

  // ---- SSM (k-split, bf16 weights) || img transpose, both post-pack ----
  k_ssm_timg<<<1088, 1024, 0, stream>>>(z_prev, act, siwT, sib, DwT, Db, Bw, Cw,
                                        Alog, Dv, st_prev, out + O_STATE,
                                        ws + W_BELIEF, prwT, prb, out,
                                        img, timg4);

  // ---- encoder ----
  k_conv1_mfma<<<4096, 256, 0, stream>>>(timg4, pc1, c1b, h1b);
  mfma_conv<32, 64, 4><<<1024, 256, 0, stream>>>(h1b, pc2, c2b, h2b, 128, 128, 64, 64);
  mfma_conv<64, 128, 4><<<512, 256, 0, stream>>>(h2b, pc3, c3b, h3b, 64, 64, 32, 32);
  mfma_conv<128, 256, 2><<<512, 256, 0, stream>>>(h3b, pc4, c4b, h4b, 32, 32, 16, 16);

  // ---- enc_fc (fused transpose+GEMM) ----
  k_encfc_fused<<<2048, 256, 0, stream>>>(h4b, efw, ws + W_ENCP);
  k_encfc_red<<<128, 256, 0, stream>>>(ws + W_ENCP, efb, ws + W_CNN);

  // ---- fused posterior + reparam (k-split, bf16 weights) ----
  k_postz<<<64, 1024, 0, stream>>>(ws + W_CNN, ws + W_BELIEF, powT, pob, eps, out, zb);

  // ---- decoder ----
  k_decfc_mfma<<<256, 256, 0, stream>>>(zb, dfw, dfb, deco);
  mfma_deconv<128, 64, 2, true><<<512, 256, 0, stream>>>(deco, pd1, d1b, d1o, 16, 16, 32, 32);
  mfma_deconv<64, 32, 2, true><<<1024, 256, 0, stream>>>(d1o, pd2, d2b, d2o, 32, 32, 64, 64);
  mfma_deconv<32, 16, 1, true><<<4096, 256, 0, stream>>>(d2o, pd3, d3b, d3o, 64, 64, 128, 128);
  k_d4t<<<1024, 256, 0, stream>>>(d3o, d4w, d4b, out + O_PRED);
}

// Round 17
// 352.662 us; speedup vs baseline: 1.2685x; 1.0128x over previous
//
#include <hip/hip_runtime.h>
#include <math.h>

#define BB 64
#define LATENT 256
#define ACTD 6
#define HIDD 512
#define DST 16

typedef __attribute__((ext_vector_type(8))) short bf16x8;
typedef __attribute__((ext_vector_type(4))) float f32x4;

static __device__ __forceinline__ ushort f2bf(float f) {
  unsigned u = __builtin_bit_cast(unsigned, f);
  unsigned r = (u + 0x7FFFu + ((u >> 16) & 1u)) >> 16;
  return (ushort)r;
}
static __device__ __forceinline__ float bf2f(ushort u) {
  return __builtin_bit_cast(float, ((unsigned)u) << 16);
}
// bijective XCD swizzle; requires gridDim.x % 8 == 0
static __device__ __forceinline__ int xcd_swz() {
  int nb = gridDim.x >> 3;
  int ob = blockIdx.x;
  return (ob & 7) * nb + (ob >> 3);
}

// ---------------- output offsets (floats) ----------------
#define O_PRED   0
#define O_ZT     4194304
#define O_STATE  4210688
#define O_MUP    4734976
#define O_LVP    4751360
#define O_MUPO   4767744
#define O_LVPO   4784128

// ---------------- ws offsets (floats), lifetime-reused ----------------
#define W_BELIEF 67584u
#define W_CNN    100352u
#define W_ZB16   133120u
#define PW_C2    137216u
#define PW_C3    153600u
#define PW_C4    219136u
#define PW_D1    481280u
#define PW_D2    546816u
#define PW_D3    563200u
#define PW_C1    567296u
#define W_TIMG   602112u      // timg4 bf16 [65536][64][4]
#define W_H1B    13185024u
#define W_H2B    29962240u
#define W_H3B    38350848u
#define W_H4B    42545152u
// bf16 4-grouped transposed dense weights (u16), after H4B:
#define W_SIWT   44642304u
#define W_DWT    44709888u
#define W_PRWT   44840960u
#define W_POWT   44972032u
// reuse:
#define W_ENCP   602112u
#define W_DECO   8990720u
#define W_D1O    10039296u
#define W_D2O    13185024u
#define W_D3O    17379328u

#define ENC_KS 128

// ================= merged weight prepack =================

static __device__ __forceinline__ void pack_conv_elem(const float* __restrict__ w,
                                                      ushort* __restrict__ o,
                                                      int Cout, int Cin, int id) {
  int NCH = Cin / 2;
  int per = NCH * 512;
  int mt = id / per, r = id % per;
  int kcg = r >> 9, s = r & 511;
  int kg = s >> 7, m = (s >> 3) & 15, k8 = s & 7;
  int co = mt * 16 + m;
  int k = kcg * 32 + kg * 8 + k8;
  int tap = k / Cin, ci = k % Cin;
  o[id] = f2bf(w[(size_t)(co * Cin + ci) * 16 + tap]);
}

static __device__ __forceinline__ void pack_deconv_elem(const float* __restrict__ w,
                                                        ushort* __restrict__ o,
                                                        int Cout, int Cin, int id) {
  int NCH = Cin / 8;
  int perM = NCH * 512;
  int perC = (Cout / 16) * perM;
  int cls = id / perC, r = id % perC;
  int mt = r / perM, r2 = r % perM;
  int kcg = r2 >> 9, s = r2 & 511;
  int kg = s >> 7, m = (s >> 3) & 15, k8 = s & 7;
  int co = mt * 16 + m;
  int k = kcg * 32 + kg * 8 + k8;
  int t = k / Cin, ci = k % Cin;
  int p = (cls >> 1) + 2 * (t >> 1);
  int q = (cls & 1) + 2 * (t & 1);
  o[id] = f2bf(w[(size_t)(ci * Cout + co) * 16 + p * 4 + q]);
}

static __device__ __forceinline__ void pack_conv1_elem(const float* __restrict__ w,
                                                       ushort* __restrict__ o, int id) {
  int mt = id >> 10, r = id & 1023;
  int kcg = r >> 9, s = r & 511;
  int kg = s >> 7, m = (s >> 3) & 15, k8 = s & 7;
  int co = mt * 16 + m;
  int k = kcg * 32 + kg * 8 + k8;
  int tap = k >> 2, ci = k & 3;
  o[id] = (ci < 3) ? f2bf(w[(size_t)(co * 3 + ci) * 16 + tap]) : (ushort)0;
}

__global__ __launch_bounds__(256) void k_pack_all(
    const float* __restrict__ c2w, const float* __restrict__ c3w,
    const float* __restrict__ c4w, const float* __restrict__ d1w,
    const float* __restrict__ d2w, const float* __restrict__ d3w,
    const float* __restrict__ c1w,
    const float* __restrict__ siw, const float* __restrict__ Dw,
    const float* __restrict__ prw, const float* __restrict__ pw,
    ushort* __restrict__ pc2, ushort* __restrict__ pc3, ushort* __restrict__ pc4,
    ushort* __restrict__ pd1, ushort* __restrict__ pd2, ushort* __restrict__ pd3,
    ushort* __restrict__ pc1,
    ushort* __restrict__ siwT, ushort* __restrict__ DwT,
    ushort* __restrict__ prwT, ushort* __restrict__ powT) {
  int id = blockIdx.x * 256 + threadIdx.x;
  if (id < 32768)            pack_conv_elem(c2w, pc2, 64, 32, id);
  else if (id < 163840)      pack_conv_elem(c3w, pc3, 128, 64, id - 32768);
  else if (id < 688128)      pack_conv_elem(c4w, pc4, 256, 128, id - 163840);
  else if (id < 819200)      pack_deconv_elem(d1w, pd1, 64, 128, id - 688128);
  else if (id < 851968)      pack_deconv_elem(d2w, pd2, 32, 64, id - 819200);
  else if (id < 860160)      pack_deconv_elem(d3w, pd3, 16, 32, id - 851968);
  else if (id < 862208)      pack_conv1_elem(c1w, pc1, id - 860160);
  else if (id < 997376) {    // siwT4 [66][512][4] bf16, K padded 262->264
    int r = id - 862208;
    int q = r >> 11, h = (r & 2047) >> 2, e = r & 3;
    int k = q * 4 + e;
    siwT[r] = (k < LATENT + ACTD) ? f2bf(siw[(size_t)h * (LATENT + ACTD) + k]) : (ushort)0;
  } else if (id < 1259520) { // DwT4 [128][512][4] bf16
    int r = id - 997376;
    int q = r >> 11, h = (r & 2047) >> 2, e = r & 3;
    DwT[r] = f2bf(Dw[(size_t)h * HIDD + q * 4 + e]);
  } else if (id < 1521664) { // prwT4 [128][512][4] bf16
    int r = id - 1259520;
    int q = r >> 11, h = (r & 2047) >> 2, e = r & 3;
    prwT[r] = f2bf(prw[(size_t)h * HIDD + q * 4 + e]);
  } else if (id < 2045952) { // powT4 [256][512][4] bf16
    int r = id - 1521664;
    int q = r >> 11, j2 = (r & 2047) >> 2, e = r & 3;
    powT[r] = f2bf(pw[(size_t)j2 * 1024 + q * 4 + e]);
  }
}

// ================= merged SSM (blocks 0..63, k-split, bf16 weights) + img transpose =================
__global__ __launch_bounds__(1024) void k_ssm_timg(
    const float* __restrict__ z_prev, const float* __restrict__ act,
    const ushort* __restrict__ siwT, const float* __restrict__ sib,
    const ushort* __restrict__ DwT, const float* __restrict__ Db,
    const float* __restrict__ Bw, const float* __restrict__ Cw,
    const float* __restrict__ Alog, const float* __restrict__ Dv,
    const float* __restrict__ st_prev, float* __restrict__ state_out,
    float* __restrict__ belief_out, const ushort* __restrict__ prwT,
    const float* __restrict__ prb, float* __restrict__ out,
    const float* __restrict__ img, ushort* __restrict__ timg4) {
  __shared__ float sm[12480];
  int blk = blockIdx.x;
  int tid = threadIdx.x;

  if (blk < 64) {
    float* xs   = sm;
    float* si   = sm + 264;
    float* bel  = sm + 776;
    float* red  = sm + 1288;
    float* part = sm + 1800;
    float* btct = sm + 1928;
    int b = blk;
    int h = tid & 511;
    int half = tid >> 9;
    if (tid < 256) xs[tid] = z_prev[(size_t)b * LATENT + tid];
    else if (tid < 256 + ACTD) xs[tid] = act[(size_t)b * ACTD + (tid - 256)];
    else if (tid < 264) xs[tid] = 0.f;
    __syncthreads();
    {
      float acc = half ? 0.f : sib[h];
      const ushort* wb = siwT + (size_t)(half * 33) * 2048 + h * 4;
      const float* xb = xs + half * 132;
      #pragma unroll 4
      for (int p = 0; p < 33; ++p) {
        ushort4 w4 = *(const ushort4*)(wb + (size_t)p * 2048);
        acc += xb[4*p]   * bf2f(w4.x) + xb[4*p+1] * bf2f(w4.y)
             + xb[4*p+2] * bf2f(w4.z) + xb[4*p+3] * bf2f(w4.w);
      }
      if (half) red[h] = acc;
      __syncthreads();
      if (!half) {
        float t = acc + red[h];
        si[h] = t / (1.f + expf(-t));
      }
    }
    __syncthreads();
    float d = 0.f;
    {
      float acc = half ? 0.f : Db[h];
      const ushort* wb = DwT + (size_t)(half * 64) * 2048 + h * 4;
      const float* sb = si + half * 256;
      #pragma unroll 4
      for (int p = 0; p < 64; ++p) {
        ushort4 w4 = *(const ushort4*)(wb + (size_t)p * 2048);
        acc += sb[4*p]   * bf2f(w4.x) + sb[4*p+1] * bf2f(w4.y)
             + sb[4*p+2] * bf2f(w4.z) + sb[4*p+3] * bf2f(w4.w);
      }
      if (half) red[h] = acc;
      __syncthreads();
      if (!half) {
        float t = acc + red[h];
        d = fmaxf(t, 0.f) + log1pf(expf(-fabsf(t)));
      }
    }
    if (tid < 128) {
      int hf2 = tid >> 6;
      int l = tid & 63;
      int n = l & 15, p = l >> 4;
      const float* wr = (hf2 ? Cw : Bw) + (size_t)n * HIDD + p * 128;
      const float* sr = si + p * 128;
      float a2 = 0.f;
      #pragma unroll 4
      for (int k = 0; k < 128; k += 4) {
        float4 w4 = *(const float4*)(wr + k);
        a2 += sr[k] * w4.x + sr[k+1] * w4.y + sr[k+2] * w4.z + sr[k+3] * w4.w;
      }
      part[(hf2 * 16 + n) * 4 + p] = a2;
    }
    __syncthreads();
    if (tid < 32) {
      int hf2 = tid >> 4, n = tid & 15;
      const float* pp = part + (hf2 * 16 + n) * 4;
      btct[hf2 * 16 + n] = pp[0] + pp[1] + pp[2] + pp[3];
    }
    __syncthreads();
    if (!half) {
      float si_h = si[h];
      float belv = Dv[h] * si_h;
      const float* al = Alog + (size_t)h * DST;
      const float* sp = st_prev + ((size_t)b * 512 + h) * DST;
      float* so = state_out + ((size_t)b * 512 + h) * DST;
      #pragma unroll
      for (int n = 0; n < DST; ++n) {
        float A = -expf(al[n]);
        float st = expf(d * A) * sp[n] + d * btct[n] * si_h;
        so[n] = st;
        belv += st * btct[16 + n];
      }
      bel[h] = belv;
      belief_out[(size_t)b * 512 + h] = belv;
    }
    __syncthreads();
    {
      float acc = half ? 0.f : prb[h];
      const ushort* wb = prwT + (size_t)(half * 64) * 2048 + h * 4;
      const float* bb2 = bel + half * 256;
      #pragma unroll 4
      for (int p = 0; p < 64; ++p) {
        ushort4 w4 = *(const ushort4*)(wb + (size_t)p * 2048);
        acc += bb2[4*p]   * bf2f(w4.x) + bb2[4*p+1] * bf2f(w4.y)
             + bb2[4*p+2] * bf2f(w4.z) + bb2[4*p+3] * bf2f(w4.w);
      }
      if (half) red[h] = acc;
      __syncthreads();
      if (!half) {
        float t = acc + red[h];
        if (h < 256) out[O_MUP + b * 256 + h] = t;
        else         out[O_LVP + b * 256 + (h - 256)] = t;
      }
    }
  } else {
    float (*ts)[64][65] = (float (*)[64][65])sm;
    int p0 = (blk - 64) << 6;
    #pragma unroll
    for (int c = 0; c < 3; ++c) {
      #pragma unroll
      for (int i = 0; i < 4; ++i) {
        int idx = tid + i * 1024;
        int b = idx >> 6, pr = idx & 63;
        ts[c][pr][b] = img[((size_t)b * 3 + c) * 65536 + p0 + pr];
      }
    }
    __syncthreads();
    #pragma unroll
    for (int i = 0; i < 4; ++i) {
      int idx = tid + i * 1024;
      int pr = idx >> 6, b = idx & 63;
      uint2 pk;
      pk.x = (unsigned)f2bf(ts[0][pr][b]) | ((unsigned)f2bf(ts[1][pr][b]) << 16);
      pk.y = (unsigned)f2bf(ts[2][pr][b]);
      *(uint2*)(timg4 + ((size_t)(p0 + pr) * 64 + b) * 4) = pk;
    }
  }
}

// ================= conv1 MFMA (XCD-swizzled) =================
__global__ __launch_bounds__(256) void k_conv1_mfma(const ushort* __restrict__ in,
                                                    const ushort* __restrict__ wp,
                                                    const float* __restrict__ bias,
                                                    ushort* __restrict__ out) {
  int wid = __builtin_amdgcn_readfirstlane(xcd_swz() * 4 + (threadIdx.x >> 6));
  int lane = threadIdx.x & 63;
  int ox = wid & 127, oy = wid >> 7;
  int ml = lane & 15, khi = lane >> 4;
  f32x4 zero = {0.f, 0.f, 0.f, 0.f};
  f32x4 acc[2][4];
  #pragma unroll
  for (int mt = 0; mt < 2; ++mt)
    #pragma unroll
    for (int nt = 0; nt < 4; ++nt) acc[mt][nt] = zero;
  int by = 2 * oy - 1, bx = 2 * ox - 1;
  bool interior = (oy >= 1) & (oy <= 126) & (ox >= 1) & (ox <= 126);

  #pragma unroll
  for (int kc = 0; kc < 2; ++kc) {
    bf16x8 a0 = *(const bf16x8*)(wp + kc * 512 + lane * 8);
    bf16x8 a1 = *(const bf16x8*)(wp + 1024 + kc * 512 + lane * 8);
    int t0 = kc * 8 + khi * 2;
    int ky0 = t0 >> 2, kx0 = t0 & 3;
    int ky1 = (t0 + 1) >> 2, kx1 = (t0 + 1) & 3;
    int iy0 = by + ky0, ix0 = bx + kx0;
    int iy1 = by + ky1, ix1 = bx + kx1;
    const ushort* pA = in + ((size_t)(iy0 * 256 + ix0) * 64 + ml) * 4;
    const ushort* pB = in + ((size_t)(iy1 * 256 + ix1) * 64 + ml) * 4;
    if (interior) {
      #pragma unroll
      for (int nt = 0; nt < 4; ++nt) {
        uint2 lo = *(const uint2*)(pA + nt * 64);
        uint2 hi = *(const uint2*)(pB + nt * 64);
        uint4 u; u.x = lo.x; u.y = lo.y; u.z = hi.x; u.w = hi.y;
        bf16x8 bb = __builtin_bit_cast(bf16x8, u);
        acc[0][nt] = __builtin_amdgcn_mfma_f32_16x16x32_bf16(a0, bb, acc[0][nt], 0, 0, 0);
        acc[1][nt] = __builtin_amdgcn_mfma_f32_16x16x32_bf16(a1, bb, acc[1][nt], 0, 0, 0);
      }
    } else {
      bool ok0 = ((unsigned)iy0 < 256u) & ((unsigned)ix0 < 256u);
      bool ok1 = ((unsigned)iy1 < 256u) & ((unsigned)ix1 < 256u);
      #pragma unroll
      for (int nt = 0; nt < 4; ++nt) {
        uint2 z2; z2.x = 0u; z2.y = 0u;
        uint2 lo = ok0 ? *(const uint2*)(pA + nt * 64) : z2;
        uint2 hi = ok1 ? *(const uint2*)(pB + nt * 64) : z2;
        uint4 u; u.x = lo.x; u.y = lo.y; u.z = hi.x; u.w = hi.y;
        bf16x8 bb = __builtin_bit_cast(bf16x8, u);
        acc[0][nt] = __builtin_amdgcn_mfma_f32_16x16x32_bf16(a0, bb, acc[0][nt], 0, 0, 0);
        acc[1][nt] = __builtin_amdgcn_mfma_f32_16x16x32_bf16(a1, bb, acc[1][nt], 0, 0, 0);
      }
    }
  }
  int px = oy * 128 + ox;
  int rb = khi * 4;
  #pragma unroll
  for (int mt = 0; mt < 2; ++mt) {
    int co = mt * 16 + rb;
    f32x4 bv = *(const f32x4*)(bias + co);
    #pragma unroll
    for (int nt = 0; nt < 4; ++nt) {
      float v0 = fmaxf(acc[mt][nt][0] + bv[0], 0.f);
      float v1 = fmaxf(acc[mt][nt][1] + bv[1], 0.f);
      float v2 = fmaxf(acc[mt][nt][2] + bv[2], 0.f);
      float v3 = fmaxf(acc[mt][nt][3] + bv[3], 0.f);
      uint2 pk;
      pk.x = (unsigned)f2bf(v0) | ((unsigned)f2bf(v1) << 16);
      pk.y = (unsigned)f2bf(v2) | ((unsigned)f2bf(v3) << 16);
      size_t off = (size_t)px * 2048 + nt * 512 + ((co >> 3) & 3) * 128 + ml * 8 + (co & 7);
      *(uint2*)(out + off) = pk;
    }
  }
}

// ================= MFMA conv, interior fast path (XCD-swizzled) =================
template<int CIN, int COUT, int MT>
__global__ __launch_bounds__(256) void mfma_conv(const ushort* __restrict__ in,
                                                 const ushort* __restrict__ wp,
                                                 const float* __restrict__ bias,
                                                 ushort* __restrict__ out,
                                                 int Hin, int Win, int Hout, int Wout) {
  constexpr int NMG = COUT / (16 * MT);
  constexpr int NKC = CIN / 32;
  constexpr int NCH = 16 * NKC;
  int wid = __builtin_amdgcn_readfirstlane(xcd_swz() * 4 + (threadIdx.x >> 6));
  int lane = threadIdx.x & 63;
  int mg = wid % NMG;
  int px = wid / NMG;
  int ox = px % Wout, oy = px / Wout;
  if (oy >= Hout) return;
  int mtile0 = mg * MT;
  f32x4 zero = {0.f, 0.f, 0.f, 0.f};
  f32x4 acc[MT][4];
  #pragma unroll
  for (int mt = 0; mt < MT; ++mt)
    #pragma unroll
    for (int nt = 0; nt < 4; ++nt) acc[mt][nt] = zero;
  const ushort* wbase = wp + (size_t)mtile0 * NCH * 512 + lane * 8;
  const size_t mstride = (size_t)NCH * 512;
  bool interior = (oy >= 1) & (oy < Hout - 1) & (ox >= 1) & (ox < Wout - 1);

  if (interior) {
    #pragma unroll
    for (int ky = 0; ky < 4; ++ky) {
      int iy = 2 * oy - 1 + ky;
      #pragma unroll
      for (int kx = 0; kx < 4; ++kx) {
        int ix = 2 * ox - 1 + kx;
        const ushort* ib = in + (size_t)(iy * Win + ix) * (CIN * 64) + lane * 8;
        int tap = ky * 4 + kx;
        #pragma unroll
        for (int kc = 0; kc < NKC; ++kc) {
          int kcg = tap * NKC + kc;
          bf16x8 a[MT], bb[4];
          #pragma unroll
          for (int mt = 0; mt < MT; ++mt)
            a[mt] = *(const bf16x8*)(wbase + mt * mstride + (size_t)kcg * 512);
          #pragma unroll
          for (int nt = 0; nt < 4; ++nt)
            bb[nt] = *(const bf16x8*)(ib + kc * 2048 + nt * 512);
          #pragma unroll
          for (int mt = 0; mt < MT; ++mt)
            #pragma unroll
            for (int nt = 0; nt < 4; ++nt)
              acc[mt][nt] = __builtin_amdgcn_mfma_f32_16x16x32_bf16(a[mt], bb[nt], acc[mt][nt], 0, 0, 0);
        }
      }
    }
  } else {
    for (int ky = 0; ky < 4; ++ky) {
      int iy = 2 * oy - 1 + ky;
      if ((unsigned)iy >= (unsigned)Hin) continue;
      for (int kx = 0; kx < 4; ++kx) {
        int ix = 2 * ox - 1 + kx;
        if ((unsigned)ix >= (unsigned)Win) continue;
        const ushort* ib = in + (size_t)(iy * Win + ix) * (CIN * 64) + lane * 8;
        int tap = ky * 4 + kx;
        #pragma unroll
        for (int kc = 0; kc < NKC; ++kc) {
          int kcg = tap * NKC + kc;
          bf16x8 a[MT], bb[4];
          #pragma unroll
          for (int mt = 0; mt < MT; ++mt)
            a[mt] = *(const bf16x8*)(wbase + mt * mstride + (size_t)kcg * 512);
          #pragma unroll
          for (int nt = 0; nt < 4; ++nt)
            bb[nt] = *(const bf16x8*)(ib + kc * 2048 + nt * 512);
          #pragma unroll
          for (int mt = 0; mt < MT; ++mt)
            #pragma unroll
            for (int nt = 0; nt < 4; ++nt)
              acc[mt][nt] = __builtin_amdgcn_mfma_f32_16x16x32_bf16(a[mt], bb[nt], acc[mt][nt], 0, 0, 0);
        }
      }
    }
  }
  int ml = lane & 15, rb = (lane >> 4) * 4;
  #pragma unroll
  for (int mt = 0; mt < MT; ++mt) {
    int co = mtile0 * 16 + mt * 16 + rb;
    f32x4 bv = *(const f32x4*)(bias + co);
    #pragma unroll
    for (int nt = 0; nt < 4; ++nt) {
      float v0 = fmaxf(acc[mt][nt][0] + bv[0], 0.f);
      float v1 = fmaxf(acc[mt][nt][1] + bv[1], 0.f);
      float v2 = fmaxf(acc[mt][nt][2] + bv[2], 0.f);
      float v3 = fmaxf(acc[mt][nt][3] + bv[3], 0.f);
      uint2 pk;
      pk.x = (unsigned)f2bf(v0) | ((unsigned)f2bf(v1) << 16);
      pk.y = (unsigned)f2bf(v2) | ((unsigned)f2bf(v3) << 16);
      size_t off = (size_t)px * (COUT * 64) + (size_t)(co >> 5) * 2048 + nt * 512
                 + ((co >> 3) & 3) * 128 + ml * 8 + (co & 7);
      *(uint2*)(out + off) = pk;
    }
  }
}

// ================= MFMA transposed conv, interior fast path (XCD-swizzled) =================
template<int CIN, int COUT, int MT, bool RELU>
__global__ __launch_bounds__(256) void mfma_deconv(const ushort* __restrict__ in,
                                                   const ushort* __restrict__ wp,
                                                   const float* __restrict__ bias,
                                                   ushort* __restrict__ out,
                                                   int Hin, int Win, int Hout, int Wout) {
  constexpr int NMG = COUT / (16 * MT);
  constexpr int NKC = CIN / 32;
  constexpr int NCH = 4 * NKC;
  constexpr int NTS = (COUT >= 32) ? 512 : (COUT * 16);
  int wid = __builtin_amdgcn_readfirstlane(xcd_swz() * 4 + (threadIdx.x >> 6));
  int lane = threadIdx.x & 63;
  int mg = wid % NMG; int r1 = wid / NMG;
  int wo2 = Wout >> 1;
  int pc = (Hout >> 1) * wo2;
  int pxc = r1 % pc; int cls = r1 / pc;
  if (cls >= 4) return;
  int p0 = cls >> 1, q0 = cls & 1;
  int tx = pxc % wo2, ty = pxc / wo2;
  int oy = 2 * ty + 1 - p0, ox = 2 * tx + 1 - q0;
  int iy0 = (oy + 1 - p0) >> 1, ix0 = (ox + 1 - q0) >> 1;
  int mtile0 = mg * MT;
  f32x4 zero = {0.f, 0.f, 0.f, 0.f};
  f32x4 acc[MT][4];
  #pragma unroll
  for (int mt = 0; mt < MT; ++mt)
    #pragma unroll
    for (int nt = 0; nt < 4; ++nt) acc[mt][nt] = zero;
  const ushort* wbase = wp + ((size_t)cls * (COUT / 16) + mtile0) * NCH * 512 + lane * 8;
  const size_t mstride = (size_t)NCH * 512;
  bool interior = (iy0 >= 1) & (iy0 <= Hin - 1) & (ix0 >= 1) & (ix0 <= Win - 1);

  if (interior) {
    #pragma unroll
    for (int i = 0; i < 2; ++i) {
      int iy = iy0 - i;
      #pragma unroll
      for (int j = 0; j < 2; ++j) {
        int ix = ix0 - j;
        const ushort* ib = in + (size_t)(iy * Win + ix) * (CIN * 64) + lane * 8;
        int tap = i * 2 + j;
        #pragma unroll
        for (int kc = 0; kc < NKC; ++kc) {
          int kcg = tap * NKC + kc;
          bf16x8 a[MT], bb[4];
          #pragma unroll
          for (int mt = 0; mt < MT; ++mt)
            a[mt] = *(const bf16x8*)(wbase + mt * mstride + (size_t)kcg * 512);
          #pragma unroll
          for (int nt = 0; nt < 4; ++nt)
            bb[nt] = *(const bf16x8*)(ib + kc * 2048 + nt * 512);
          #pragma unroll
          for (int mt = 0; mt < MT; ++mt)
            #pragma unroll
            for (int nt = 0; nt < 4; ++nt)
              acc[mt][nt] = __builtin_amdgcn_mfma_f32_16x16x32_bf16(a[mt], bb[nt], acc[mt][nt], 0, 0, 0);
        }
      }
    }
  } else {
    for (int i = 0; i < 2; ++i) {
      int iy = iy0 - i;
      if ((unsigned)iy >= (unsigned)Hin) continue;
      for (int j = 0; j < 2; ++j) {
        int ix = ix0 - j;
        if ((unsigned)ix >= (unsigned)Win) continue;
        const ushort* ib = in + (size_t)(iy * Win + ix) * (CIN * 64) + lane * 8;
        int tap = i * 2 + j;
        #pragma unroll
        for (int kc = 0; kc < NKC; ++kc) {
          int kcg = tap * NKC + kc;
          bf16x8 a[MT], bb[4];
          #pragma unroll
          for (int mt = 0; mt < MT; ++mt)
            a[mt] = *(const bf16x8*)(wbase + mt * mstride + (size_t)kcg * 512);
          #pragma unroll
          for (int nt = 0; nt < 4; ++nt)
            bb[nt] = *(const bf16x8*)(ib + kc * 2048 + nt * 512);
          #pragma unroll
          for (int mt = 0; mt < MT; ++mt)
            #pragma unroll
            for (int nt = 0; nt < 4; ++nt)
              acc[mt][nt] = __builtin_amdgcn_mfma_f32_16x16x32_bf16(a[mt], bb[nt], acc[mt][nt], 0, 0, 0);
        }
      }
    }
  }
  int ml = lane & 15, rb = (lane >> 4) * 4;
  int px = oy * Wout + ox;
  #pragma unroll
  for (int mt = 0; mt < MT; ++mt) {
    int co = mtile0 * 16 + mt * 16 + rb;
    f32x4 bv = *(const f32x4*)(bias + co);
    #pragma unroll
    for (int nt = 0; nt < 4; ++nt) {
      float v0 = acc[mt][nt][0] + bv[0];
      float v1 = acc[mt][nt][1] + bv[1];
      float v2 = acc[mt][nt][2] + bv[2];
      float v3 = acc[mt][nt][3] + bv[3];
      if (RELU) { v0=fmaxf(v0,0.f); v1=fmaxf(v1,0.f); v2=fmaxf(v2,0.f); v3=fmaxf(v3,0.f); }
      uint2 pk;
      pk.x = (unsigned)f2bf(v0) | ((unsigned)f2bf(v1) << 16);
      pk.y = (unsigned)f2bf(v2) | ((unsigned)f2bf(v3) << 16);
      size_t off = (size_t)px * (COUT * 64) + (size_t)(co >> 5) * 2048 + (size_t)nt * NTS
                 + ((co >> 3) & 3) * 128 + ml * 8 + (co & 7);
      *(uint2*)(out + off) = pk;
    }
  }
}

// ================= enc_fc fused: LDS-transpose staging + MFMA =================
#define APXS 1032
__global__ __launch_bounds__(256) void k_encfc_fused(const ushort* __restrict__ h4,
                                                     const float* __restrict__ wE,
                                                     float* __restrict__ partial) {
  __shared__ float smem[8320];
  ushort* au = (ushort*)smem;
  int s = blockIdx.x;
  int bid = (s & 7) * 256 + (s >> 3);
  int mg = bid & 15;
  int ccf = (bid >> 4) & 7;
  int pxg = bid >> 7;
  int tid = threadIdx.x;
  int co0 = mg * 32;
  #pragma unroll
  for (int i = 0; i < 16; ++i) {
    int idx = tid + i * 256;
    int px4 = idx & 3;
    int ci_l = (idx >> 2) & 31;
    int co_l = idx >> 7;
    float4 v = *(const float4*)&wE[((size_t)(co0 + co_l) << 16)
                                   + (size_t)(ccf * 32 + ci_l) * 256 + pxg * 16 + px4 * 4];
    int mt = co_l >> 4, m = co_l & 15;
    int kg = ci_l >> 3, k8 = ci_l & 7;
    int base = mt * 512 + kg * 128 + m * 8 + k8;
    au[(px4 * 4 + 0) * APXS + base] = f2bf(v.x);
    au[(px4 * 4 + 1) * APXS + base] = f2bf(v.y);
    au[(px4 * 4 + 2) * APXS + base] = f2bf(v.z);
    au[(px4 * 4 + 3) * APXS + base] = f2bf(v.w);
  }
  __syncthreads();
  int lane = tid & 63, wv = tid >> 6;
  int ml = lane & 15, rb = (lane >> 4) * 4;
  f32x4 zero = {0.f, 0.f, 0.f, 0.f};
  f32x4 acc[2][4];
  #pragma unroll
  for (int mt = 0; mt < 2; ++mt)
    #pragma unroll
    for (int nt = 0; nt < 4; ++nt) acc[mt][nt] = zero;
  #pragma unroll
  for (int jj = 0; jj < 4; ++jj) {
    int j = wv * 4 + jj;
    int px = pxg * 16 + j;
    bf16x8 a0 = *(const bf16x8*)(au + j * APXS + lane * 8);
    bf16x8 a1 = *(const bf16x8*)(au + j * APXS + 512 + lane * 8);
    const ushort* hb = h4 + (size_t)px * 16384 + ccf * 2048 + lane * 8;
    bf16x8 bb[4];
    #pragma unroll
    for (int nt = 0; nt < 4; ++nt)
      bb[nt] = *(const bf16x8*)(hb + nt * 512);
    #pragma unroll
    for (int nt = 0; nt < 4; ++nt) {
      acc[0][nt] = __builtin_amdgcn_mfma_f32_16x16x32_bf16(a0, bb[nt], acc[0][nt], 0, 0, 0);
      acc[1][nt] = __builtin_amdgcn_mfma_f32_16x16x32_bf16(a1, bb[nt], acc[1][nt], 0, 0, 0);
    }
  }
  __syncthreads();
  #pragma unroll
  for (int mt = 0; mt < 2; ++mt)
    #pragma unroll
    for (int nt = 0; nt < 4; ++nt)
      #pragma unroll
      for (int r = 0; r < 4; ++r)
        smem[wv * 2080 + (mt * 16 + rb + r) * 65 + nt * 16 + ml] = acc[mt][nt][r];
  __syncthreads();
  int ks = pxg * 8 + ccf;
  #pragma unroll
  for (int i = 0; i < 8; ++i) {
    int e = tid + i * 256;
    int b = e & 63, co_l = e >> 6;
    float sum = smem[co_l * 65 + b] + smem[2080 + co_l * 65 + b]
              + smem[4160 + co_l * 65 + b] + smem[6240 + co_l * 65 + b];
    partial[((size_t)(co0 + co_l) * ENC_KS + ks) * 64 + b] = sum;
  }
}

__global__ void k_encfc_red(const float* __restrict__ partial, const float* __restrict__ bias,
                            float* __restrict__ cnn) {
  int id = blockIdx.x * blockDim.x + threadIdx.x;
  int o = id >> 6, b = id & 63;
  float acc = bias[o];
  #pragma unroll 8
  for (int s = 0; s < ENC_KS; ++s) acc += partial[((size_t)o * ENC_KS + s) * 64 + b];
  cnn[(size_t)b * 512 + o] = fmaxf(acc, 0.f);
}

// ================= fused posterior + reparam: 1024-thread k-split, bf16 powT4 =================
__global__ __launch_bounds__(1024) void k_postz(const float* __restrict__ cnn,
                                                const float* __restrict__ belief,
                                                const ushort* __restrict__ powT,
                                                const float* __restrict__ bias,
                                                const float* __restrict__ eps,
                                                float* __restrict__ out,
                                                ushort* __restrict__ zb) {
  __shared__ float cs[512];
  __shared__ float bs[512];
  __shared__ float smv[512];
  __shared__ float red[512];
  int b = blockIdx.x;
  int tid = threadIdx.x;
  int j = tid & 511;
  int half = tid >> 9;
  if (tid < 512) cs[tid] = cnn[(size_t)b * HIDD + tid];
  else           bs[tid - 512] = belief[(size_t)b * HIDD + (tid - 512)];
  __syncthreads();
  float acc = half ? 0.f : bias[j];
  const ushort* wb = powT + (size_t)(half * 128) * 2048 + j * 4;
  const float* src = half ? bs : cs;
  #pragma unroll 4
  for (int p = 0; p < 128; ++p) {
    ushort4 w4 = *(const ushort4*)(wb + (size_t)p * 2048);
    acc += src[4*p]   * bf2f(w4.x) + src[4*p+1] * bf2f(w4.y)
         + src[4*p+2] * bf2f(w4.z) + src[4*p+3] * bf2f(w4.w);
  }
  if (half) red[j] = acc;
  __syncthreads();
  if (!half) {
    float t = acc + red[j];
    smv[j] = t;
    if (j < 256) out[O_MUPO + b * 256 + j] = t;
    else         out[O_LVPO + b * 256 + (j - 256)] = t;
  }
  __syncthreads();
  if (tid < 256) {
    float z = smv[tid] + eps[b * 256 + tid] * expf(0.5f * smv[tid + 256]);
    out[O_ZT + b * 256 + tid] = z;
    if (tid < 128) zb[b * 128 + tid] = f2bf(z);
  }
}

// ================= dec_fc MFMA: direct f32 weights, frag-order out =================
__global__ __launch_bounds__(256) void k_decfc_mfma(const ushort* __restrict__ zb,
                                                    const float* __restrict__ dfw,
                                                    const float* __restrict__ dfb,
                                                    ushort* __restrict__ dec) {
  int wid = __builtin_amdgcn_readfirstlane(blockIdx.x * 4 + (threadIdx.x >> 6));
  int lane = threadIdx.x & 63;
  int m0 = wid * 32;
  int ml = lane & 15, kl = (lane >> 4) * 8;
  f32x4 zero = {0.f, 0.f, 0.f, 0.f};
  f32x4 acc[2][4];
  #pragma unroll
  for (int mt = 0; mt < 2; ++mt)
    #pragma unroll
    for (int nt = 0; nt < 4; ++nt) acc[mt][nt] = zero;
  #pragma unroll
  for (int kc = 0; kc < 4; ++kc) {
    bf16x8 a[2], bb[4];
    #pragma unroll
    for (int mt = 0; mt < 2; ++mt) {
      int m_r = m0 + mt * 16 + ml;
      const float* wr = dfw + (size_t)((m_r & 127) * 256 + (m_r >> 7)) * 128 + kc * 32 + kl;
      float4 u0 = *(const float4*)wr;
      float4 u1 = *(const float4*)(wr + 4);
      bf16x8 av;
      av[0] = (short)f2bf(u0.x); av[1] = (short)f2bf(u0.y);
      av[2] = (short)f2bf(u0.z); av[3] = (short)f2bf(u0.w);
      av[4] = (short)f2bf(u1.x); av[5] = (short)f2bf(u1.y);
      av[6] = (short)f2bf(u1.z); av[7] = (short)f2bf(u1.w);
      a[mt] = av;
    }
    #pragma unroll
    for (int nt = 0; nt < 4; ++nt)
      bb[nt] = *(const bf16x8*)(zb + (size_t)(nt * 16 + ml) * 128 + kc * 32 + kl);
    #pragma unroll
    for (int mt = 0; mt < 2; ++mt)
      #pragma unroll
      for (int nt = 0; nt < 4; ++nt)
        acc[mt][nt] = __builtin_amdgcn_mfma_f32_16x16x32_bf16(a[mt], bb[nt], acc[mt][nt], 0, 0, 0);
  }
  int rb = (lane >> 4) * 4;
  #pragma unroll
  for (int mt = 0; mt < 2; ++mt) {
    int m = m0 + mt * 16 + rb;
    int pix = m >> 7, co = m & 127;
    float bv0 = dfb[(size_t)(co + 0) * 256 + pix];
    float bv1 = dfb[(size_t)(co + 1) * 256 + pix];
    float bv2 = dfb[(size_t)(co + 2) * 256 + pix];
    float bv3 = dfb[(size_t)(co + 3) * 256 + pix];
    #pragma unroll
    for (int nt = 0; nt < 4; ++nt) {
      uint2 pk;
      pk.x = (unsigned)f2bf(acc[mt][nt][0] + bv0) | ((unsigned)f2bf(acc[mt][nt][1] + bv1) << 16);
      pk.y = (unsigned)f2bf(acc[mt][nt][2] + bv2) | ((unsigned)f2bf(acc[mt][nt][3] + bv3) << 16);
      size_t off = (size_t)pix * 8192 + (size_t)(co >> 5) * 2048 + nt * 512
                 + ((co >> 3) & 3) * 128 + ml * 8 + (co & 7);
      *(uint2*)(dec + off) = pk;
    }
  }
}

// ================= d4 fused with output transpose (XCD-swizzled) =================
__global__ __launch_bounds__(256) void k_d4t(const ushort* __restrict__ in,
                                             const float* __restrict__ w,
                                             const float* __restrict__ bias,
                                             float* __restrict__ out) {
  __shared__ float lds[64][65];
  int blk = xcd_swz();
  int oy = blk >> 2, ox0 = (blk & 3) << 6;
  int t = threadIdx.x;
  int b = t & 63, sub = t >> 6;
  float bv = bias[0];
  for (int j = 0; j < 16; ++j) {
    int oxl = j * 4 + sub;
    int ox = ox0 + oxl;
    int p0 = (oy + 1) & 1, q0 = (ox + 1) & 1;
    int iy0 = (oy + 1 - p0) >> 1, ix0 = (ox + 1 - q0) >> 1;
    float acc = bv;
    #pragma unroll
    for (int i = 0; i < 2; ++i) {
      int iy = iy0 - i;
      if ((unsigned)iy >= 128u) continue;
      int p = p0 + 2 * i;
      #pragma unroll
      for (int jj = 0; jj < 2; ++jj) {
        int ix = ix0 - jj;
        if ((unsigned)ix >= 128u) continue;
        int q = q0 + 2 * jj;
        const ushort* base = in + (size_t)(iy * 128 + ix) * 1024 + (b >> 4) * 256 + (b & 15) * 8;
        bf16x8 v0 = *(const bf16x8*)(base);
        bf16x8 v1 = *(const bf16x8*)(base + 128);
        const float* wq = w + p * 4 + q;
        #pragma unroll
        for (int ci = 0; ci < 8; ++ci) acc += bf2f((ushort)v0[ci]) * wq[ci * 16];
        #pragma unroll
        for (int ci = 0; ci < 8; ++ci) acc += bf2f((ushort)v1[ci]) * wq[(ci + 8) * 16];
      }
    }
    lds[oxl][b] = acc;
  }
  __syncthreads();
  #pragma unroll
  for (int j = 0; j < 16; ++j) {
    int idx = t + j * 256;
    int b2 = idx >> 6, oxl = idx & 63;
    out[(size_t)b2 * 65536 + oy * 256 + ox0 + oxl] = lds[oxl][b2];
  }
}

// ================= launch =================

extern "C" void kernel_launch(void* const* d_in, const int* in_sizes, int n_in,
                              void* d_out, int out_size, void* d_ws, size_t ws_size,
                              hipStream_t stream) {
  const float* img      = (const float*)d_in[0];
  const float* act      = (const float*)d_in[1];
  const float* z_prev   = (const float*)d_in[2];
  const float* st_prev  = (const float*)d_in[3];
  const float* eps      = (const float*)d_in[4];
  const float* c1w = (const float*)d_in[5];  const float* c1b = (const float*)d_in[6];
  const float* c2w = (const float*)d_in[7];  const float* c2b = (const float*)d_in[8];
  const float* c3w = (const float*)d_in[9];  const float* c3b = (const float*)d_in[10];
  const float* c4w = (const float*)d_in[11]; const float* c4b = (const float*)d_in[12];
  const float* efw = (const float*)d_in[13]; const float* efb = (const float*)d_in[14];
  const float* pow_ = (const float*)d_in[15]; const float* pob = (const float*)d_in[16];
  const float* prw = (const float*)d_in[17]; const float* prb = (const float*)d_in[18];
  const float* siw = (const float*)d_in[19]; const float* sib = (const float*)d_in[20];
  const float* Alog = (const float*)d_in[21];
  const float* Bw = (const float*)d_in[22];  const float* Cw = (const float*)d_in[23];
  const float* Dw = (const float*)d_in[24];  const float* Db = (const float*)d_in[25];
  const float* Dv = (const float*)d_in[26];
  const float* dfw = (const float*)d_in[27]; const float* dfb = (const float*)d_in[28];
  const float* d1w = (const float*)d_in[29]; const float* d1b = (const float*)d_in[30];
  const float* d2w = (const float*)d_in[31]; const float* d2b = (const float*)d_in[32];
  const float* d3w = (const float*)d_in[33]; const float* d3b = (const float*)d_in[34];
  const float* d4w = (const float*)d_in[35]; const float* d4b = (const float*)d_in[36];

  float* ws = (float*)d_ws;
  float* out = (float*)d_out;

  ushort* pc2 = (ushort*)(ws + PW_C2);
  ushort* pc3 = (ushort*)(ws + PW_C3);
  ushort* pc4 = (ushort*)(ws + PW_C4);
  ushort* pd1 = (ushort*)(ws + PW_D1);
  ushort* pd2 = (ushort*)(ws + PW_D2);
  ushort* pd3 = (ushort*)(ws + PW_D3);
  ushort* pc1 = (ushort*)(ws + PW_C1);
  ushort* timg4 = (ushort*)(ws + W_TIMG);
  ushort* h1b = (ushort*)(ws + W_H1B);
  ushort* h2b = (ushort*)(ws + W_H2B);
  ushort* h3b = (ushort*)(ws + W_H3B);
  ushort* h4b = (ushort*)(ws + W_H4B);
  ushort* deco = (ushort*)(ws + W_DECO);
  ushort* d1o = (ushort*)(ws + W_D1O);
  ushort* d2o = (ushort*)(ws + W_D2O);
  ushort* d3o = (ushort*)(ws + W_D3O);
  ushort* zb = (ushort*)(ws + W_ZB16);
  ushort* siwT = (ushort*)(ws + W_SIWT);
  ushort* DwT  = (ushort*)(ws + W_DWT);
  ushort* prwT = (ushort*)(ws + W_PRWT);
  ushort* powT = (ushort*)(ws + W_POWT);

  // ---- merged weight prepack (bf16 4-grouped dense transposes) ----
  k_pack_all<<<7992, 256, 0, stream>>>(c2w, c3w, c4w, d1w, d2w, d3w, c1w,
                                       siw, Dw, prw, pow_,
                                       pc2, pc3, pc4, pd1, pd2, pd3, pc1,
                                       siwT, DwT, prwT, powT);

  // ---- SSM (k-split, bf16 weights) || img transpose, both post-pack ----
  k_ssm_timg<<<1088, 1024, 0, stream>>>(z_prev, act, siwT, sib, DwT, Db, Bw, Cw,
                                        Alog, Dv, st_prev, out + O_STATE,
                                        ws + W_BELIEF, prwT, prb, out,
                                        img, timg4);

  // ---- encoder (XCD-swizzled convs) ----
  k_conv1_mfma<<<4096, 256, 0, stream>>>(timg4, pc1, c1b, h1b);
  mfma_conv<32, 64, 4><<<1024, 256, 0, stream>>>(h1b, pc2, c2b, h2b, 128, 128, 64, 64);
  mfma_conv<64, 128, 4><<<512, 256, 0, stream>>>(h2b, pc3, c3b, h3b, 64, 64, 32, 32);
  mfma_conv<128, 256, 2><<<512, 256, 0, stream>>>(h3b, pc4, c4b, h4b, 32, 32, 16, 16);

  // ---- enc_fc (fused transpose+GEMM, already swizzled) ----
  k_encfc_fused<<<2048, 256, 0, stream>>>(h4b, efw, ws + W_ENCP);
  k_encfc_red<<<128, 256, 0, stream>>>(ws + W_ENCP, efb, ws + W_CNN);

  // ---- fused posterior + reparam (k-split, bf16 weights) ----
  k_postz<<<64, 1024, 0, stream>>>(ws + W_CNN, ws + W_BELIEF, powT, pob, eps, out, zb);

  // ---- decoder (XCD-swizzled deconvs) ----
  k_decfc_mfma<<<256, 256, 0, stream>>>(zb, dfw, dfb, deco);
  mfma_deconv<128, 64, 2, true><<<512, 256, 0, stream>>>(deco, pd1, d1b, d1o, 16, 16, 32, 32);
  mfma_deconv<64, 32, 2, true><<<1024, 256, 0, stream>>>(d1o, pd2, d2b, d2o, 32, 32, 64, 64);
  mfma_deconv<32, 16, 1, true><<<4096, 256, 0, stream>>>(d2o, pd3, d3b, d3o, 64, 64, 128, 128);
  k_d4t<<<1024, 256, 0, stream>>>(d3o, d4w, d4b, out + O_PRED);
}